// Round 3
// baseline (79688.196 us; speedup 1.0000x reference)
//
#include <hip/hip_runtime.h>
#include <cstddef>
#include <cstdint>
#include <math.h>

// ============================ constants ============================
static constexpr int NN   = 1024;   // lr_dim
static constexpr int HRD  = 2048;   // hr_dim
static constexpr int DIMF = 320;
static constexpr int TB   = 85;     // sytrd LDS tail block (85x87 fp64 = 59 KB LDS)
static constexpr int CB   = 128;    // persistent sytrd blocks (<= CU count -> co-resident)

#define EPI_NONE      0
#define EPI_BIAS      1
#define EPI_BIAS_ADD  2
#define EPI_ABS_DIAG1 3
#define EPI_RELU      4

// ============================ fp32 GEMM 64-tile (fallback, odd K) ============================
template<int EPI>
__global__ __launch_bounds__(256) void gemm32(
    const float* __restrict__ A, const float* __restrict__ B, float* __restrict__ C,
    int M, int N, int K, const float* __restrict__ bias, const float* __restrict__ D)
{
    __shared__ float As[16][65];
    __shared__ float Bs[16][65];
    const int bm = blockIdx.y << 6, bn = blockIdx.x << 6;
    const int tid = threadIdx.x;
    const int tm = (tid >> 4) << 2, tn = (tid & 15) << 2;
    float acc[4][4] = {};
    const int kt = (K + 15) >> 4;
    for (int k0 = 0; k0 < kt; ++k0){
        const int kb = k0 << 4;
        for (int t = tid; t < 1024; t += 256){
            int m = t >> 4, k = t & 15;
            int gm = bm + m, gk = kb + k;
            As[k][m] = (gm < M && gk < K) ? A[(size_t)gm*K + gk] : 0.f;
        }
        for (int t = tid; t < 1024; t += 256){
            int k = t >> 6, nn2 = t & 63;
            int gk = kb + k, gn = bn + nn2;
            Bs[k][nn2] = (gk < K && gn < N) ? B[(size_t)gk*N + gn] : 0.f;
        }
        __syncthreads();
        #pragma unroll
        for (int k = 0; k < 16; ++k){
            float a0 = As[k][tm], a1 = As[k][tm+1], a2 = As[k][tm+2], a3 = As[k][tm+3];
            float b0 = Bs[k][tn], b1 = Bs[k][tn+1], b2 = Bs[k][tn+2], b3 = Bs[k][tn+3];
            acc[0][0] += a0*b0; acc[0][1] += a0*b1; acc[0][2] += a0*b2; acc[0][3] += a0*b3;
            acc[1][0] += a1*b0; acc[1][1] += a1*b1; acc[1][2] += a1*b2; acc[1][3] += a1*b3;
            acc[2][0] += a2*b0; acc[2][1] += a2*b1; acc[2][2] += a2*b2; acc[2][3] += a2*b3;
            acc[3][0] += a3*b0; acc[3][1] += a3*b1; acc[3][2] += a3*b2; acc[3][3] += a3*b3;
        }
        __syncthreads();
    }
    #pragma unroll
    for (int r = 0; r < 4; ++r){
        int gm = bm + tm + r; if (gm >= M) continue;
        #pragma unroll
        for (int c = 0; c < 4; ++c){
            int gn = bn + tn + c; if (gn >= N) continue;
            float v = acc[r][c];
            if (EPI == EPI_BIAS)            v += bias[gn];
            else if (EPI == EPI_BIAS_ADD)   v += bias[gn] + D[(size_t)gm*N + gn];
            else if (EPI == EPI_ABS_DIAG1)  v = (gm == gn) ? 1.0f : fabsf(v);
            else if (EPI == EPI_RELU)       v = fmaxf(v, 0.0f);
            C[(size_t)gm*N + gn] = v;
        }
    }
}

// ============================ fp32 GEMM 128-tile (K%16==0, N%8==0) ============================
template<int EPI>
__global__ __launch_bounds__(256) void gemm128(
    const float* __restrict__ A, const float* __restrict__ B, float* __restrict__ C,
    int M, int N, int K, const float* __restrict__ bias, const float* __restrict__ D)
{
    __shared__ float As[16][132];
    __shared__ float Bs[16][132];
    const int bm = blockIdx.y << 7, bn = blockIdx.x << 7;
    const int tid = threadIdx.x;
    const int tm = (tid >> 4) << 3;
    const int tn = (tid & 15) << 3;
    const int ar = tid >> 1;
    const int ak = (tid & 1) << 3;
    const int br = tid >> 4;
    const int bc = (tid & 15) << 3;
    float acc[8][8] = {};
    for (int kb = 0; kb < K; kb += 16){
        {
            int gm = bm + ar, gk = kb + ak;
            float4 a0, a1;
            if (gm < M){
                const float* p = A + (size_t)gm*K + gk;
                a0 = *(const float4*)p; a1 = *(const float4*)(p + 4);
            } else { a0 = make_float4(0.f,0.f,0.f,0.f); a1 = a0; }
            As[ak+0][ar]=a0.x; As[ak+1][ar]=a0.y; As[ak+2][ar]=a0.z; As[ak+3][ar]=a0.w;
            As[ak+4][ar]=a1.x; As[ak+5][ar]=a1.y; As[ak+6][ar]=a1.z; As[ak+7][ar]=a1.w;
        }
        {
            int gk = kb + br, gn = bn + bc;
            float4 b0, b1;
            if (gn + 7 < N){
                const float* p = B + (size_t)gk*N + gn;
                b0 = *(const float4*)p; b1 = *(const float4*)(p + 4);
            } else {
                float t0[8];
                #pragma unroll
                for (int i = 0; i < 8; ++i){ int g = gn + i; t0[i] = (g < N) ? B[(size_t)gk*N + g] : 0.f; }
                b0 = make_float4(t0[0],t0[1],t0[2],t0[3]); b1 = make_float4(t0[4],t0[5],t0[6],t0[7]);
            }
            *(float4*)&Bs[br][bc] = b0; *(float4*)&Bs[br][bc+4] = b1;
        }
        __syncthreads();
        #pragma unroll
        for (int k = 0; k < 16; ++k){
            float4 a0 = *(const float4*)&As[k][tm];
            float4 a1 = *(const float4*)&As[k][tm+4];
            float4 b0 = *(const float4*)&Bs[k][tn];
            float4 b1 = *(const float4*)&Bs[k][tn+4];
            float av[8] = {a0.x,a0.y,a0.z,a0.w,a1.x,a1.y,a1.z,a1.w};
            float bv[8] = {b0.x,b0.y,b0.z,b0.w,b1.x,b1.y,b1.z,b1.w};
            #pragma unroll
            for (int i = 0; i < 8; ++i)
                #pragma unroll
                for (int jj = 0; jj < 8; ++jj) acc[i][jj] += av[i]*bv[jj];
        }
        __syncthreads();
    }
    #pragma unroll
    for (int i = 0; i < 8; ++i){
        int gm = bm + tm + i; if (gm >= M) continue;
        #pragma unroll
        for (int jj = 0; jj < 8; ++jj){
            int gn = bn + tn + jj; if (gn >= N) continue;
            float v = acc[i][jj];
            if (EPI == EPI_BIAS)            v += bias[gn];
            else if (EPI == EPI_BIAS_ADD)   v += bias[gn] + D[(size_t)gm*N + gn];
            else if (EPI == EPI_ABS_DIAG1)  v = (gm == gn) ? 1.0f : fabsf(v);
            else if (EPI == EPI_RELU)       v = fmaxf(v, 0.0f);
            C[(size_t)gm*N + gn] = v;
        }
    }
}

// ============================ fp64 GEMM 64-tile, 4x4 micro ============================
template<bool TRA>
__global__ __launch_bounds__(256) void gemm64b(
    const double* __restrict__ A, int lda, const double* __restrict__ B, int ldb,
    double* __restrict__ C, int ldc, int M, int N, int K, double alpha, double beta)
{
    __shared__ double As[16][66];
    __shared__ double Bs[16][66];
    const int bm = blockIdx.y << 6, bn = blockIdx.x << 6;
    const int tid = threadIdx.x;
    const int tm = (tid >> 4) << 2, tn = (tid & 15) << 2;
    double acc[4][4] = {};
    for (int kb = 0; kb < K; kb += 16){
        if (!TRA){
            for (int t = tid; t < 1024; t += 256){
                int m = t >> 4, k = t & 15;
                int gm = bm + m, gk = kb + k;
                As[k][m] = (gm < M && gk < K) ? A[(size_t)gm*lda + gk] : 0.0;
            }
        } else {
            for (int t = tid; t < 1024; t += 256){
                int k = t >> 6, m = t & 63;
                int gm = bm + m, gk = kb + k;
                As[k][m] = (gm < M && gk < K) ? A[(size_t)gk*lda + gm] : 0.0;
            }
        }
        for (int t = tid; t < 1024; t += 256){
            int k = t >> 6, nn2 = t & 63;
            int gk = kb + k, gn = bn + nn2;
            Bs[k][nn2] = (gk < K && gn < N) ? B[(size_t)gk*ldb + gn] : 0.0;
        }
        __syncthreads();
        #pragma unroll
        for (int k = 0; k < 16; ++k){
            double a0=As[k][tm],a1=As[k][tm+1],a2=As[k][tm+2],a3=As[k][tm+3];
            double b0=Bs[k][tn],b1=Bs[k][tn+1],b2=Bs[k][tn+2],b3=Bs[k][tn+3];
            acc[0][0]+=a0*b0; acc[0][1]+=a0*b1; acc[0][2]+=a0*b2; acc[0][3]+=a0*b3;
            acc[1][0]+=a1*b0; acc[1][1]+=a1*b1; acc[1][2]+=a1*b2; acc[1][3]+=a1*b3;
            acc[2][0]+=a2*b0; acc[2][1]+=a2*b1; acc[2][2]+=a2*b2; acc[2][3]+=a2*b3;
            acc[3][0]+=a3*b0; acc[3][1]+=a3*b1; acc[3][2]+=a3*b2; acc[3][3]+=a3*b3;
        }
        __syncthreads();
    }
    #pragma unroll
    for (int r = 0; r < 4; ++r){
        int gm = bm + tm + r; if (gm >= M) continue;
        #pragma unroll
        for (int c = 0; c < 4; ++c){
            int gn = bn + tn + c; if (gn >= N) continue;
            double v = alpha*acc[r][c];
            if (beta != 0.0) v += beta*C[(size_t)gm*ldc + gn];
            C[(size_t)gm*ldc + gn] = v;
        }
    }
}

// ============================ small kernels ============================
__global__ __launch_bounds__(256) void rowsum_rsqrt_k(const float* __restrict__ lr, double* __restrict__ r64, int n)
{
    __shared__ double sm[256];
    int row = blockIdx.x;
    double s = 0.0;
    for (int j = threadIdx.x; j < n; j += 256) s += (double)lr[(size_t)row*n + j];
    sm[threadIdx.x] = s; __syncthreads();
    for (int o = 128; o; o >>= 1){ if (threadIdx.x < o) sm[threadIdx.x] += sm[threadIdx.x + o]; __syncthreads(); }
    if (threadIdx.x == 0){
        double t = sm[0];
        r64[row] = (t > 0.0) ? 1.0/sqrt(t) : 0.0;
    }
}

__global__ __launch_bounds__(256) void build_A_k(const float* __restrict__ lr, const double* __restrict__ r64,
                                                 float* __restrict__ A32, double* __restrict__ A64, int n)
{
    size_t idx = (size_t)blockIdx.x*256 + threadIdx.x;
    if (idx >= (size_t)n*n) return;
    int i = (int)(idx / n), j = (int)(idx % n);
    if (j < i) return;
    double v = (double)lr[(size_t)j*n + i] * r64[i] * r64[j];
    A64[(size_t)i*n + j] = v; A64[(size_t)j*n + i] = v;
    float vf = (float)v;
    A32[(size_t)i*n + j] = vf; A32[(size_t)j*n + i] = vf;
}

__global__ __launch_bounds__(256) void score_k(const float* __restrict__ X, const float* __restrict__ pw,
                                               const float* __restrict__ pb, float* __restrict__ out,
                                               int n, int dim)
{
    int row = blockIdx.x*4 + (threadIdx.x >> 6);
    int lane = threadIdx.x & 63;
    if (row >= n) return;
    float acc = 0.f;
    for (int c = lane; c < dim; c += 64) acc += X[(size_t)row*dim + c]*pw[c];
    #pragma unroll
    for (int o = 32; o; o >>= 1) acc += __shfl_down(acc, o);
    if (lane == 0){
        float t = (acc + pb[0]) * 0.01f;
        out[row] = 1.0f/(1.0f + expf(-t));
    }
}

// jax.lax.top_k semantics: descending value, ties -> lower index first
__global__ __launch_bounds__(256) void topk_k(const float* __restrict__ scores, int n, int k,
                                              int* __restrict__ idxo, float* __restrict__ valo)
{
    __shared__ float s[1024];
    int tid = threadIdx.x;
    for (int i = tid; i < n; i += 256) s[i] = scores[i];
    __syncthreads();
    for (int i = tid; i < n; i += 256){
        float si = s[i]; int r = 0;
        for (int j = 0; j < n; ++j){
            float sj = s[j];
            r += (sj > si) || (sj == si && j < i);
        }
        if (r < k){ idxo[r] = i; valo[r] = si; }
    }
}

__global__ __launch_bounds__(256) void gatherX_k(const float* __restrict__ X, const int* __restrict__ idx,
                                                 const float* __restrict__ vals, float* __restrict__ Xo,
                                                 int k, int dim)
{
    size_t t = (size_t)blockIdx.x*256 + threadIdx.x;
    if (t >= (size_t)k*dim) return;
    int m = (int)(t / dim), c = (int)(t % dim);
    Xo[t] = X[(size_t)idx[m]*dim + c] * vals[m];
}

__global__ __launch_bounds__(256) void scatterX_k(const float* __restrict__ Xs, const int* __restrict__ idx,
                                                  float* __restrict__ Xu, int k, int dim)
{
    size_t t = (size_t)blockIdx.x*256 + threadIdx.x;
    if (t >= (size_t)k*dim) return;
    int m = (int)(t / dim), c = (int)(t % dim);
    Xu[(size_t)idx[m]*dim + c] = Xs[t];
}

__global__ __launch_bounds__(256) void gatherA_k(const float* __restrict__ A, const int* __restrict__ idx,
                                                 float* __restrict__ Ao, int k, int n)
{
    size_t t = (size_t)blockIdx.x*256 + threadIdx.x;
    if (t >= (size_t)k*k) return;
    int m1 = (int)(t / k), m2 = (int)(t % k);
    Ao[t] = A[(size_t)idx[m1]*n + idx[m2]];
}

__global__ __launch_bounds__(256) void fill0_k(float* __restrict__ p, size_t cnt)
{
    size_t t = (size_t)blockIdx.x*256 + threadIdx.x;
    if (t < cnt) p[t] = 0.f;
}

__global__ __launch_bounds__(256) void init_sync_k(double* __restrict__ pv, unsigned* __restrict__ bar, int n)
{
    int t = blockIdx.x*256 + threadIdx.x;
    if (t < n) pv[t] = 0.0;
    if (t < 64) bar[t] = 0u;
}

__global__ __launch_bounds__(256) void concat_k(const float* __restrict__ X, const float* __restrict__ orgX,
                                                float* __restrict__ Xc, int n, int dim)
{
    size_t t = (size_t)blockIdx.x*256 + threadIdx.x;
    size_t tot = (size_t)n*2*dim;
    if (t >= tot) return;
    int i = (int)(t / (2*dim)), c = (int)(t % (2*dim));
    Xc[t] = (c < dim) ? X[(size_t)i*dim + c] : orgX[(size_t)i*dim + (c - dim)];
}

__global__ __launch_bounds__(256) void build_a_k(const float* __restrict__ gsr, float* __restrict__ a)
{
    size_t idx = (size_t)blockIdx.x*256 + threadIdx.x;
    if (idx >= (size_t)HRD*NN) return;
    int i = (int)(idx >> 10), k = (int)(idx & 1023);
    a[idx] = gsr[(size_t)i*HRD + k] + gsr[(size_t)i*HRD + NN + k];
}

__global__ __launch_bounds__(256) void symabs1_k(float* __restrict__ Z, int n)
{
    size_t idx = (size_t)blockIdx.x*256 + threadIdx.x;
    if (idx >= (size_t)n*n) return;
    int i = (int)(idx / n), j = (int)(idx % n);
    if (i > j) return;
    float a = Z[(size_t)i*n + j], b = Z[(size_t)j*n + i];
    float v = 0.5f*(a + b);
    float o = (i == j) ? 1.0f : fabsf(v);
    Z[(size_t)i*n + j] = o; Z[(size_t)j*n + i] = o;
}

__global__ __launch_bounds__(256) void final_z_k(const float* __restrict__ h2, float* __restrict__ z, int n)
{
    size_t idx = (size_t)blockIdx.x*256 + threadIdx.x;
    if (idx >= (size_t)n*n) return;
    int i = (int)(idx / n), j = (int)(idx % n);
    if (i > j) return;
    float v = 0.5f*(h2[(size_t)i*n + j] + h2[(size_t)j*n + i]);
    float o = (i == j) ? 1.0f : fabsf(v);
    z[(size_t)i*n + j] = o; z[(size_t)j*n + i] = o;
}

// dst[c][r] = (float)src[r][c]   (n x n, n % 32 == 0)
__global__ __launch_bounds__(256) void transpose_cast_k(const double* __restrict__ src, float* __restrict__ dst, int n)
{
    __shared__ float tile[32][33];
    int r0 = blockIdx.y*32, c0 = blockIdx.x*32;
    int tx = threadIdx.x & 31, ty = threadIdx.x >> 5;
    for (int i = ty; i < 32; i += 8)
        tile[i][tx] = (float)src[(size_t)(r0 + i)*n + (c0 + tx)];
    __syncthreads();
    for (int i = ty; i < 32; i += 8)
        dst[(size_t)(c0 + i)*n + (r0 + tx)] = tile[tx][i];
}

// dst[c][r] = src[r][c]  (n x n, n % 32 == 0)
__global__ __launch_bounds__(256) void transpose32_k(const float* __restrict__ src, float* __restrict__ dst, int n)
{
    __shared__ float tile[32][33];
    int r0 = blockIdx.y*32, c0 = blockIdx.x*32;
    int tx = threadIdx.x & 31, ty = threadIdx.x >> 5;
    for (int i = ty; i < 32; i += 8)
        tile[i][tx] = src[(size_t)(r0 + i)*n + (c0 + tx)];
    __syncthreads();
    for (int i = ty; i < 32; i += 8)
        dst[(size_t)(c0 + i)*n + (r0 + tx)] = tile[tx][i];
}

// ============================ persistent Householder tridiagonalization ============================
// Lightweight grid barrier: monotonic ticket counter, agent-scope atomics + fences.
// All CB blocks are co-resident (CB <= CU count, 1 block/CU capacity guaranteed).
__device__ __forceinline__ void gbar(unsigned* __restrict__ cnt, unsigned nb)
{
    __syncthreads();
    if (threadIdx.x == 0){
        __threadfence();  // release: make prior writes visible at agent scope
        unsigned t = __hip_atomic_fetch_add(cnt, 1u, __ATOMIC_ACQ_REL, __HIP_MEMORY_SCOPE_AGENT);
        unsigned target = (t/nb + 1u)*nb;
        while (__hip_atomic_load(cnt, __ATOMIC_ACQUIRE, __HIP_MEMORY_SCOPE_AGENT) < target){
            __builtin_amdgcn_s_sleep(2);
        }
        __threadfence();  // acquire: invalidate stale cache lines before subsequent loads
    }
    __syncthreads();
}

// v lives implicitly in ROW j of A (symmetric): v[0]=1, v[c]=row[c]*scale.
__global__ __launch_bounds__(256) void sytrd_coop(
    double* __restrict__ A, double* __restrict__ e, double* __restrict__ tau,
    double* __restrict__ scl, double* __restrict__ p, double* __restrict__ pvv,
    unsigned* __restrict__ bar, int n, int jend)
{
    __shared__ double red[256];
    const int tid  = threadIdx.x;
    const int bid  = blockIdx.x;
    const int lane = tid & 63;
    const int wv   = bid*4 + (tid >> 6);
    const int NW   = CB*4;
    const unsigned gtid = (unsigned)bid*256u + (unsigned)tid;
    const unsigned NT   = (unsigned)CB*256u;

    for (int j = 0; j < jend; ++j){
        const int m = n - 1 - j;
        const double* __restrict__ row = A + (size_t)j*n + (j+1);
        // --- redundant per-block norm of the column tail (row j, cols j+2..) ---
        double s = 0.0;
        for (int c = 1 + tid; c < m; c += 256){ double x = row[c]; s += x*x; }
        red[tid] = s; __syncthreads();
        #pragma unroll
        for (int o = 128; o; o >>= 1){ if (tid < o) red[tid] += red[tid + o]; __syncthreads(); }
        double sigma2 = red[0];
        __syncthreads();
        double alpha = row[0];
        double beta, tl, sc;
        if (sigma2 == 0.0){ beta = alpha; tl = 0.0; sc = 0.0; }
        else {
            beta = -copysign(sqrt(alpha*alpha + sigma2), alpha);
            tl = (beta - alpha)/beta;
            sc = 1.0/(alpha - beta);
        }
        if (bid == 0 && tid == 0){ e[j] = beta; tau[j] = tl; scl[j] = sc; }
        // --- matvec p = A_trailing * v, pv = v^T p ---
        double pvloc = 0.0;
        for (int r = wv; r < m; r += NW){
            const double* __restrict__ Ar = A + (size_t)(j+1+r)*n + (j+1);
            double acc = 0.0;
            for (int c = lane; c < m; c += 64){
                double vv = (c == 0) ? 1.0 : row[c]*sc;
                acc += Ar[c]*vv;
            }
            #pragma unroll
            for (int o = 32; o; o >>= 1) acc += __shfl_down(acc, o);
            if (lane == 0){
                p[r] = acc;
                double vr = (r == 0) ? 1.0 : row[r]*sc;
                pvloc += acc*vr;
            }
        }
        red[tid] = pvloc; __syncthreads();
        #pragma unroll
        for (int o = 128; o; o >>= 1){ if (tid < o) red[tid] += red[tid + o]; __syncthreads(); }
        if (tid == 0 && red[0] != 0.0) atomicAdd(&pvv[j], red[0]);
        gbar(bar, CB);
        // --- rank-2 trailing update: A -= v w^T + w v^T ---
        double pv = pvv[j];
        double c2 = 0.5*tl*tl*pv;
        unsigned um = (unsigned)m;
        unsigned tot = um*um;
        for (unsigned idx = gtid; idx < tot; idx += NT){
            unsigned r = idx / um, c = idx - r*um;
            double vr = (r == 0u) ? 1.0 : row[r]*sc;
            double vc = (c == 0u) ? 1.0 : row[c]*sc;
            double wr = tl*p[r] - c2*vr;
            double wc = tl*p[c] - c2*vc;
            A[(size_t)(j+1+(int)r)*n + (j+1+(int)c)] -= vr*wc + wr*vc;
        }
        gbar(bar, CB);
    }
}

// Tail: remaining (TB-2) Householder steps entirely in LDS (single block).
__global__ __launch_bounds__(256) void hh_tail(double* __restrict__ A64, double* __restrict__ e,
                                               double* __restrict__ tau, double* __restrict__ scaleg, int n)
{
    __shared__ double T[TB][TB+2];
    __shared__ double v[TB], p[TB], red[256];
    const int base = n - TB;
    const int tid = threadIdx.x;
    for (int t = tid; t < TB*TB; t += 256){
        int r = t / TB, c = t % TB;
        T[r][c] = A64[(size_t)(base + r)*n + base + c];
    }
    __syncthreads();
    for (int l = 0; l <= TB - 3; ++l){
        const int m = TB - 1 - l;
        double s = 0.0;
        for (int i = 1 + tid; i < m; i += 256){ double x = T[l+1+i][l]; s += x*x; }
        red[tid] = s; __syncthreads();
        for (int o = 128; o; o >>= 1){ if (tid < o) red[tid] += red[tid + o]; __syncthreads(); }
        double sigma2 = red[0];
        double alpha = T[l+1][l];
        double beta, tl, sc;
        if (sigma2 == 0.0){ beta = alpha; tl = 0.0; sc = 0.0; }
        else {
            beta = -copysign(sqrt(alpha*alpha + sigma2), alpha);
            tl = (beta - alpha)/beta;
            sc = 1.0/(alpha - beta);
        }
        for (int i = tid; i < m; i += 256) v[i] = (i == 0) ? 1.0 : T[l+1+i][l]*sc;
        __syncthreads();
        for (int i = tid; i < m; i += 256){
            double acc = 0.0;
            for (int c = 0; c < m; ++c) acc += T[l+1+i][l+1+c]*v[c];
            p[i] = acc;
        }
        __syncthreads();
        double s2 = 0.0;
        for (int i = tid; i < m; i += 256) s2 += p[i]*v[i];
        red[tid] = s2; __syncthreads();
        for (int o = 128; o; o >>= 1){ if (tid < o) red[tid] += red[tid + o]; __syncthreads(); }
        double pvv = red[0];
        double c2 = 0.5*tl*tl*pvv;
        for (int t2 = tid; t2 < m*m; t2 += 256){
            int r = t2 / m, c = t2 % m;
            double wr = tl*p[r] - c2*v[r];
            double wc = tl*p[c] - c2*v[c];
            T[l+1+r][l+1+c] -= v[r]*wc + wr*v[c];
        }
        if (tid == 0){ int j = base + l; e[j] = beta; tau[j] = tl; scaleg[j] = 1.0; }
        for (int i = tid; i < m; i += 256) A64[(size_t)(base + l)*n + (base + l + 1) + i] = v[i];
        __syncthreads();
    }
    for (int r = tid; r < TB; r += 256) A64[(size_t)(base + r)*n + base + r] = T[r][r];
    if (tid == 0) A64[(size_t)(n-1)*n + (n-2)] = T[TB-1][TB-2];
}

__global__ __launch_bounds__(256) void extract_de_k(const double* __restrict__ A64, double* __restrict__ d,
                                                    double* __restrict__ e, int n)
{
    int i = blockIdx.x*256 + threadIdx.x;
    if (i < n) d[i] = A64[(size_t)i*n + i];
    if (i == 0) e[n-2] = A64[(size_t)(n-1)*n + (n-2)];
}

// ============================ tridiagonal eigensolver ============================
__global__ __launch_bounds__(256) void bisect_k(const double* __restrict__ d, const double* __restrict__ e,
                                                double* __restrict__ w, int n)
{
    int k = blockIdx.x*256 + threadIdx.x;
    if (k >= n) return;
    double gl = 1e300, gu = -1e300;
    for (int i = 0; i < n; ++i){
        double em = (i > 0) ? fabs(e[i-1]) : 0.0, ep = (i < n-1) ? fabs(e[i]) : 0.0;
        double lo2 = d[i] - em - ep, hi2 = d[i] + em + ep;
        gl = fmin(gl, lo2); gu = fmax(gu, hi2);
    }
    double lo = gl - 1e-10, hi = gu + 1e-10;
    const double pivmin = 1e-280;
    for (int it = 0; it < 42; ++it){
        double mid = 0.5*(lo + hi);
        int cnt = 0; double q = 1.0;
        for (int i = 0; i < n; ++i){
            double t;
            if (i == 0) t = d[0] - mid;
            else { double ei = e[i-1]; t = d[i] - mid - ei*(ei/q); }
            if (fabs(t) < pivmin) t = -pivmin;
            if (t < 0.0) ++cnt;
            q = t;
        }
        if (cnt <= k) lo = mid; else hi = mid;
    }
    w[k] = 0.5*(lo + hi);
}

__global__ __launch_bounds__(256) void invit_k(const double* __restrict__ d, const double* __restrict__ e,
                                               const double* __restrict__ w,
                                               double* __restrict__ FD, double* __restrict__ FL,
                                               double* __restrict__ FU, double* __restrict__ FU2,
                                               signed char* __restrict__ PIV, double* __restrict__ Z, int n)
{
    int k = blockIdx.x*256 + threadIdx.x;
    if (k >= n) return;
    const double lam = w[k];
    const double tiny = 1e-280;
    // pivoted LU (dgttrf-style), register-carried recurrence
    double dcur = d[0] - lam;
    double ucur = e[0];
    for (int i = 0; i < n-1; ++i){
        double dli = e[i];
        double dnext_init = d[i+1] - lam;
        double unext_init = (i < n-2) ? e[i+1] : 0.0;
        size_t o = (size_t)i*n + k;
        if (fabs(dcur) >= fabs(dli)){
            if (dcur == 0.0) dcur = tiny;
            double f = dli/dcur;
            FD[o] = dcur; FL[o] = f; FU[o] = ucur; FU2[o] = 0.0; PIV[o] = 0;
            dcur = dnext_init - f*ucur;
            ucur = unext_init;
        } else {
            double f = dcur/dli;
            FD[o] = dli; FL[o] = f; FU[o] = dnext_init; FU2[o] = unext_init; PIV[o] = 1;
            dcur = ucur - f*dnext_init;
            ucur = -f*unext_init;
        }
    }
    if (dcur == 0.0) dcur = tiny;
    FD[(size_t)(n-1)*n + k] = dcur;
    // pseudo-random start vector
    for (int i = 0; i < n; ++i){
        unsigned h = (unsigned)(i + 1)*0x9E3779B9u + (unsigned)(k + 1)*0x85EBCA6Bu;
        h ^= h >> 16; h *= 0x7FEB352Du; h ^= h >> 15; h *= 0x846CA68Bu; h ^= h >> 16;
        Z[(size_t)i*n + k] = (double)(h >> 8)*(1.0/16777216.0) - 0.5;
    }
    for (int iter = 0; iter < 2; ++iter){
        // forward substitution (register-carried)
        double zc = Z[k];
        for (int i = 0; i < n-1; ++i){
            size_t o = (size_t)i*n + k;
            double fl = FL[o];
            double zn = Z[o + n];
            if (!PIV[o]){
                Z[o] = zc;
                zc = zn - fl*zc;
            } else {
                Z[o] = zn;
                zc = zc - fl*zn;
            }
        }
        // backward substitution (register-carried)
        double za = zc / FD[(size_t)(n-1)*n + k];
        Z[(size_t)(n-1)*n + k] = za;
        size_t o2 = (size_t)(n-2)*n + k;
        double zaa = (Z[o2] - FU[o2]*za) / FD[o2];
        Z[o2] = zaa;
        double zb = za;
        for (int i = n-3; i >= 0; --i){
            size_t o = (size_t)i*n + k;
            double znew = (Z[o] - FU[o]*zaa - FU2[o]*zb) / FD[o];
            Z[o] = znew;
            zb = zaa; zaa = znew;
        }
        double mx = 0.0;
        for (int i = 0; i < n; ++i) mx = fmax(mx, fabs(Z[(size_t)i*n + k]));
        double s = (mx > 0.0) ? 1.0/mx : 1.0;
        for (int i = 0; i < n; ++i) Z[(size_t)i*n + k] *= s;
    }
    double nrm = 0.0;
    for (int i = 0; i < n; ++i){ double v = Z[(size_t)i*n + k]; nrm += v*v; }
    double s = 1.0/sqrt(nrm);
    for (int i = 0; i < n; ++i) Z[(size_t)i*n + k] *= s;
}

// ============================ blocked-WY back-transform ============================
// v_j stored in ROW j of A64 (cols j+1..): v(r)=1 at r==j+1, else A64[j][r]*scale[j]
__global__ __launch_bounds__(256) void build_V_k(const double* __restrict__ A64, const double* __restrict__ scaleg,
                                                 double* __restrict__ V, int n, int b, int nbsz)
{
    size_t idx = (size_t)blockIdx.x*256 + threadIdx.x;
    if (idx >= (size_t)n*64) return;
    int r = (int)(idx >> 6), t = (int)(idx & 63);
    double v = 0.0;
    if (t < nbsz){
        int j = b + t;
        if (r == j + 1) v = 1.0;
        else if (r > j + 1) v = A64[(size_t)j*n + r]*scaleg[j];
    }
    V[(size_t)r*64 + t] = v;
}

__global__ __launch_bounds__(256) void build_T_k(const double* __restrict__ V, const double* __restrict__ tau,
                                                 double* __restrict__ T, int n, int b, int nbsz)
{
    __shared__ double G[64][64];
    int tid = threadIdx.x;
    for (int p = tid; p < 64*64; p += 256){
        int t = p >> 6, s2 = p & 63;
        double g = 0.0;
        if (t < s2 && s2 < nbsz){
            for (int r = b + s2 + 1; r < n; ++r) g += V[(size_t)r*64 + t]*V[(size_t)r*64 + s2];
        }
        G[t][s2] = g;
    }
    __syncthreads();
    for (int t = nbsz - 1; t >= 0; --t){
        for (int u = tid; u < nbsz; u += 256){
            if (u == t) T[t*64 + u] = tau[b + t];
            else if (u > t){
                double s = 0.0;
                for (int s2 = t + 1; s2 <= u; ++s2) s += G[t][s2]*T[s2*64 + u];
                T[t*64 + u] = -tau[b + t]*s;
            } else T[t*64 + u] = 0.0;
        }
        __syncthreads();
    }
}

// ============================ host dispatch helpers ============================
static void gemmf32(hipStream_t st, int epi,
                    const float* A, const float* B, float* C, int M, int N, int K,
                    const float* bias, const float* D)
{
    if ((K & 15) == 0 && (N & 7) == 0){
        dim3 g((N + 127)/128, (M + 127)/128), b(256);
        switch (epi){
        case EPI_NONE:      gemm128<EPI_NONE><<<g, b, 0, st>>>(A, B, C, M, N, K, bias, D); break;
        case EPI_BIAS:      gemm128<EPI_BIAS><<<g, b, 0, st>>>(A, B, C, M, N, K, bias, D); break;
        case EPI_BIAS_ADD:  gemm128<EPI_BIAS_ADD><<<g, b, 0, st>>>(A, B, C, M, N, K, bias, D); break;
        case EPI_ABS_DIAG1: gemm128<EPI_ABS_DIAG1><<<g, b, 0, st>>>(A, B, C, M, N, K, bias, D); break;
        case EPI_RELU:      gemm128<EPI_RELU><<<g, b, 0, st>>>(A, B, C, M, N, K, bias, D); break;
        }
    } else {
        dim3 g((N + 63)/64, (M + 63)/64), b(256);
        switch (epi){
        case EPI_NONE:      gemm32<EPI_NONE><<<g, b, 0, st>>>(A, B, C, M, N, K, bias, D); break;
        case EPI_BIAS:      gemm32<EPI_BIAS><<<g, b, 0, st>>>(A, B, C, M, N, K, bias, D); break;
        case EPI_BIAS_ADD:  gemm32<EPI_BIAS_ADD><<<g, b, 0, st>>>(A, B, C, M, N, K, bias, D); break;
        case EPI_ABS_DIAG1: gemm32<EPI_ABS_DIAG1><<<g, b, 0, st>>>(A, B, C, M, N, K, bias, D); break;
        case EPI_RELU:      gemm32<EPI_RELU><<<g, b, 0, st>>>(A, B, C, M, N, K, bias, D); break;
        }
    }
}

static void gemmf64(hipStream_t st, bool tra,
                    const double* A, int lda, const double* B, int ldb,
                    double* C, int ldc, int M, int N, int K, double alpha, double beta)
{
    dim3 g((N + 63)/64, (M + 63)/64), b(256);
    if (tra) gemm64b<true ><<<g, b, 0, st>>>(A, lda, B, ldb, C, ldc, M, N, K, alpha, beta);
    else     gemm64b<false><<<g, b, 0, st>>>(A, lda, B, ldb, C, ldc, M, N, K, alpha, beta);
}

// ============================ kernel_launch ============================
extern "C" void kernel_launch(void* const* d_in, const int* in_sizes, int n_in,
                              void* d_out, int out_size, void* d_ws, size_t ws_size,
                              hipStream_t stream)
{
    (void)in_sizes; (void)n_in; (void)out_size; (void)ws_size;
    const float* lr       = (const float*)d_in[0];
    const float* gsr_w    = (const float*)d_in[1];
    const float* start_w  = (const float*)d_in[2];
    const float* start_b  = (const float*)d_in[3];
    const float* down_w   = (const float*)d_in[4];
    const float* down_b   = (const float*)d_in[5];
    const float* pool_w   = (const float*)d_in[6];
    const float* pool_b   = (const float*)d_in[7];
    const float* bottom_w = (const float*)d_in[8];
    const float* bottom_b = (const float*)d_in[9];
    const float* end_w    = (const float*)d_in[10];
    const float* end_b    = (const float*)d_in[11];
    const float* up_w     = (const float*)d_in[12];
    const float* up_b     = (const float*)d_in[13];
    const float* gc1      = (const float*)d_in[14];
    const float* gc2      = (const float*)d_in[15];

    float* out_z     = (float*)d_out;                       // [2048,2048]
    float* out_net   = out_z + (size_t)HRD*HRD;             // [1024,2048]
    float* out_start = out_net + (size_t)NN*HRD;            // [1024,320]
    float* out_adj   = out_start + (size_t)NN*DIMF;         // [2048,2048]

    static const int LVL_N[4] = {1024, 921, 644, 386};
    static const int LVL_K[4] = {921, 644, 386, 193};

    // -------- workspace arena --------
    char* Wb = (char*)d_ws;
    size_t off = 0;
    auto alloc = [&](size_t bb)->char*{ char* p = Wb + off; off = (off + bb + 255) & ~(size_t)255; return p; };

    float*  A32  = (float*) alloc((size_t)NN*NN*4);
    double* A64  = (double*)alloc((size_t)NN*NN*8);
    float*  UfT  = (float*) alloc((size_t)NN*NN*4);   // U^T as [k][j] fp32
    double* r64  = (double*)alloc(NN*8);
    double* dD   = (double*)alloc(NN*8);
    double* dE   = (double*)alloc(NN*8);
    double* dTau = (double*)alloc(NN*8);
    double* dScl = (double*)alloc(NN*8);
    double* dWev = (double*)alloc(NN*8);
    double* pbuf = (double*)alloc(NN*8);
    double* pvA  = (double*)alloc(NN*8);
    unsigned* barcnt = (unsigned*)alloc(256);
    double* Tm   = (double*)alloc(64*64*8);
    double* Vp   = (double*)alloc((size_t)NN*64*8);
    double* Yt   = (double*)alloc((size_t)64*NN*8);
    double* W2   = (double*)alloc((size_t)64*NN*8);
    char* SBASE = Wb + off;

    // P2 overlay (U-Net)
    size_t so = 0;
    auto salloc = [&](size_t bb)->char*{ char* p = SBASE + so; so = (so + bb + 255) & ~(size_t)255; return p; };
    float* XT  = (float*)salloc((size_t)NN*DIMF*4);
    float* XP1 = (float*)salloc((size_t)NN*DIMF*4);
    float* XP2 = (float*)salloc((size_t)NN*DIMF*4);
    float* XU  = (float*)salloc((size_t)NN*DIMF*4);
    float* DN[4]; for (int l = 0; l < 4; ++l) DN[l] = (float*)salloc((size_t)NN*DIMF*4);
    float* Asub[4];
    for (int l = 0; l < 4; ++l) Asub[l] = (float*)salloc((size_t)LVL_K[l]*LVL_K[l]*4);
    float* SC = (float*)salloc(NN*4);
    int*   IDX[4]; for (int l = 0; l < 4; ++l) IDX[l] = (int*)salloc(NN*4);
    float* VAL[4]; for (int l = 0; l < 4; ++l) VAL[l] = (float*)salloc(NN*4);
    float* XC  = (float*)salloc((size_t)NN*2*DIMF*4);
    float* AXC = (float*)salloc((size_t)NN*2*DIMF*4);

    // P3 overlay (eigensolver scratch)
    const size_t PL = (size_t)NN*NN*8;
    double* Z64 = (double*)(SBASE);
    double* FD  = (double*)(SBASE + PL);
    double* FL  = (double*)(SBASE + 2*PL);
    double* FU  = (double*)(SBASE + 3*PL);
    double* FU2 = (double*)(SBASE + 4*PL);
    signed char* FPIV = (signed char*)(SBASE + 5*PL);

    // P4 overlay (GSR / refinement)
    const size_t MB8  = (size_t)HRD*NN*4;    // 8 MiB
    const size_t MB16 = (size_t)HRD*HRD*4;   // 16 MiB
    float* P4a   = (float*)(SBASE);               // [2048,1024]
    float* P4t1  = (float*)(SBASE + MB8);         // [2048,1024]
    float* P4adT = (float*)(SBASE);               // [2048,2048]
    float* P4Zb  = (float*)(SBASE + MB16);        // [2048,2048]
    float* P4ZG  = (float*)(SBASE);               // [2048,1024]
    float* P4h1  = (float*)(SBASE + MB8);         // [2048,1024]
    float* P4HG  = (float*)(SBASE + MB16);        // [2048,2048]
    float* P4h2  = (float*)(SBASE);               // [2048,2048]

    // =============== P1: normalized adjacency ===============
    rowsum_rsqrt_k<<<NN, 256, 0, stream>>>(lr, r64, NN);
    build_A_k<<<(NN*NN + 255)/256, 256, 0, stream>>>(lr, r64, A32, A64, NN);

    // =============== P2: graph U-Net (fp32) ===============
    gemmf32(stream, EPI_BIAS, A32, start_w, out_start, NN, DIMF, NN, start_b, nullptr);

    const float* Xcur = out_start;
    const float* Acur = A32;
    float* ping = XP1; float* pong = XP2;
    for (int l = 0; l < 4; ++l){
        int nl = LVL_N[l], kl = LVL_K[l];
        gemmf32(stream, EPI_NONE, Acur, Xcur, XT, nl, DIMF, nl, nullptr, nullptr);
        gemmf32(stream, EPI_BIAS, XT, down_w + (size_t)l*DIMF*DIMF, DN[l], nl, DIMF, DIMF,
                down_b + (size_t)l*DIMF, nullptr);
        score_k<<<(nl + 3)/4, 256, 0, stream>>>(DN[l], pool_w + (size_t)l*DIMF, pool_b + l, SC, nl, DIMF);
        topk_k<<<1, 256, 0, stream>>>(SC, nl, kl, IDX[l], VAL[l]);
        gatherX_k<<<(unsigned)(((size_t)kl*DIMF + 255)/256), 256, 0, stream>>>(DN[l], IDX[l], VAL[l], ping, kl, DIMF);
        gatherA_k<<<(unsigned)(((size_t)kl*kl + 255)/256), 256, 0, stream>>>(Acur, IDX[l], Asub[l], kl, nl);
        Xcur = ping; Acur = Asub[l];
        float* t = ping; ping = pong; pong = t;
    }
    gemmf32(stream, EPI_NONE, Acur, Xcur, XT, 193, DIMF, 193, nullptr, nullptr);
    float* Xb = ping;
    gemmf32(stream, EPI_BIAS, XT, bottom_w, Xb, 193, DIMF, DIMF, bottom_b, nullptr);
    const float* Xup = Xb;
    float* upbuf[2] = { (Xb == XP1) ? XP2 : XP1, (Xb == XP1) ? XP1 : XP2 };
    for (int i2 = 0; i2 < 4; ++i2){
        int jl = 3 - i2;
        int nj = LVL_N[jl];
        int kj = LVL_K[jl];
        fill0_k<<<(unsigned)(((size_t)nj*DIMF + 255)/256), 256, 0, stream>>>(XU, (size_t)nj*DIMF);
        scatterX_k<<<(unsigned)(((size_t)kj*DIMF + 255)/256), 256, 0, stream>>>(Xup, IDX[jl], XU, kj, DIMF);
        const float* Aj = (jl == 0) ? A32 : Asub[jl - 1];
        gemmf32(stream, EPI_NONE, Aj, XU, XT, nj, DIMF, nj, nullptr, nullptr);
        float* Xn = upbuf[i2 & 1];
        gemmf32(stream, EPI_BIAS_ADD, XT, up_w + (size_t)i2*DIMF*DIMF, Xn, nj, DIMF, DIMF,
                up_b + (size_t)i2*DIMF, DN[jl]);
        Xup = Xn;
    }
    concat_k<<<(unsigned)(((size_t)NN*2*DIMF + 255)/256), 256, 0, stream>>>(Xup, out_start, XC, NN, DIMF);
    gemmf32(stream, EPI_NONE, A32, XC, AXC, NN, 2*DIMF, NN, nullptr, nullptr);
    gemmf32(stream, EPI_BIAS, AXC, end_w, out_net, NN, HRD, 2*DIMF, end_b, nullptr);

    // =============== P3: eigendecomposition of A (fp64) ===============
    init_sync_k<<<4, 256, 0, stream>>>(pvA, barcnt, NN);
    sytrd_coop<<<CB, 256, 0, stream>>>(A64, dE, dTau, dScl, pbuf, pvA, barcnt, NN, NN - TB);
    hh_tail<<<1, 256, 0, stream>>>(A64, dE, dTau, dScl, NN);
    extract_de_k<<<4, 256, 0, stream>>>(A64, dD, dE, NN);
    bisect_k<<<4, 256, 0, stream>>>(dD, dE, dWev, NN);
    invit_k<<<4, 256, 0, stream>>>(dD, dE, dWev, FD, FL, FU, FU2, FPIV, Z64, NN);
    for (int g = 15; g >= 0; --g){
        int b0 = g*64;
        int nbsz = (NN - 2) - b0; if (nbsz > 64) nbsz = 64;
        build_V_k<<<(NN*64 + 255)/256, 256, 0, stream>>>(A64, dScl, Vp, NN, b0, nbsz);
        build_T_k<<<1, 256, 0, stream>>>(Vp, dTau, Tm, NN, b0, nbsz);
        int r0 = b0 + 1;
        gemmf64(stream, true,  Vp + (size_t)r0*64, 64, Z64 + (size_t)r0*NN, NN, Yt, NN, nbsz, NN, NN - r0, 1.0, 0.0);
        gemmf64(stream, false, Tm, 64, Yt, NN, W2, NN, nbsz, NN, nbsz, 1.0, 0.0);
        gemmf64(stream, false, Vp + (size_t)r0*64, 64, W2, NN, Z64 + (size_t)r0*NN, NN, NN - r0, NN, nbsz, -1.0, 1.0);
    }
    {
        dim3 g(NN/32, NN/32), b(256);
        transpose_cast_k<<<g, b, 0, stream>>>(Z64, UfT, NN);
    }

    // =============== P4: GSR layer + refinement (fp32) ===============
    build_a_k<<<(unsigned)(((size_t)HRD*NN + 255)/256), 256, 0, stream>>>(gsr_w, P4a);
    gemmf32(stream, EPI_NONE, P4a, UfT, P4t1, HRD, NN, NN, nullptr, nullptr);               // a @ U^T
    gemmf32(stream, EPI_ABS_DIAG1, P4t1, out_net, out_adj, HRD, HRD, NN, nullptr, nullptr); // adj
    {
        dim3 g(HRD/32, HRD/32), b(256);
        transpose32_k<<<g, b, 0, stream>>>(out_adj, P4adT, HRD);                            // adj^T
    }
    gemmf32(stream, EPI_NONE, out_adj, P4adT, P4Zb, HRD, HRD, HRD, nullptr, nullptr);       // adj @ adj^T
    symabs1_k<<<(unsigned)(((size_t)HRD*HRD + 255)/256), 256, 0, stream>>>(P4Zb, HRD);      // Z
    gemmf32(stream, EPI_NONE, P4Zb, gc1, P4ZG, HRD, NN, HRD, nullptr, nullptr);             // Z @ gc1
    gemmf32(stream, EPI_RELU, out_adj, P4ZG, P4h1, HRD, NN, HRD, nullptr, nullptr);         // h1
    gemmf32(stream, EPI_NONE, P4h1, gc2, P4HG, HRD, HRD, NN, nullptr, nullptr);             // h1 @ gc2
    gemmf32(stream, EPI_RELU, out_adj, P4HG, P4h2, HRD, HRD, HRD, nullptr, nullptr);        // h2
    final_z_k<<<(unsigned)(((size_t)HRD*HRD + 255)/256), 256, 0, stream>>>(P4h2, out_z, HRD); // z
}

// Round 4
// 79331.879 us; speedup vs baseline: 1.0045x; 1.0045x over previous
//
#include <hip/hip_runtime.h>
#include <cstddef>
#include <cstdint>
#include <math.h>

// ============================ constants ============================
static constexpr int NN   = 1024;   // lr_dim
static constexpr int HRD  = 2048;   // hr_dim
static constexpr int DIMF = 320;
static constexpr int TB   = 85;     // sytrd LDS tail block (85x87 fp64 = 59 KB LDS)
static constexpr int CB2  = 256;    // persistent sytrd blocks (<= CU count -> co-resident)
static constexpr int BT2  = 1024;   // threads per sytrd block (16 waves)
static constexpr int NGRP = 8;      // barrier tree groups
static constexpr int BPG  = 32;     // blocks per group (CB2 = NGRP*BPG)

#define EPI_NONE      0
#define EPI_BIAS      1
#define EPI_BIAS_ADD  2
#define EPI_ABS_DIAG1 3
#define EPI_RELU      4

// ============================ fp32 GEMM 64-tile (fallback, odd K) ============================
template<int EPI>
__global__ __launch_bounds__(256) void gemm32(
    const float* __restrict__ A, const float* __restrict__ B, float* __restrict__ C,
    int M, int N, int K, const float* __restrict__ bias, const float* __restrict__ D)
{
    __shared__ float As[16][65];
    __shared__ float Bs[16][65];
    const int bm = blockIdx.y << 6, bn = blockIdx.x << 6;
    const int tid = threadIdx.x;
    const int tm = (tid >> 4) << 2, tn = (tid & 15) << 2;
    float acc[4][4] = {};
    const int kt = (K + 15) >> 4;
    for (int k0 = 0; k0 < kt; ++k0){
        const int kb = k0 << 4;
        for (int t = tid; t < 1024; t += 256){
            int m = t >> 4, k = t & 15;
            int gm = bm + m, gk = kb + k;
            As[k][m] = (gm < M && gk < K) ? A[(size_t)gm*K + gk] : 0.f;
        }
        for (int t = tid; t < 1024; t += 256){
            int k = t >> 6, nn2 = t & 63;
            int gk = kb + k, gn = bn + nn2;
            Bs[k][nn2] = (gk < K && gn < N) ? B[(size_t)gk*N + gn] : 0.f;
        }
        __syncthreads();
        #pragma unroll
        for (int k = 0; k < 16; ++k){
            float a0 = As[k][tm], a1 = As[k][tm+1], a2 = As[k][tm+2], a3 = As[k][tm+3];
            float b0 = Bs[k][tn], b1 = Bs[k][tn+1], b2 = Bs[k][tn+2], b3 = Bs[k][tn+3];
            acc[0][0] += a0*b0; acc[0][1] += a0*b1; acc[0][2] += a0*b2; acc[0][3] += a0*b3;
            acc[1][0] += a1*b0; acc[1][1] += a1*b1; acc[1][2] += a1*b2; acc[1][3] += a1*b3;
            acc[2][0] += a2*b0; acc[2][1] += a2*b1; acc[2][2] += a2*b2; acc[2][3] += a2*b3;
            acc[3][0] += a3*b0; acc[3][1] += a3*b1; acc[3][2] += a3*b2; acc[3][3] += a3*b3;
        }
        __syncthreads();
    }
    #pragma unroll
    for (int r = 0; r < 4; ++r){
        int gm = bm + tm + r; if (gm >= M) continue;
        #pragma unroll
        for (int c = 0; c < 4; ++c){
            int gn = bn + tn + c; if (gn >= N) continue;
            float v = acc[r][c];
            if (EPI == EPI_BIAS)            v += bias[gn];
            else if (EPI == EPI_BIAS_ADD)   v += bias[gn] + D[(size_t)gm*N + gn];
            else if (EPI == EPI_ABS_DIAG1)  v = (gm == gn) ? 1.0f : fabsf(v);
            else if (EPI == EPI_RELU)       v = fmaxf(v, 0.0f);
            C[(size_t)gm*N + gn] = v;
        }
    }
}

// ============================ fp32 GEMM 128-tile (K%16==0, N%8==0) ============================
template<int EPI>
__global__ __launch_bounds__(256) void gemm128(
    const float* __restrict__ A, const float* __restrict__ B, float* __restrict__ C,
    int M, int N, int K, const float* __restrict__ bias, const float* __restrict__ D)
{
    __shared__ float As[16][132];
    __shared__ float Bs[16][132];
    const int bm = blockIdx.y << 7, bn = blockIdx.x << 7;
    const int tid = threadIdx.x;
    const int tm = (tid >> 4) << 3;
    const int tn = (tid & 15) << 3;
    const int ar = tid >> 1;
    const int ak = (tid & 1) << 3;
    const int br = tid >> 4;
    const int bc = (tid & 15) << 3;
    float acc[8][8] = {};
    for (int kb = 0; kb < K; kb += 16){
        {
            int gm = bm + ar, gk = kb + ak;
            float4 a0, a1;
            if (gm < M){
                const float* p = A + (size_t)gm*K + gk;
                a0 = *(const float4*)p; a1 = *(const float4*)(p + 4);
            } else { a0 = make_float4(0.f,0.f,0.f,0.f); a1 = a0; }
            As[ak+0][ar]=a0.x; As[ak+1][ar]=a0.y; As[ak+2][ar]=a0.z; As[ak+3][ar]=a0.w;
            As[ak+4][ar]=a1.x; As[ak+5][ar]=a1.y; As[ak+6][ar]=a1.z; As[ak+7][ar]=a1.w;
        }
        {
            int gk = kb + br, gn = bn + bc;
            float4 b0, b1;
            if (gn + 7 < N){
                const float* p = B + (size_t)gk*N + gn;
                b0 = *(const float4*)p; b1 = *(const float4*)(p + 4);
            } else {
                float t0[8];
                #pragma unroll
                for (int i = 0; i < 8; ++i){ int g = gn + i; t0[i] = (g < N) ? B[(size_t)gk*N + g] : 0.f; }
                b0 = make_float4(t0[0],t0[1],t0[2],t0[3]); b1 = make_float4(t0[4],t0[5],t0[6],t0[7]);
            }
            *(float4*)&Bs[br][bc] = b0; *(float4*)&Bs[br][bc+4] = b1;
        }
        __syncthreads();
        #pragma unroll
        for (int k = 0; k < 16; ++k){
            float4 a0 = *(const float4*)&As[k][tm];
            float4 a1 = *(const float4*)&As[k][tm+4];
            float4 b0 = *(const float4*)&Bs[k][tn];
            float4 b1 = *(const float4*)&Bs[k][tn+4];
            float av[8] = {a0.x,a0.y,a0.z,a0.w,a1.x,a1.y,a1.z,a1.w};
            float bv[8] = {b0.x,b0.y,b0.z,b0.w,b1.x,b1.y,b1.z,b1.w};
            #pragma unroll
            for (int i = 0; i < 8; ++i)
                #pragma unroll
                for (int jj = 0; jj < 8; ++jj) acc[i][jj] += av[i]*bv[jj];
        }
        __syncthreads();
    }
    #pragma unroll
    for (int i = 0; i < 8; ++i){
        int gm = bm + tm + i; if (gm >= M) continue;
        #pragma unroll
        for (int jj = 0; jj < 8; ++jj){
            int gn = bn + tn + jj; if (gn >= N) continue;
            float v = acc[i][jj];
            if (EPI == EPI_BIAS)            v += bias[gn];
            else if (EPI == EPI_BIAS_ADD)   v += bias[gn] + D[(size_t)gm*N + gn];
            else if (EPI == EPI_ABS_DIAG1)  v = (gm == gn) ? 1.0f : fabsf(v);
            else if (EPI == EPI_RELU)       v = fmaxf(v, 0.0f);
            C[(size_t)gm*N + gn] = v;
        }
    }
}

// ============================ fp64 GEMM 64-tile, 4x4 micro ============================
template<bool TRA>
__global__ __launch_bounds__(256) void gemm64b(
    const double* __restrict__ A, int lda, const double* __restrict__ B, int ldb,
    double* __restrict__ C, int ldc, int M, int N, int K, double alpha, double beta)
{
    __shared__ double As[16][66];
    __shared__ double Bs[16][66];
    const int bm = blockIdx.y << 6, bn = blockIdx.x << 6;
    const int tid = threadIdx.x;
    const int tm = (tid >> 4) << 2, tn = (tid & 15) << 2;
    double acc[4][4] = {};
    for (int kb = 0; kb < K; kb += 16){
        if (!TRA){
            for (int t = tid; t < 1024; t += 256){
                int m = t >> 4, k = t & 15;
                int gm = bm + m, gk = kb + k;
                As[k][m] = (gm < M && gk < K) ? A[(size_t)gm*lda + gk] : 0.0;
            }
        } else {
            for (int t = tid; t < 1024; t += 256){
                int k = t >> 6, m = t & 63;
                int gm = bm + m, gk = kb + k;
                As[k][m] = (gm < M && gk < K) ? A[(size_t)gk*lda + gm] : 0.0;
            }
        }
        for (int t = tid; t < 1024; t += 256){
            int k = t >> 6, nn2 = t & 63;
            int gk = kb + k, gn = bn + nn2;
            Bs[k][nn2] = (gk < K && gn < N) ? B[(size_t)gk*ldb + gn] : 0.0;
        }
        __syncthreads();
        #pragma unroll
        for (int k = 0; k < 16; ++k){
            double a0=As[k][tm],a1=As[k][tm+1],a2=As[k][tm+2],a3=As[k][tm+3];
            double b0=Bs[k][tn],b1=Bs[k][tn+1],b2=Bs[k][tn+2],b3=Bs[k][tn+3];
            acc[0][0]+=a0*b0; acc[0][1]+=a0*b1; acc[0][2]+=a0*b2; acc[0][3]+=a0*b3;
            acc[1][0]+=a1*b0; acc[1][1]+=a1*b1; acc[1][2]+=a1*b2; acc[1][3]+=a1*b3;
            acc[2][0]+=a2*b0; acc[2][1]+=a2*b1; acc[2][2]+=a2*b2; acc[2][3]+=a2*b3;
            acc[3][0]+=a3*b0; acc[3][1]+=a3*b1; acc[3][2]+=a3*b2; acc[3][3]+=a3*b3;
        }
        __syncthreads();
    }
    #pragma unroll
    for (int r = 0; r < 4; ++r){
        int gm = bm + tm + r; if (gm >= M) continue;
        #pragma unroll
        for (int c = 0; c < 4; ++c){
            int gn = bn + tn + c; if (gn >= N) continue;
            double v = alpha*acc[r][c];
            if (beta != 0.0) v += beta*C[(size_t)gm*ldc + gn];
            C[(size_t)gm*ldc + gn] = v;
        }
    }
}

// ============================ small kernels ============================
__global__ __launch_bounds__(256) void rowsum_rsqrt_k(const float* __restrict__ lr, double* __restrict__ r64, int n)
{
    __shared__ double sm[256];
    int row = blockIdx.x;
    double s = 0.0;
    for (int j = threadIdx.x; j < n; j += 256) s += (double)lr[(size_t)row*n + j];
    sm[threadIdx.x] = s; __syncthreads();
    for (int o = 128; o; o >>= 1){ if (threadIdx.x < o) sm[threadIdx.x] += sm[threadIdx.x + o]; __syncthreads(); }
    if (threadIdx.x == 0){
        double t = sm[0];
        r64[row] = (t > 0.0) ? 1.0/sqrt(t) : 0.0;
    }
}

__global__ __launch_bounds__(256) void build_A_k(const float* __restrict__ lr, const double* __restrict__ r64,
                                                 float* __restrict__ A32, double* __restrict__ A64, int n)
{
    size_t idx = (size_t)blockIdx.x*256 + threadIdx.x;
    if (idx >= (size_t)n*n) return;
    int i = (int)(idx / n), j = (int)(idx % n);
    if (j < i) return;
    double v = (double)lr[(size_t)j*n + i] * r64[i] * r64[j];
    A64[(size_t)i*n + j] = v; A64[(size_t)j*n + i] = v;
    float vf = (float)v;
    A32[(size_t)i*n + j] = vf; A32[(size_t)j*n + i] = vf;
}

__global__ __launch_bounds__(256) void score_k(const float* __restrict__ X, const float* __restrict__ pw,
                                               const float* __restrict__ pb, float* __restrict__ out,
                                               int n, int dim)
{
    int row = blockIdx.x*4 + (threadIdx.x >> 6);
    int lane = threadIdx.x & 63;
    if (row >= n) return;
    float acc = 0.f;
    for (int c = lane; c < dim; c += 64) acc += X[(size_t)row*dim + c]*pw[c];
    #pragma unroll
    for (int o = 32; o; o >>= 1) acc += __shfl_down(acc, o);
    if (lane == 0){
        float t = (acc + pb[0]) * 0.01f;
        out[row] = 1.0f/(1.0f + expf(-t));
    }
}

// jax.lax.top_k semantics: descending value, ties -> lower index first
__global__ __launch_bounds__(256) void topk_k(const float* __restrict__ scores, int n, int k,
                                              int* __restrict__ idxo, float* __restrict__ valo)
{
    __shared__ float s[1024];
    int tid = threadIdx.x;
    for (int i = tid; i < n; i += 256) s[i] = scores[i];
    __syncthreads();
    for (int i = tid; i < n; i += 256){
        float si = s[i]; int r = 0;
        for (int j = 0; j < n; ++j){
            float sj = s[j];
            r += (sj > si) || (sj == si && j < i);
        }
        if (r < k){ idxo[r] = i; valo[r] = si; }
    }
}

__global__ __launch_bounds__(256) void gatherX_k(const float* __restrict__ X, const int* __restrict__ idx,
                                                 const float* __restrict__ vals, float* __restrict__ Xo,
                                                 int k, int dim)
{
    size_t t = (size_t)blockIdx.x*256 + threadIdx.x;
    if (t >= (size_t)k*dim) return;
    int m = (int)(t / dim), c = (int)(t % dim);
    Xo[t] = X[(size_t)idx[m]*dim + c] * vals[m];
}

__global__ __launch_bounds__(256) void scatterX_k(const float* __restrict__ Xs, const int* __restrict__ idx,
                                                  float* __restrict__ Xu, int k, int dim)
{
    size_t t = (size_t)blockIdx.x*256 + threadIdx.x;
    if (t >= (size_t)k*dim) return;
    int m = (int)(t / dim), c = (int)(t % dim);
    Xu[(size_t)idx[m]*dim + c] = Xs[t];
}

__global__ __launch_bounds__(256) void gatherA_k(const float* __restrict__ A, const int* __restrict__ idx,
                                                 float* __restrict__ Ao, int k, int n)
{
    size_t t = (size_t)blockIdx.x*256 + threadIdx.x;
    if (t >= (size_t)k*k) return;
    int m1 = (int)(t / k), m2 = (int)(t % k);
    Ao[t] = A[(size_t)idx[m1]*n + idx[m2]];
}

__global__ __launch_bounds__(256) void fill0_k(float* __restrict__ p, size_t cnt)
{
    size_t t = (size_t)blockIdx.x*256 + threadIdx.x;
    if (t < cnt) p[t] = 0.f;
}

__global__ __launch_bounds__(256) void init_sytrd_k(double* __restrict__ sig, double* __restrict__ pv,
                                                    unsigned* __restrict__ bar, int n)
{
    int t = blockIdx.x*256 + threadIdx.x;
    if (t < n){ sig[t] = 0.0; pv[t] = 0.0; }
    if (t < 1024) bar[t] = 0u;
}

__global__ __launch_bounds__(256) void concat_k(const float* __restrict__ X, const float* __restrict__ orgX,
                                                float* __restrict__ Xc, int n, int dim)
{
    size_t t = (size_t)blockIdx.x*256 + threadIdx.x;
    size_t tot = (size_t)n*2*dim;
    if (t >= tot) return;
    int i = (int)(t / (2*dim)), c = (int)(t % (2*dim));
    Xc[t] = (c < dim) ? X[(size_t)i*dim + c] : orgX[(size_t)i*dim + (c - dim)];
}

__global__ __launch_bounds__(256) void build_a_k(const float* __restrict__ gsr, float* __restrict__ a)
{
    size_t idx = (size_t)blockIdx.x*256 + threadIdx.x;
    if (idx >= (size_t)HRD*NN) return;
    int i = (int)(idx >> 10), k = (int)(idx & 1023);
    a[idx] = gsr[(size_t)i*HRD + k] + gsr[(size_t)i*HRD + NN + k];
}

__global__ __launch_bounds__(256) void symabs1_k(float* __restrict__ Z, int n)
{
    size_t idx = (size_t)blockIdx.x*256 + threadIdx.x;
    if (idx >= (size_t)n*n) return;
    int i = (int)(idx / n), j = (int)(idx % n);
    if (i > j) return;
    float a = Z[(size_t)i*n + j], b = Z[(size_t)j*n + i];
    float v = 0.5f*(a + b);
    float o = (i == j) ? 1.0f : fabsf(v);
    Z[(size_t)i*n + j] = o; Z[(size_t)j*n + i] = o;
}

__global__ __launch_bounds__(256) void final_z_k(const float* __restrict__ h2, float* __restrict__ z, int n)
{
    size_t idx = (size_t)blockIdx.x*256 + threadIdx.x;
    if (idx >= (size_t)n*n) return;
    int i = (int)(idx / n), j = (int)(idx % n);
    if (i > j) return;
    float v = 0.5f*(h2[(size_t)i*n + j] + h2[(size_t)j*n + i]);
    float o = (i == j) ? 1.0f : fabsf(v);
    z[(size_t)i*n + j] = o; z[(size_t)j*n + i] = o;
}

// dst[c][r] = (float)src[r][c]   (n x n, n % 32 == 0)
__global__ __launch_bounds__(256) void transpose_cast_k(const double* __restrict__ src, float* __restrict__ dst, int n)
{
    __shared__ float tile[32][33];
    int r0 = blockIdx.y*32, c0 = blockIdx.x*32;
    int tx = threadIdx.x & 31, ty = threadIdx.x >> 5;
    for (int i = ty; i < 32; i += 8)
        tile[i][tx] = (float)src[(size_t)(r0 + i)*n + (c0 + tx)];
    __syncthreads();
    for (int i = ty; i < 32; i += 8)
        dst[(size_t)(c0 + i)*n + (r0 + tx)] = tile[tx][i];
}

// dst[c][r] = src[r][c]  (n x n, n % 32 == 0)
__global__ __launch_bounds__(256) void transpose32_k(const float* __restrict__ src, float* __restrict__ dst, int n)
{
    __shared__ float tile[32][33];
    int r0 = blockIdx.y*32, c0 = blockIdx.x*32;
    int tx = threadIdx.x & 31, ty = threadIdx.x >> 5;
    for (int i = ty; i < 32; i += 8)
        tile[i][tx] = src[(size_t)(r0 + i)*n + (c0 + tx)];
    __syncthreads();
    for (int i = ty; i < 32; i += 8)
        dst[(size_t)(c0 + i)*n + (r0 + tx)] = tile[tx][i];
}

// ============================ persistent Householder tridiagonalization ============================
// Two-level grid barrier: NGRP group counters (one cache line apart) + root counter.
// All CB2 blocks co-resident (256 blocks <= 256 CUs at 16 waves/block).
__device__ __forceinline__ void gbar2(unsigned* __restrict__ bar, unsigned epoch)
{
    __syncthreads();
    if (threadIdx.x == 0){
        __threadfence();  // release: drain writes to agent scope
        int g = blockIdx.x >> 5;  // / BPG
        unsigned t = __hip_atomic_fetch_add(&bar[g*32], 1u, __ATOMIC_ACQ_REL, __HIP_MEMORY_SCOPE_AGENT);
        if ((t & (unsigned)(BPG - 1)) == (unsigned)(BPG - 1))
            __hip_atomic_fetch_add(&bar[256], 1u, __ATOMIC_ACQ_REL, __HIP_MEMORY_SCOPE_AGENT);
        unsigned target = epoch * (unsigned)NGRP;
        while (__hip_atomic_load(&bar[256], __ATOMIC_ACQUIRE, __HIP_MEMORY_SCOPE_AGENT) < target)
            __builtin_amdgcn_s_sleep(8);
        __threadfence();  // acquire: invalidate stale lines
    }
    __syncthreads();
}

// Fused one-column-delayed sytrd:
//   phase A (column j): apply pending (v_{j-1}, w_{j-1}) update to ROW j on the fly,
//     store corrected unscaled column into row j, reduce sigma2; also zero p_cur.
//   phase B: all blocks redundantly compute beta/tau/sc; each wave-quartet owns a
//     trailing row: applies the pending rank-2 update element-wise (single rw pass)
//     and dots the UPDATED row with v_j; p via 4-chunk fp64 atomics; pv reduced.
// v_j stored unscaled in row j (v[0]=1 implied, v[i]=row[i]*scl[j]); w never materialized
// (recomputed as tau*p - c2*v from the p ping-pong buffers).
__global__ __launch_bounds__(BT2) void sytrd_coop2(
    double* __restrict__ A, double* __restrict__ e, double* __restrict__ tauA,
    double* __restrict__ sclA, double* __restrict__ p0, double* __restrict__ p1,
    double* __restrict__ pvA, double* __restrict__ sigA,
    unsigned* __restrict__ bar, int n, int jend)
{
    __shared__ double red[BT2];
    const int tid  = threadIdx.x;
    const int bid  = blockIdx.x;
    const int lane = tid & 63;
    const int gw   = bid*(BT2/64) + (tid >> 6);   // 0..4095
    const unsigned gtid = (unsigned)bid*(unsigned)BT2 + (unsigned)tid;
    const unsigned NT   = (unsigned)CB2*(unsigned)BT2;
    const int rowUnit = gw >> 2;                  // 0..1023  (>= max m)
    const int chunk   = gw & 3;

    double tau_p = 0.0, sc_p = 0.0, c2_p = 0.0;
    unsigned ep = 0;

    for (int j = 0; j < jend; ++j){
        const int m = n - 1 - j;
        double* __restrict__ row        = A + (size_t)j*n + (j+1);
        const double* __restrict__ rowp = A + (size_t)(j-1)*n + j;   // valid for j>0
        const double* __restrict__ pp   = (((j+1) & 1) ? p1 : p0);   // p of column j-1
        double* __restrict__ pc         = ((j & 1) ? p1 : p0);       // p of column j
        // ---------------- phase A ----------------
        for (unsigned r = gtid; r < (unsigned)m; r += NT) pc[r] = 0.0;
        double s = 0.0;
        if (j > 0){
            double wp0 = tau_p*pp[0] - c2_p;   // w_p at row j (v_p[0] = 1)
            for (unsigned c = 1u + gtid; c < (unsigned)m; c += NT){
                double vpc = rowp[c+1]*sc_p;
                double wpc = tau_p*pp[c+1] - c2_p*vpc;
                double x = row[c] - wpc - wp0*vpc;
                row[c] = x;
                s += x*x;
            }
            if (gtid == 0){
                double vp1 = rowp[1]*sc_p;
                double wp1 = tau_p*pp[1] - c2_p*vp1;
                row[0] -= wp1 + wp0*vp1;            // alpha
                A[(size_t)j*n + j] -= 2.0*wp0;      // diagonal d[j]
            }
        } else {
            for (unsigned c = 1u + gtid; c < (unsigned)m; c += NT){
                double x = row[c]; s += x*x;
            }
        }
        red[tid] = s; __syncthreads();
        #pragma unroll
        for (int o = BT2/2; o; o >>= 1){ if (tid < o) red[tid] += red[tid + o]; __syncthreads(); }
        if (tid == 0 && red[0] != 0.0) atomicAdd(&sigA[j], red[0]);
        ++ep; gbar2(bar, ep);
        // ---------------- phase B ----------------
        double sigma2 = sigA[j];
        double alpha = row[0];
        double beta, tl, sc;
        if (sigma2 == 0.0){ beta = alpha; tl = 0.0; sc = 0.0; }
        else {
            beta = -copysign(sqrt(alpha*alpha + sigma2), alpha);
            tl = (beta - alpha)/beta;
            sc = 1.0/(alpha - beta);
        }
        if (bid == 0 && tid == 0){ e[j] = beta; tauA[j] = tl; sclA[j] = sc; }
        double pvloc = 0.0;
        if (rowUnit < m){
            const int r = rowUnit;
            double* __restrict__ Ar = A + (size_t)(j+1+r)*n + (j+1);
            double acc = 0.0;
            if (j > 0){
                double vpr = rowp[r+1]*sc_p;
                double wpr = tau_p*pp[r+1] - c2_p*vpr;
                for (int c = chunk*64 + lane; c < m; c += 256){
                    double vpc = rowp[c+1]*sc_p;
                    double wpc = tau_p*pp[c+1] - c2_p*vpc;
                    double a = Ar[c] - (vpr*wpc + wpr*vpc);
                    Ar[c] = a;
                    double vj = (c == 0) ? 1.0 : row[c]*sc;
                    acc += a*vj;
                }
            } else {
                for (int c = chunk*64 + lane; c < m; c += 256){
                    double a = Ar[c];
                    double vj = (c == 0) ? 1.0 : row[c]*sc;
                    acc += a*vj;
                }
            }
            #pragma unroll
            for (int o = 32; o; o >>= 1) acc += __shfl_down(acc, o);
            if (lane == 0){
                atomicAdd(&pc[r], acc);
                double vr = (r == 0) ? 1.0 : row[r]*sc;
                pvloc = acc*vr;
            }
        }
        red[tid] = (lane == 0) ? pvloc : 0.0; __syncthreads();
        #pragma unroll
        for (int o = BT2/2; o; o >>= 1){ if (tid < o) red[tid] += red[tid + o]; __syncthreads(); }
        if (tid == 0 && red[0] != 0.0) atomicAdd(&pvA[j], red[0]);
        ++ep; gbar2(bar, ep);
        tau_p = tl; sc_p = sc; c2_p = 0.5*tl*tl*pvA[j];
    }
    // ------- apply final pending update (column jend-1) on the TB x TB tail -------
    {
        const double* __restrict__ rowp = A + (size_t)(jend-1)*n + jend;
        const double* __restrict__ pp   = (((jend+1) & 1) ? p1 : p0);
        const int tb = n - jend;
        const unsigned tot = (unsigned)(tb*tb);
        for (unsigned idx = gtid; idx < tot; idx += NT){
            int ri = (int)(idx / (unsigned)tb), ci = (int)(idx % (unsigned)tb);
            double vpr = (ri == 0) ? 1.0 : rowp[ri]*sc_p;
            double wpr = tau_p*pp[ri] - c2_p*vpr;
            double vpc = (ci == 0) ? 1.0 : rowp[ci]*sc_p;
            double wpc = tau_p*pp[ci] - c2_p*vpc;
            A[(size_t)(jend+ri)*n + (jend+ci)] -= vpr*wpc + wpr*vpc;
        }
    }
}

// Tail: remaining (TB-2) Householder steps entirely in LDS (single block).
__global__ __launch_bounds__(256) void hh_tail(double* __restrict__ A64, double* __restrict__ e,
                                               double* __restrict__ tau, double* __restrict__ scaleg, int n)
{
    __shared__ double T[TB][TB+2];
    __shared__ double v[TB], p[TB], red[256];
    const int base = n - TB;
    const int tid = threadIdx.x;
    for (int t = tid; t < TB*TB; t += 256){
        int r = t / TB, c = t % TB;
        T[r][c] = A64[(size_t)(base + r)*n + base + c];
    }
    __syncthreads();
    for (int l = 0; l <= TB - 3; ++l){
        const int m = TB - 1 - l;
        double s = 0.0;
        for (int i = 1 + tid; i < m; i += 256){ double x = T[l+1+i][l]; s += x*x; }
        red[tid] = s; __syncthreads();
        for (int o = 128; o; o >>= 1){ if (tid < o) red[tid] += red[tid + o]; __syncthreads(); }
        double sigma2 = red[0];
        double alpha = T[l+1][l];
        double beta, tl, sc;
        if (sigma2 == 0.0){ beta = alpha; tl = 0.0; sc = 0.0; }
        else {
            beta = -copysign(sqrt(alpha*alpha + sigma2), alpha);
            tl = (beta - alpha)/beta;
            sc = 1.0/(alpha - beta);
        }
        for (int i = tid; i < m; i += 256) v[i] = (i == 0) ? 1.0 : T[l+1+i][l]*sc;
        __syncthreads();
        for (int i = tid; i < m; i += 256){
            double acc = 0.0;
            for (int c = 0; c < m; ++c) acc += T[l+1+i][l+1+c]*v[c];
            p[i] = acc;
        }
        __syncthreads();
        double s2 = 0.0;
        for (int i = tid; i < m; i += 256) s2 += p[i]*v[i];
        red[tid] = s2; __syncthreads();
        for (int o = 128; o; o >>= 1){ if (tid < o) red[tid] += red[tid + o]; __syncthreads(); }
        double pvv = red[0];
        double c2 = 0.5*tl*tl*pvv;
        for (int t2 = tid; t2 < m*m; t2 += 256){
            int r = t2 / m, c = t2 % m;
            double wr = tl*p[r] - c2*v[r];
            double wc = tl*p[c] - c2*v[c];
            T[l+1+r][l+1+c] -= v[r]*wc + wr*v[c];
        }
        if (tid == 0){ int j = base + l; e[j] = beta; tau[j] = tl; scaleg[j] = 1.0; }
        for (int i = tid; i < m; i += 256) A64[(size_t)(base + l)*n + (base + l + 1) + i] = v[i];
        __syncthreads();
    }
    for (int r = tid; r < TB; r += 256) A64[(size_t)(base + r)*n + base + r] = T[r][r];
    if (tid == 0) A64[(size_t)(n-1)*n + (n-2)] = T[TB-1][TB-2];
}

__global__ __launch_bounds__(256) void extract_de_k(const double* __restrict__ A64, double* __restrict__ d,
                                                    double* __restrict__ e, int n)
{
    int i = blockIdx.x*256 + threadIdx.x;
    if (i < n) d[i] = A64[(size_t)i*n + i];
    if (i == 0) e[n-2] = A64[(size_t)(n-1)*n + (n-2)];
}

// ============================ tridiagonal eigensolver ============================
__global__ __launch_bounds__(256) void bisect_k(const double* __restrict__ d, const double* __restrict__ e,
                                                double* __restrict__ w, int n)
{
    int k = blockIdx.x*256 + threadIdx.x;
    if (k >= n) return;
    double gl = 1e300, gu = -1e300;
    for (int i = 0; i < n; ++i){
        double em = (i > 0) ? fabs(e[i-1]) : 0.0, ep = (i < n-1) ? fabs(e[i]) : 0.0;
        double lo2 = d[i] - em - ep, hi2 = d[i] + em + ep;
        gl = fmin(gl, lo2); gu = fmax(gu, hi2);
    }
    double lo = gl - 1e-10, hi = gu + 1e-10;
    const double pivmin = 1e-280;
    for (int it = 0; it < 42; ++it){
        double mid = 0.5*(lo + hi);
        int cnt = 0; double q = 1.0;
        for (int i = 0; i < n; ++i){
            double t;
            if (i == 0) t = d[0] - mid;
            else { double ei = e[i-1]; t = d[i] - mid - ei*(ei/q); }
            if (fabs(t) < pivmin) t = -pivmin;
            if (t < 0.0) ++cnt;
            q = t;
        }
        if (cnt <= k) lo = mid; else hi = mid;
    }
    w[k] = 0.5*(lo + hi);
}

__global__ __launch_bounds__(256) void invit_k(const double* __restrict__ d, const double* __restrict__ e,
                                               const double* __restrict__ w,
                                               double* __restrict__ FD, double* __restrict__ FL,
                                               double* __restrict__ FU, double* __restrict__ FU2,
                                               signed char* __restrict__ PIV, double* __restrict__ Z, int n)
{
    int k = blockIdx.x*256 + threadIdx.x;
    if (k >= n) return;
    const double lam = w[k];
    const double tiny = 1e-280;
    double dcur = d[0] - lam;
    double ucur = e[0];
    for (int i = 0; i < n-1; ++i){
        double dli = e[i];
        double dnext_init = d[i+1] - lam;
        double unext_init = (i < n-2) ? e[i+1] : 0.0;
        size_t o = (size_t)i*n + k;
        if (fabs(dcur) >= fabs(dli)){
            if (dcur == 0.0) dcur = tiny;
            double f = dli/dcur;
            FD[o] = dcur; FL[o] = f; FU[o] = ucur; FU2[o] = 0.0; PIV[o] = 0;
            dcur = dnext_init - f*ucur;
            ucur = unext_init;
        } else {
            double f = dcur/dli;
            FD[o] = dli; FL[o] = f; FU[o] = dnext_init; FU2[o] = unext_init; PIV[o] = 1;
            dcur = ucur - f*dnext_init;
            ucur = -f*unext_init;
        }
    }
    if (dcur == 0.0) dcur = tiny;
    FD[(size_t)(n-1)*n + k] = dcur;
    for (int i = 0; i < n; ++i){
        unsigned h = (unsigned)(i + 1)*0x9E3779B9u + (unsigned)(k + 1)*0x85EBCA6Bu;
        h ^= h >> 16; h *= 0x7FEB352Du; h ^= h >> 15; h *= 0x846CA68Bu; h ^= h >> 16;
        Z[(size_t)i*n + k] = (double)(h >> 8)*(1.0/16777216.0) - 0.5;
    }
    for (int iter = 0; iter < 2; ++iter){
        double zc = Z[k];
        for (int i = 0; i < n-1; ++i){
            size_t o = (size_t)i*n + k;
            double fl = FL[o];
            double zn = Z[o + n];
            if (!PIV[o]){
                Z[o] = zc;
                zc = zn - fl*zc;
            } else {
                Z[o] = zn;
                zc = zc - fl*zn;
            }
        }
        double za = zc / FD[(size_t)(n-1)*n + k];
        Z[(size_t)(n-1)*n + k] = za;
        size_t o2 = (size_t)(n-2)*n + k;
        double zaa = (Z[o2] - FU[o2]*za) / FD[o2];
        Z[o2] = zaa;
        double zb = za;
        for (int i = n-3; i >= 0; --i){
            size_t o = (size_t)i*n + k;
            double znew = (Z[o] - FU[o]*zaa - FU2[o]*zb) / FD[o];
            Z[o] = znew;
            zb = zaa; zaa = znew;
        }
        double mx = 0.0;
        for (int i = 0; i < n; ++i) mx = fmax(mx, fabs(Z[(size_t)i*n + k]));
        double s = (mx > 0.0) ? 1.0/mx : 1.0;
        for (int i = 0; i < n; ++i) Z[(size_t)i*n + k] *= s;
    }
    double nrm = 0.0;
    for (int i = 0; i < n; ++i){ double v = Z[(size_t)i*n + k]; nrm += v*v; }
    double s = 1.0/sqrt(nrm);
    for (int i = 0; i < n; ++i) Z[(size_t)i*n + k] *= s;
}

// ============================ blocked-WY back-transform ============================
// v_j stored in ROW j of A64 (cols j+1..): v(r)=1 at r==j+1, else A64[j][r]*scale[j]
__global__ __launch_bounds__(256) void build_V_k(const double* __restrict__ A64, const double* __restrict__ scaleg,
                                                 double* __restrict__ V, int n, int b, int nbsz)
{
    size_t idx = (size_t)blockIdx.x*256 + threadIdx.x;
    if (idx >= (size_t)n*64) return;
    int r = (int)(idx >> 6), t = (int)(idx & 63);
    double v = 0.0;
    if (t < nbsz){
        int j = b + t;
        if (r == j + 1) v = 1.0;
        else if (r > j + 1) v = A64[(size_t)j*n + r]*scaleg[j];
    }
    V[(size_t)r*64 + t] = v;
}

__global__ __launch_bounds__(256) void build_T_k(const double* __restrict__ V, const double* __restrict__ tau,
                                                 double* __restrict__ T, int n, int b, int nbsz)
{
    __shared__ double G[64][64];
    int tid = threadIdx.x;
    for (int p = tid; p < 64*64; p += 256){
        int t = p >> 6, s2 = p & 63;
        double g = 0.0;
        if (t < s2 && s2 < nbsz){
            for (int r = b + s2 + 1; r < n; ++r) g += V[(size_t)r*64 + t]*V[(size_t)r*64 + s2];
        }
        G[t][s2] = g;
    }
    __syncthreads();
    for (int t = nbsz - 1; t >= 0; --t){
        for (int u = tid; u < nbsz; u += 256){
            if (u == t) T[t*64 + u] = tau[b + t];
            else if (u > t){
                double s = 0.0;
                for (int s2 = t + 1; s2 <= u; ++s2) s += G[t][s2]*T[s2*64 + u];
                T[t*64 + u] = -tau[b + t]*s;
            } else T[t*64 + u] = 0.0;
        }
        __syncthreads();
    }
}

// ============================ host dispatch helpers ============================
static void gemmf32(hipStream_t st, int epi,
                    const float* A, const float* B, float* C, int M, int N, int K,
                    const float* bias, const float* D)
{
    if ((K & 15) == 0 && (N & 7) == 0){
        dim3 g((N + 127)/128, (M + 127)/128), b(256);
        switch (epi){
        case EPI_NONE:      gemm128<EPI_NONE><<<g, b, 0, st>>>(A, B, C, M, N, K, bias, D); break;
        case EPI_BIAS:      gemm128<EPI_BIAS><<<g, b, 0, st>>>(A, B, C, M, N, K, bias, D); break;
        case EPI_BIAS_ADD:  gemm128<EPI_BIAS_ADD><<<g, b, 0, st>>>(A, B, C, M, N, K, bias, D); break;
        case EPI_ABS_DIAG1: gemm128<EPI_ABS_DIAG1><<<g, b, 0, st>>>(A, B, C, M, N, K, bias, D); break;
        case EPI_RELU:      gemm128<EPI_RELU><<<g, b, 0, st>>>(A, B, C, M, N, K, bias, D); break;
        }
    } else {
        dim3 g((N + 63)/64, (M + 63)/64), b(256);
        switch (epi){
        case EPI_NONE:      gemm32<EPI_NONE><<<g, b, 0, st>>>(A, B, C, M, N, K, bias, D); break;
        case EPI_BIAS:      gemm32<EPI_BIAS><<<g, b, 0, st>>>(A, B, C, M, N, K, bias, D); break;
        case EPI_BIAS_ADD:  gemm32<EPI_BIAS_ADD><<<g, b, 0, st>>>(A, B, C, M, N, K, bias, D); break;
        case EPI_ABS_DIAG1: gemm32<EPI_ABS_DIAG1><<<g, b, 0, st>>>(A, B, C, M, N, K, bias, D); break;
        case EPI_RELU:      gemm32<EPI_RELU><<<g, b, 0, st>>>(A, B, C, M, N, K, bias, D); break;
        }
    }
}

static void gemmf64(hipStream_t st, bool tra,
                    const double* A, int lda, const double* B, int ldb,
                    double* C, int ldc, int M, int N, int K, double alpha, double beta)
{
    dim3 g((N + 63)/64, (M + 63)/64), b(256);
    if (tra) gemm64b<true ><<<g, b, 0, st>>>(A, lda, B, ldb, C, ldc, M, N, K, alpha, beta);
    else     gemm64b<false><<<g, b, 0, st>>>(A, lda, B, ldb, C, ldc, M, N, K, alpha, beta);
}

// ============================ kernel_launch ============================
extern "C" void kernel_launch(void* const* d_in, const int* in_sizes, int n_in,
                              void* d_out, int out_size, void* d_ws, size_t ws_size,
                              hipStream_t stream)
{
    (void)in_sizes; (void)n_in; (void)out_size; (void)ws_size;
    const float* lr       = (const float*)d_in[0];
    const float* gsr_w    = (const float*)d_in[1];
    const float* start_w  = (const float*)d_in[2];
    const float* start_b  = (const float*)d_in[3];
    const float* down_w   = (const float*)d_in[4];
    const float* down_b   = (const float*)d_in[5];
    const float* pool_w   = (const float*)d_in[6];
    const float* pool_b   = (const float*)d_in[7];
    const float* bottom_w = (const float*)d_in[8];
    const float* bottom_b = (const float*)d_in[9];
    const float* end_w    = (const float*)d_in[10];
    const float* end_b    = (const float*)d_in[11];
    const float* up_w     = (const float*)d_in[12];
    const float* up_b     = (const float*)d_in[13];
    const float* gc1      = (const float*)d_in[14];
    const float* gc2      = (const float*)d_in[15];

    float* out_z     = (float*)d_out;                       // [2048,2048]
    float* out_net   = out_z + (size_t)HRD*HRD;             // [1024,2048]
    float* out_start = out_net + (size_t)NN*HRD;            // [1024,320]
    float* out_adj   = out_start + (size_t)NN*DIMF;         // [2048,2048]

    static const int LVL_N[4] = {1024, 921, 644, 386};
    static const int LVL_K[4] = {921, 644, 386, 193};

    // -------- workspace arena --------
    char* Wb = (char*)d_ws;
    size_t off = 0;
    auto alloc = [&](size_t bb)->char*{ char* p = Wb + off; off = (off + bb + 255) & ~(size_t)255; return p; };

    float*  A32  = (float*) alloc((size_t)NN*NN*4);
    double* A64  = (double*)alloc((size_t)NN*NN*8);
    float*  UfT  = (float*) alloc((size_t)NN*NN*4);   // U^T as [k][j] fp32
    double* r64  = (double*)alloc(NN*8);
    double* dD   = (double*)alloc(NN*8);
    double* dE   = (double*)alloc(NN*8);
    double* dTau = (double*)alloc(NN*8);
    double* dScl = (double*)alloc(NN*8);
    double* dWev = (double*)alloc(NN*8);
    double* pb0  = (double*)alloc(NN*8);
    double* pb1  = (double*)alloc(NN*8);
    double* pvA  = (double*)alloc(NN*8);
    double* sigA = (double*)alloc(NN*8);
    unsigned* barcnt = (unsigned*)alloc(8192);
    double* Tm   = (double*)alloc(64*64*8);
    double* Vp   = (double*)alloc((size_t)NN*64*8);
    double* Yt   = (double*)alloc((size_t)64*NN*8);
    double* W2   = (double*)alloc((size_t)64*NN*8);
    char* SBASE = Wb + off;

    // P2 overlay (U-Net)
    size_t so = 0;
    auto salloc = [&](size_t bb)->char*{ char* p = SBASE + so; so = (so + bb + 255) & ~(size_t)255; return p; };
    float* XT  = (float*)salloc((size_t)NN*DIMF*4);
    float* XP1 = (float*)salloc((size_t)NN*DIMF*4);
    float* XP2 = (float*)salloc((size_t)NN*DIMF*4);
    float* XU  = (float*)salloc((size_t)NN*DIMF*4);
    float* DN[4]; for (int l = 0; l < 4; ++l) DN[l] = (float*)salloc((size_t)NN*DIMF*4);
    float* Asub[4];
    for (int l = 0; l < 4; ++l) Asub[l] = (float*)salloc((size_t)LVL_K[l]*LVL_K[l]*4);
    float* SC = (float*)salloc(NN*4);
    int*   IDX[4]; for (int l = 0; l < 4; ++l) IDX[l] = (int*)salloc(NN*4);
    float* VAL[4]; for (int l = 0; l < 4; ++l) VAL[l] = (float*)salloc(NN*4);
    float* XC  = (float*)salloc((size_t)NN*2*DIMF*4);
    float* AXC = (float*)salloc((size_t)NN*2*DIMF*4);

    // P3 overlay (eigensolver scratch)
    const size_t PL = (size_t)NN*NN*8;
    double* Z64 = (double*)(SBASE);
    double* FD  = (double*)(SBASE + PL);
    double* FL  = (double*)(SBASE + 2*PL);
    double* FU  = (double*)(SBASE + 3*PL);
    double* FU2 = (double*)(SBASE + 4*PL);
    signed char* FPIV = (signed char*)(SBASE + 5*PL);

    // P4 overlay (GSR / refinement)
    const size_t MB8  = (size_t)HRD*NN*4;    // 8 MiB
    const size_t MB16 = (size_t)HRD*HRD*4;   // 16 MiB
    float* P4a   = (float*)(SBASE);               // [2048,1024]
    float* P4t1  = (float*)(SBASE + MB8);         // [2048,1024]
    float* P4adT = (float*)(SBASE);               // [2048,2048]
    float* P4Zb  = (float*)(SBASE + MB16);        // [2048,2048]
    float* P4ZG  = (float*)(SBASE);               // [2048,1024]
    float* P4h1  = (float*)(SBASE + MB8);         // [2048,1024]
    float* P4HG  = (float*)(SBASE + MB16);        // [2048,2048]
    float* P4h2  = (float*)(SBASE);               // [2048,2048]

    // =============== P1: normalized adjacency ===============
    rowsum_rsqrt_k<<<NN, 256, 0, stream>>>(lr, r64, NN);
    build_A_k<<<(NN*NN + 255)/256, 256, 0, stream>>>(lr, r64, A32, A64, NN);

    // =============== P2: graph U-Net (fp32) ===============
    gemmf32(stream, EPI_BIAS, A32, start_w, out_start, NN, DIMF, NN, start_b, nullptr);

    const float* Xcur = out_start;
    const float* Acur = A32;
    float* ping = XP1; float* pong = XP2;
    for (int l = 0; l < 4; ++l){
        int nl = LVL_N[l], kl = LVL_K[l];
        gemmf32(stream, EPI_NONE, Acur, Xcur, XT, nl, DIMF, nl, nullptr, nullptr);
        gemmf32(stream, EPI_BIAS, XT, down_w + (size_t)l*DIMF*DIMF, DN[l], nl, DIMF, DIMF,
                down_b + (size_t)l*DIMF, nullptr);
        score_k<<<(nl + 3)/4, 256, 0, stream>>>(DN[l], pool_w + (size_t)l*DIMF, pool_b + l, SC, nl, DIMF);
        topk_k<<<1, 256, 0, stream>>>(SC, nl, kl, IDX[l], VAL[l]);
        gatherX_k<<<(unsigned)(((size_t)kl*DIMF + 255)/256), 256, 0, stream>>>(DN[l], IDX[l], VAL[l], ping, kl, DIMF);
        gatherA_k<<<(unsigned)(((size_t)kl*kl + 255)/256), 256, 0, stream>>>(Acur, IDX[l], Asub[l], kl, nl);
        Xcur = ping; Acur = Asub[l];
        float* t = ping; ping = pong; pong = t;
    }
    gemmf32(stream, EPI_NONE, Acur, Xcur, XT, 193, DIMF, 193, nullptr, nullptr);
    float* Xb = ping;
    gemmf32(stream, EPI_BIAS, XT, bottom_w, Xb, 193, DIMF, DIMF, bottom_b, nullptr);
    const float* Xup = Xb;
    float* upbuf[2] = { (Xb == XP1) ? XP2 : XP1, (Xb == XP1) ? XP1 : XP2 };
    for (int i2 = 0; i2 < 4; ++i2){
        int jl = 3 - i2;
        int nj = LVL_N[jl];
        int kj = LVL_K[jl];
        fill0_k<<<(unsigned)(((size_t)nj*DIMF + 255)/256), 256, 0, stream>>>(XU, (size_t)nj*DIMF);
        scatterX_k<<<(unsigned)(((size_t)kj*DIMF + 255)/256), 256, 0, stream>>>(Xup, IDX[jl], XU, kj, DIMF);
        const float* Aj = (jl == 0) ? A32 : Asub[jl - 1];
        gemmf32(stream, EPI_NONE, Aj, XU, XT, nj, DIMF, nj, nullptr, nullptr);
        float* Xn = upbuf[i2 & 1];
        gemmf32(stream, EPI_BIAS_ADD, XT, up_w + (size_t)i2*DIMF*DIMF, Xn, nj, DIMF, DIMF,
                up_b + (size_t)i2*DIMF, DN[jl]);
        Xup = Xn;
    }
    concat_k<<<(unsigned)(((size_t)NN*2*DIMF + 255)/256), 256, 0, stream>>>(Xup, out_start, XC, NN, DIMF);
    gemmf32(stream, EPI_NONE, A32, XC, AXC, NN, 2*DIMF, NN, nullptr, nullptr);
    gemmf32(stream, EPI_BIAS, AXC, end_w, out_net, NN, HRD, 2*DIMF, end_b, nullptr);

    // =============== P3: eigendecomposition of A (fp64) ===============
    init_sytrd_k<<<4, 256, 0, stream>>>(sigA, pvA, barcnt, NN);
    sytrd_coop2<<<CB2, BT2, 0, stream>>>(A64, dE, dTau, dScl, pb0, pb1, pvA, sigA, barcnt, NN, NN - TB);
    hh_tail<<<1, 256, 0, stream>>>(A64, dE, dTau, dScl, NN);
    extract_de_k<<<4, 256, 0, stream>>>(A64, dD, dE, NN);
    bisect_k<<<4, 256, 0, stream>>>(dD, dE, dWev, NN);
    invit_k<<<4, 256, 0, stream>>>(dD, dE, dWev, FD, FL, FU, FU2, FPIV, Z64, NN);
    for (int g = 15; g >= 0; --g){
        int b0 = g*64;
        int nbsz = (NN - 2) - b0; if (nbsz > 64) nbsz = 64;
        build_V_k<<<(NN*64 + 255)/256, 256, 0, stream>>>(A64, dScl, Vp, NN, b0, nbsz);
        build_T_k<<<1, 256, 0, stream>>>(Vp, dTau, Tm, NN, b0, nbsz);
        int r0 = b0 + 1;
        gemmf64(stream, true,  Vp + (size_t)r0*64, 64, Z64 + (size_t)r0*NN, NN, Yt, NN, nbsz, NN, NN - r0, 1.0, 0.0);
        gemmf64(stream, false, Tm, 64, Yt, NN, W2, NN, nbsz, NN, nbsz, 1.0, 0.0);
        gemmf64(stream, false, Vp + (size_t)r0*64, 64, W2, NN, Z64 + (size_t)r0*NN, NN, NN - r0, NN, nbsz, -1.0, 1.0);
    }
    {
        dim3 g(NN/32, NN/32), b(256);
        transpose_cast_k<<<g, b, 0, stream>>>(Z64, UfT, NN);
    }

    // =============== P4: GSR layer + refinement (fp32) ===============
    build_a_k<<<(unsigned)(((size_t)HRD*NN + 255)/256), 256, 0, stream>>>(gsr_w, P4a);
    gemmf32(stream, EPI_NONE, P4a, UfT, P4t1, HRD, NN, NN, nullptr, nullptr);               // a @ U^T
    gemmf32(stream, EPI_ABS_DIAG1, P4t1, out_net, out_adj, HRD, HRD, NN, nullptr, nullptr); // adj
    {
        dim3 g(HRD/32, HRD/32), b(256);
        transpose32_k<<<g, b, 0, stream>>>(out_adj, P4adT, HRD);                            // adj^T
    }
    gemmf32(stream, EPI_NONE, out_adj, P4adT, P4Zb, HRD, HRD, HRD, nullptr, nullptr);       // adj @ adj^T
    symabs1_k<<<(unsigned)(((size_t)HRD*HRD + 255)/256), 256, 0, stream>>>(P4Zb, HRD);      // Z
    gemmf32(stream, EPI_NONE, P4Zb, gc1, P4ZG, HRD, NN, HRD, nullptr, nullptr);             // Z @ gc1
    gemmf32(stream, EPI_RELU, out_adj, P4ZG, P4h1, HRD, NN, HRD, nullptr, nullptr);         // h1
    gemmf32(stream, EPI_NONE, P4h1, gc2, P4HG, HRD, HRD, NN, nullptr, nullptr);             // h1 @ gc2
    gemmf32(stream, EPI_RELU, out_adj, P4HG, P4h2, HRD, HRD, HRD, nullptr, nullptr);        // h2
    final_z_k<<<(unsigned)(((size_t)HRD*HRD + 255)/256), 256, 0, stream>>>(P4h2, out_z, HRD); // z
}

// Round 6
// 45101.312 us; speedup vs baseline: 1.7669x; 1.7590x over previous
//
#include <hip/hip_runtime.h>
#include <cstddef>
#include <cstdint>
#include <math.h>

// ============================ constants ============================
static constexpr int NN   = 1024;   // lr_dim
static constexpr int HRD  = 2048;   // hr_dim
static constexpr int DIMF = 320;
static constexpr int TB   = 85;     // sytrd LDS tail block (85x87 fp64 = 59 KB LDS)
static constexpr int CB2  = 256;    // persistent sytrd blocks (<= CU count -> co-resident)
static constexpr int BT2  = 1024;   // threads per sytrd block (16 waves)
static constexpr int NGRP = 8;      // barrier tree groups
static constexpr int BPG  = 32;     // blocks per group (CB2 = NGRP*BPG)

#define EPI_NONE      0
#define EPI_BIAS      1
#define EPI_BIAS_ADD  2
#define EPI_ABS_DIAG1 3
#define EPI_RELU      4

// ============================ fp32 GEMM 64-tile (fallback, odd K) ============================
template<int EPI>
__global__ __launch_bounds__(256) void gemm32(
    const float* __restrict__ A, const float* __restrict__ B, float* __restrict__ C,
    int M, int N, int K, const float* __restrict__ bias, const float* __restrict__ D)
{
    __shared__ float As[16][65];
    __shared__ float Bs[16][65];
    const int bm = blockIdx.y << 6, bn = blockIdx.x << 6;
    const int tid = threadIdx.x;
    const int tm = (tid >> 4) << 2, tn = (tid & 15) << 2;
    float acc[4][4] = {};
    const int kt = (K + 15) >> 4;
    for (int k0 = 0; k0 < kt; ++k0){
        const int kb = k0 << 4;
        for (int t = tid; t < 1024; t += 256){
            int m = t >> 4, k = t & 15;
            int gm = bm + m, gk = kb + k;
            As[k][m] = (gm < M && gk < K) ? A[(size_t)gm*K + gk] : 0.f;
        }
        for (int t = tid; t < 1024; t += 256){
            int k = t >> 6, nn2 = t & 63;
            int gk = kb + k, gn = bn + nn2;
            Bs[k][nn2] = (gk < K && gn < N) ? B[(size_t)gk*N + gn] : 0.f;
        }
        __syncthreads();
        #pragma unroll
        for (int k = 0; k < 16; ++k){
            float a0 = As[k][tm], a1 = As[k][tm+1], a2 = As[k][tm+2], a3 = As[k][tm+3];
            float b0 = Bs[k][tn], b1 = Bs[k][tn+1], b2 = Bs[k][tn+2], b3 = Bs[k][tn+3];
            acc[0][0] += a0*b0; acc[0][1] += a0*b1; acc[0][2] += a0*b2; acc[0][3] += a0*b3;
            acc[1][0] += a1*b0; acc[1][1] += a1*b1; acc[1][2] += a1*b2; acc[1][3] += a1*b3;
            acc[2][0] += a2*b0; acc[2][1] += a2*b1; acc[2][2] += a2*b2; acc[2][3] += a2*b3;
            acc[3][0] += a3*b0; acc[3][1] += a3*b1; acc[3][2] += a3*b2; acc[3][3] += a3*b3;
        }
        __syncthreads();
    }
    #pragma unroll
    for (int r = 0; r < 4; ++r){
        int gm = bm + tm + r; if (gm >= M) continue;
        #pragma unroll
        for (int c = 0; c < 4; ++c){
            int gn = bn + tn + c; if (gn >= N) continue;
            float v = acc[r][c];
            if (EPI == EPI_BIAS)            v += bias[gn];
            else if (EPI == EPI_BIAS_ADD)   v += bias[gn] + D[(size_t)gm*N + gn];
            else if (EPI == EPI_ABS_DIAG1)  v = (gm == gn) ? 1.0f : fabsf(v);
            else if (EPI == EPI_RELU)       v = fmaxf(v, 0.0f);
            C[(size_t)gm*N + gn] = v;
        }
    }
}

// ============================ fp32 GEMM 128-tile (K%16==0, N%8==0) ============================
template<int EPI>
__global__ __launch_bounds__(256) void gemm128(
    const float* __restrict__ A, const float* __restrict__ B, float* __restrict__ C,
    int M, int N, int K, const float* __restrict__ bias, const float* __restrict__ D)
{
    __shared__ float As[16][132];
    __shared__ float Bs[16][132];
    const int bm = blockIdx.y << 7, bn = blockIdx.x << 7;
    const int tid = threadIdx.x;
    const int tm = (tid >> 4) << 3;
    const int tn = (tid & 15) << 3;
    const int ar = tid >> 1;
    const int ak = (tid & 1) << 3;
    const int br = tid >> 4;
    const int bc = (tid & 15) << 3;
    float acc[8][8] = {};
    for (int kb = 0; kb < K; kb += 16){
        {
            int gm = bm + ar, gk = kb + ak;
            float4 a0, a1;
            if (gm < M){
                const float* p = A + (size_t)gm*K + gk;
                a0 = *(const float4*)p; a1 = *(const float4*)(p + 4);
            } else { a0 = make_float4(0.f,0.f,0.f,0.f); a1 = a0; }
            As[ak+0][ar]=a0.x; As[ak+1][ar]=a0.y; As[ak+2][ar]=a0.z; As[ak+3][ar]=a0.w;
            As[ak+4][ar]=a1.x; As[ak+5][ar]=a1.y; As[ak+6][ar]=a1.z; As[ak+7][ar]=a1.w;
        }
        {
            int gk = kb + br, gn = bn + bc;
            float4 b0, b1;
            if (gn + 7 < N){
                const float* p = B + (size_t)gk*N + gn;
                b0 = *(const float4*)p; b1 = *(const float4*)(p + 4);
            } else {
                float t0[8];
                #pragma unroll
                for (int i = 0; i < 8; ++i){ int g = gn + i; t0[i] = (g < N) ? B[(size_t)gk*N + g] : 0.f; }
                b0 = make_float4(t0[0],t0[1],t0[2],t0[3]); b1 = make_float4(t0[4],t0[5],t0[6],t0[7]);
            }
            *(float4*)&Bs[br][bc] = b0; *(float4*)&Bs[br][bc+4] = b1;
        }
        __syncthreads();
        #pragma unroll
        for (int k = 0; k < 16; ++k){
            float4 a0 = *(const float4*)&As[k][tm];
            float4 a1 = *(const float4*)&As[k][tm+4];
            float4 b0 = *(const float4*)&Bs[k][tn];
            float4 b1 = *(const float4*)&Bs[k][tn+4];
            float av[8] = {a0.x,a0.y,a0.z,a0.w,a1.x,a1.y,a1.z,a1.w};
            float bv[8] = {b0.x,b0.y,b0.z,b0.w,b1.x,b1.y,b1.z,b1.w};
            #pragma unroll
            for (int i = 0; i < 8; ++i)
                #pragma unroll
                for (int jj = 0; jj < 8; ++jj) acc[i][jj] += av[i]*bv[jj];
        }
        __syncthreads();
    }
    #pragma unroll
    for (int i = 0; i < 8; ++i){
        int gm = bm + tm + i; if (gm >= M) continue;
        #pragma unroll
        for (int jj = 0; jj < 8; ++jj){
            int gn = bn + tn + jj; if (gn >= N) continue;
            float v = acc[i][jj];
            if (EPI == EPI_BIAS)            v += bias[gn];
            else if (EPI == EPI_BIAS_ADD)   v += bias[gn] + D[(size_t)gm*N + gn];
            else if (EPI == EPI_ABS_DIAG1)  v = (gm == gn) ? 1.0f : fabsf(v);
            else if (EPI == EPI_RELU)       v = fmaxf(v, 0.0f);
            C[(size_t)gm*N + gn] = v;
        }
    }
}

// ============================ fp64 GEMM 64-tile, 4x4 micro ============================
template<bool TRA>
__global__ __launch_bounds__(256) void gemm64b(
    const double* __restrict__ A, int lda, const double* __restrict__ B, int ldb,
    double* __restrict__ C, int ldc, int M, int N, int K, double alpha, double beta)
{
    __shared__ double As[16][66];
    __shared__ double Bs[16][66];
    const int bm = blockIdx.y << 6, bn = blockIdx.x << 6;
    const int tid = threadIdx.x;
    const int tm = (tid >> 4) << 2, tn = (tid & 15) << 2;
    double acc[4][4] = {};
    for (int kb = 0; kb < K; kb += 16){
        if (!TRA){
            for (int t = tid; t < 1024; t += 256){
                int m = t >> 4, k = t & 15;
                int gm = bm + m, gk = kb + k;
                As[k][m] = (gm < M && gk < K) ? A[(size_t)gm*lda + gk] : 0.0;
            }
        } else {
            for (int t = tid; t < 1024; t += 256){
                int k = t >> 6, m = t & 63;
                int gm = bm + m, gk = kb + k;
                As[k][m] = (gm < M && gk < K) ? A[(size_t)gk*lda + gm] : 0.0;
            }
        }
        for (int t = tid; t < 1024; t += 256){
            int k = t >> 6, nn2 = t & 63;
            int gk = kb + k, gn = bn + nn2;
            Bs[k][nn2] = (gk < K && gn < N) ? B[(size_t)gk*ldb + gn] : 0.0;
        }
        __syncthreads();
        #pragma unroll
        for (int k = 0; k < 16; ++k){
            double a0=As[k][tm],a1=As[k][tm+1],a2=As[k][tm+2],a3=As[k][tm+3];
            double b0=Bs[k][tn],b1=Bs[k][tn+1],b2=Bs[k][tn+2],b3=Bs[k][tn+3];
            acc[0][0]+=a0*b0; acc[0][1]+=a0*b1; acc[0][2]+=a0*b2; acc[0][3]+=a0*b3;
            acc[1][0]+=a1*b0; acc[1][1]+=a1*b1; acc[1][2]+=a1*b2; acc[1][3]+=a1*b3;
            acc[2][0]+=a2*b0; acc[2][1]+=a2*b1; acc[2][2]+=a2*b2; acc[2][3]+=a2*b3;
            acc[3][0]+=a3*b0; acc[3][1]+=a3*b1; acc[3][2]+=a3*b2; acc[3][3]+=a3*b3;
        }
        __syncthreads();
    }
    #pragma unroll
    for (int r = 0; r < 4; ++r){
        int gm = bm + tm + r; if (gm >= M) continue;
        #pragma unroll
        for (int c = 0; c < 4; ++c){
            int gn = bn + tn + c; if (gn >= N) continue;
            double v = alpha*acc[r][c];
            if (beta != 0.0) v += beta*C[(size_t)gm*ldc + gn];
            C[(size_t)gm*ldc + gn] = v;
        }
    }
}

// ============================ small kernels ============================
__global__ __launch_bounds__(256) void rowsum_rsqrt_k(const float* __restrict__ lr, double* __restrict__ r64, int n)
{
    __shared__ double sm[256];
    int row = blockIdx.x;
    double s = 0.0;
    for (int j = threadIdx.x; j < n; j += 256) s += (double)lr[(size_t)row*n + j];
    sm[threadIdx.x] = s; __syncthreads();
    for (int o = 128; o; o >>= 1){ if (threadIdx.x < o) sm[threadIdx.x] += sm[threadIdx.x + o]; __syncthreads(); }
    if (threadIdx.x == 0){
        double t = sm[0];
        r64[row] = (t > 0.0) ? 1.0/sqrt(t) : 0.0;
    }
}

__global__ __launch_bounds__(256) void build_A_k(const float* __restrict__ lr, const double* __restrict__ r64,
                                                 float* __restrict__ A32, double* __restrict__ A64, int n)
{
    size_t idx = (size_t)blockIdx.x*256 + threadIdx.x;
    if (idx >= (size_t)n*n) return;
    int i = (int)(idx / n), j = (int)(idx % n);
    if (j < i) return;
    double v = (double)lr[(size_t)j*n + i] * r64[i] * r64[j];
    A64[(size_t)i*n + j] = v; A64[(size_t)j*n + i] = v;
    float vf = (float)v;
    A32[(size_t)i*n + j] = vf; A32[(size_t)j*n + i] = vf;
}

__global__ __launch_bounds__(256) void score_k(const float* __restrict__ X, const float* __restrict__ pw,
                                               const float* __restrict__ pb, float* __restrict__ out,
                                               int n, int dim)
{
    int row = blockIdx.x*4 + (threadIdx.x >> 6);
    int lane = threadIdx.x & 63;
    if (row >= n) return;
    float acc = 0.f;
    for (int c = lane; c < dim; c += 64) acc += X[(size_t)row*dim + c]*pw[c];
    #pragma unroll
    for (int o = 32; o; o >>= 1) acc += __shfl_down(acc, o);
    if (lane == 0){
        float t = (acc + pb[0]) * 0.01f;
        out[row] = 1.0f/(1.0f + expf(-t));
    }
}

// jax.lax.top_k semantics: descending value, ties -> lower index first
__global__ __launch_bounds__(256) void topk_k(const float* __restrict__ scores, int n, int k,
                                              int* __restrict__ idxo, float* __restrict__ valo)
{
    __shared__ float s[1024];
    int tid = threadIdx.x;
    for (int i = tid; i < n; i += 256) s[i] = scores[i];
    __syncthreads();
    for (int i = tid; i < n; i += 256){
        float si = s[i]; int r = 0;
        for (int j = 0; j < n; ++j){
            float sj = s[j];
            r += (sj > si) || (sj == si && j < i);
        }
        if (r < k){ idxo[r] = i; valo[r] = si; }
    }
}

__global__ __launch_bounds__(256) void gatherX_k(const float* __restrict__ X, const int* __restrict__ idx,
                                                 const float* __restrict__ vals, float* __restrict__ Xo,
                                                 int k, int dim)
{
    size_t t = (size_t)blockIdx.x*256 + threadIdx.x;
    if (t >= (size_t)k*dim) return;
    int m = (int)(t / dim), c = (int)(t % dim);
    Xo[t] = X[(size_t)idx[m]*dim + c] * vals[m];
}

__global__ __launch_bounds__(256) void scatterX_k(const float* __restrict__ Xs, const int* __restrict__ idx,
                                                  float* __restrict__ Xu, int k, int dim)
{
    size_t t = (size_t)blockIdx.x*256 + threadIdx.x;
    if (t >= (size_t)k*dim) return;
    int m = (int)(t / dim), c = (int)(t % dim);
    Xu[(size_t)idx[m]*dim + c] = Xs[t];
}

__global__ __launch_bounds__(256) void gatherA_k(const float* __restrict__ A, const int* __restrict__ idx,
                                                 float* __restrict__ Ao, int k, int n)
{
    size_t t = (size_t)blockIdx.x*256 + threadIdx.x;
    if (t >= (size_t)k*k) return;
    int m1 = (int)(t / k), m2 = (int)(t % k);
    Ao[t] = A[(size_t)idx[m1]*n + idx[m2]];
}

__global__ __launch_bounds__(256) void fill0_k(float* __restrict__ p, size_t cnt)
{
    size_t t = (size_t)blockIdx.x*256 + threadIdx.x;
    if (t < cnt) p[t] = 0.f;
}

__global__ __launch_bounds__(256) void filld0_k(double* __restrict__ p, size_t cnt)
{
    size_t t = (size_t)blockIdx.x*256 + threadIdx.x;
    if (t < cnt) p[t] = 0.0;
}

__global__ __launch_bounds__(256) void init_sytrd_k(double* __restrict__ pv, unsigned* __restrict__ bar, int n)
{
    int t = blockIdx.x*256 + threadIdx.x;
    if (t < n) pv[t] = 0.0;
    if (t < 1024) bar[t] = 0u;
}

__global__ __launch_bounds__(256) void concat_k(const float* __restrict__ X, const float* __restrict__ orgX,
                                                float* __restrict__ Xc, int n, int dim)
{
    size_t t = (size_t)blockIdx.x*256 + threadIdx.x;
    size_t tot = (size_t)n*2*dim;
    if (t >= tot) return;
    int i = (int)(t / (2*dim)), c = (int)(t % (2*dim));
    Xc[t] = (c < dim) ? X[(size_t)i*dim + c] : orgX[(size_t)i*dim + (c - dim)];
}

__global__ __launch_bounds__(256) void build_a_k(const float* __restrict__ gsr, float* __restrict__ a)
{
    size_t idx = (size_t)blockIdx.x*256 + threadIdx.x;
    if (idx >= (size_t)HRD*NN) return;
    int i = (int)(idx >> 10), k = (int)(idx & 1023);
    a[idx] = gsr[(size_t)i*HRD + k] + gsr[(size_t)i*HRD + NN + k];
}

__global__ __launch_bounds__(256) void symabs1_k(float* __restrict__ Z, int n)
{
    size_t idx = (size_t)blockIdx.x*256 + threadIdx.x;
    if (idx >= (size_t)n*n) return;
    int i = (int)(idx / n), j = (int)(idx % n);
    if (i > j) return;
    float a = Z[(size_t)i*n + j], b = Z[(size_t)j*n + i];
    float v = 0.5f*(a + b);
    float o = (i == j) ? 1.0f : fabsf(v);
    Z[(size_t)i*n + j] = o; Z[(size_t)j*n + i] = o;
}

__global__ __launch_bounds__(256) void final_z_k(const float* __restrict__ h2, float* __restrict__ z, int n)
{
    size_t idx = (size_t)blockIdx.x*256 + threadIdx.x;
    if (idx >= (size_t)n*n) return;
    int i = (int)(idx / n), j = (int)(idx % n);
    if (i > j) return;
    float v = 0.5f*(h2[(size_t)i*n + j] + h2[(size_t)j*n + i]);
    float o = (i == j) ? 1.0f : fabsf(v);
    z[(size_t)i*n + j] = o; z[(size_t)j*n + i] = o;
}

// dst[c][r] = (float)src[r][c]   (n x n, n % 32 == 0)
__global__ __launch_bounds__(256) void transpose_cast_k(const double* __restrict__ src, float* __restrict__ dst, int n)
{
    __shared__ float tile[32][33];
    int r0 = blockIdx.y*32, c0 = blockIdx.x*32;
    int tx = threadIdx.x & 31, ty = threadIdx.x >> 5;
    for (int i = ty; i < 32; i += 8)
        tile[i][tx] = (float)src[(size_t)(r0 + i)*n + (c0 + tx)];
    __syncthreads();
    for (int i = ty; i < 32; i += 8)
        dst[(size_t)(c0 + i)*n + (r0 + tx)] = tile[tx][i];
}

// dst[c][r] = src[r][c]  (n x n, n % 32 == 0)
__global__ __launch_bounds__(256) void transpose32_k(const float* __restrict__ src, float* __restrict__ dst, int n)
{
    __shared__ float tile[32][33];
    int r0 = blockIdx.y*32, c0 = blockIdx.x*32;
    int tx = threadIdx.x & 31, ty = threadIdx.x >> 5;
    for (int i = ty; i < 32; i += 8)
        tile[i][tx] = src[(size_t)(r0 + i)*n + (c0 + tx)];
    __syncthreads();
    for (int i = ty; i < 32; i += 8)
        dst[(size_t)(c0 + i)*n + (r0 + tx)] = tile[tx][i];
}

// ============================ persistent Householder tridiagonalization ============================
// Barrier: RELAXED arrivals + RELAXED spin (no per-poll cache invalidate!), one
// release fence before arrival, one acquire fence after exit. Two-level tree.
__device__ __forceinline__ void gbar3(unsigned* __restrict__ bar, unsigned epoch)
{
    __syncthreads();
    if (threadIdx.x == 0){
        __threadfence();   // release: writeback local L2 so other XCDs can see our writes
        int g = blockIdx.x >> 5;   // / BPG
        unsigned t = __hip_atomic_fetch_add(&bar[g*32], 1u, __ATOMIC_RELAXED, __HIP_MEMORY_SCOPE_AGENT);
        if ((t & (unsigned)(BPG - 1)) == (unsigned)(BPG - 1))
            __hip_atomic_fetch_add(&bar[256], 1u, __ATOMIC_RELAXED, __HIP_MEMORY_SCOPE_AGENT);
        unsigned target = epoch * (unsigned)NGRP;
        while (__hip_atomic_load(&bar[256], __ATOMIC_RELAXED, __HIP_MEMORY_SCOPE_AGENT) < target)
            __builtin_amdgcn_s_sleep(8);
        __threadfence();   // acquire: invalidate stale lines before reading others' data
    }
    __syncthreads();
}

// One-barrier-per-column fused sytrd:
//  phase A (block-redundant): stage v_{j-1} (VP) and w_{j-1} (WP) into LDS from
//    barrier-finalized global data; apply pending update to pivot row j in LDS (VJ),
//    reduce sigma2 block-locally (bitwise identical across blocks), derive beta/tau/sc.
//    Block 0 writes updated row j (unscaled v_j storage), diag, e/tau/scl.
//  phase B: wave-quartet per trailing row: apply pending rank-2 update (one rw pass)
//    and dot updated row with v_j; p via 4-chunk fp64 atomics into P[j]; pv via atomics.
//  ONE grid barrier; next column reads everything post-barrier.
__global__ __launch_bounds__(BT2) void sytrd_coop3(
    double* __restrict__ A, double* __restrict__ e, double* __restrict__ tauA,
    double* __restrict__ sclA, double* __restrict__ P, double* __restrict__ pvA,
    unsigned* __restrict__ bar, int n, int jend)
{
    __shared__ double VP[1024], WP[1024], VJ[1024];
    __shared__ double red16[16];
    __shared__ double sh_b;
    const int tid  = threadIdx.x;
    const int bid  = blockIdx.x;
    const int lane = tid & 63;
    const int wid  = tid >> 6;                    // 0..15
    const int gw   = bid*(BT2/64) + wid;          // 0..4095
    const int rowUnit = gw >> 2;                  // 0..1023
    const int chunk   = gw & 3;
    const unsigned gtid = (unsigned)bid*(unsigned)BT2 + (unsigned)tid;
    const unsigned NT   = (unsigned)CB2*(unsigned)BT2;

    double tau_p = 0.0, sc_p = 0.0;
    unsigned ep = 0;

    for (int j = 0; j < jend; ++j){
        const int m = n - 1 - j;
        double* __restrict__ row = A + (size_t)j*n + (j+1);
        double c2_p = 0.0;
        // ---- phase A: block-redundant pivot-row update + sigma2 ----
        if (j > 0){
            c2_p = 0.5*tau_p*tau_p*pvA[j-1];
            const double* __restrict__ rowp = A + (size_t)(j-1)*n + j;
            const double* __restrict__ pp   = P + (size_t)(j-1)*NN;
            for (int i = tid; i <= m; i += BT2){
                double vp = (i == 0) ? 1.0 : rowp[i]*sc_p;
                VP[i] = vp;
                WP[i] = tau_p*pp[i] - c2_p*vp;
            }
            __syncthreads();
        }
        double s = 0.0;
        if (j > 0){
            double wp0 = WP[0];
            for (int t = tid; t < m; t += BT2){
                double x = row[t] - WP[1+t] - wp0*VP[1+t];
                VJ[t] = x;
                if (t >= 1) s += x*x;
            }
        } else {
            for (int t = tid; t < m; t += BT2){
                double x = row[t];
                VJ[t] = x;
                if (t >= 1) s += x*x;
            }
        }
        #pragma unroll
        for (int o = 32; o; o >>= 1) s += __shfl_down(s, o);
        if (lane == 0) red16[wid] = s;
        __syncthreads();
        if (tid == 0){
            double t2 = 0.0;
            #pragma unroll
            for (int i = 0; i < 16; ++i) t2 += red16[i];
            sh_b = t2;
        }
        __syncthreads();
        double sigma2 = sh_b;
        double alpha = VJ[0];
        double beta, tl, sc;
        if (sigma2 == 0.0){ beta = alpha; tl = 0.0; sc = 0.0; }
        else {
            beta = -copysign(sqrt(alpha*alpha + sigma2), alpha);
            tl = (beta - alpha)/beta;
            sc = 1.0/(alpha - beta);
        }
        if (bid == 0){
            for (int t = tid; t < m; t += BT2) row[t] = VJ[t];
            if (tid == 0){
                e[j] = beta; tauA[j] = tl; sclA[j] = sc;
                if (j > 0) A[(size_t)j*n + j] -= 2.0*WP[0];
            }
        }
        // ---- phase B: trailing update + matvec ----
        double pvloc = 0.0;
        if (rowUnit < m){
            const int r = rowUnit;
            double* __restrict__ Ar = A + (size_t)(j+1+r)*n + (j+1);
            double acc = 0.0;
            if (j > 0){
                double vpr = VP[1+r], wpr = WP[1+r];
                for (int c = chunk*64 + lane; c < m; c += 256){
                    double a = Ar[c] - (vpr*WP[1+c] + wpr*VP[1+c]);
                    Ar[c] = a;
                    double vj = (c == 0) ? 1.0 : VJ[c]*sc;
                    acc += a*vj;
                }
            } else {
                for (int c = chunk*64 + lane; c < m; c += 256){
                    double a = Ar[c];
                    double vj = (c == 0) ? 1.0 : VJ[c]*sc;
                    acc += a*vj;
                }
            }
            #pragma unroll
            for (int o = 32; o; o >>= 1) acc += __shfl_down(acc, o);
            if (lane == 0){
                atomicAdd(&P[(size_t)j*NN + r], acc);
                double vr = (r == 0) ? 1.0 : VJ[r]*sc;
                pvloc = acc*vr;
            }
        }
        if (lane == 0) red16[wid] = pvloc;
        __syncthreads();
        if (tid == 0){
            double t2 = 0.0;
            #pragma unroll
            for (int i = 0; i < 16; ++i) t2 += red16[i];
            if (t2 != 0.0) atomicAdd(&pvA[j], t2);
        }
        ++ep; gbar3(bar, ep);
        tau_p = tl; sc_p = sc;
    }
    // ---- apply final pending update (column jend-1) on the TB x TB tail ----
    {
        double c2f = 0.5*tau_p*tau_p*pvA[jend-1];
        const double* __restrict__ rowp = A + (size_t)(jend-1)*n + jend;
        const double* __restrict__ pp   = P + (size_t)(jend-1)*NN;
        const int tb = n - jend;
        const unsigned tot = (unsigned)(tb*tb);
        for (unsigned idx = gtid; idx < tot; idx += NT){
            int ri = (int)(idx / (unsigned)tb), ci = (int)(idx % (unsigned)tb);
            double vpr = (ri == 0) ? 1.0 : rowp[ri]*sc_p;
            double wpr = tau_p*pp[ri] - c2f*vpr;
            double vpc = (ci == 0) ? 1.0 : rowp[ci]*sc_p;
            double wpc = tau_p*pp[ci] - c2f*vpc;
            A[(size_t)(jend+ri)*n + (jend+ci)] -= vpr*wpc + wpr*vpc;
        }
    }
}

// Tail: remaining (TB-2) Householder steps entirely in LDS (single block).
__global__ __launch_bounds__(256) void hh_tail(double* __restrict__ A64, double* __restrict__ e,
                                               double* __restrict__ tau, double* __restrict__ scaleg, int n)
{
    __shared__ double T[TB][TB+2];
    __shared__ double v[TB], p[TB], red[256];
    const int base = n - TB;
    const int tid = threadIdx.x;
    for (int t = tid; t < TB*TB; t += 256){
        int r = t / TB, c = t % TB;
        T[r][c] = A64[(size_t)(base + r)*n + base + c];
    }
    __syncthreads();
    for (int l = 0; l <= TB - 3; ++l){
        const int m = TB - 1 - l;
        double s = 0.0;
        for (int i = 1 + tid; i < m; i += 256){ double x = T[l+1+i][l]; s += x*x; }
        red[tid] = s; __syncthreads();
        for (int o = 128; o; o >>= 1){ if (tid < o) red[tid] += red[tid + o]; __syncthreads(); }
        double sigma2 = red[0];
        double alpha = T[l+1][l];
        double beta, tl, sc;
        if (sigma2 == 0.0){ beta = alpha; tl = 0.0; sc = 0.0; }
        else {
            beta = -copysign(sqrt(alpha*alpha + sigma2), alpha);
            tl = (beta - alpha)/beta;
            sc = 1.0/(alpha - beta);
        }
        for (int i = tid; i < m; i += 256) v[i] = (i == 0) ? 1.0 : T[l+1+i][l]*sc;
        __syncthreads();
        for (int i = tid; i < m; i += 256){
            double acc = 0.0;
            for (int c = 0; c < m; ++c) acc += T[l+1+i][l+1+c]*v[c];
            p[i] = acc;
        }
        __syncthreads();
        double s2 = 0.0;
        for (int i = tid; i < m; i += 256) s2 += p[i]*v[i];
        red[tid] = s2; __syncthreads();
        for (int o = 128; o; o >>= 1){ if (tid < o) red[tid] += red[tid + o]; __syncthreads(); }
        double pvv = red[0];
        double c2 = 0.5*tl*tl*pvv;
        for (int t2 = tid; t2 < m*m; t2 += 256){
            int r = t2 / m, c = t2 % m;
            double wr = tl*p[r] - c2*v[r];
            double wc = tl*p[c] - c2*v[c];
            T[l+1+r][l+1+c] -= v[r]*wc + wr*v[c];
        }
        if (tid == 0){ int j = base + l; e[j] = beta; tau[j] = tl; scaleg[j] = 1.0; }
        for (int i = tid; i < m; i += 256) A64[(size_t)(base + l)*n + (base + l + 1) + i] = v[i];
        __syncthreads();
    }
    for (int r = tid; r < TB; r += 256) A64[(size_t)(base + r)*n + base + r] = T[r][r];
    if (tid == 0) A64[(size_t)(n-1)*n + (n-2)] = T[TB-1][TB-2];
}

__global__ __launch_bounds__(256) void extract_de_k(const double* __restrict__ A64, double* __restrict__ d,
                                                    double* __restrict__ e, int n)
{
    int i = blockIdx.x*256 + threadIdx.x;
    if (i < n) d[i] = A64[(size_t)i*n + i];
    if (i == 0) e[n-2] = A64[(size_t)(n-1)*n + (n-2)];
}

// ============================ tridiagonal eigensolver ============================
__global__ __launch_bounds__(256) void bisect_k(const double* __restrict__ d, const double* __restrict__ e,
                                                double* __restrict__ w, int n)
{
    int k = blockIdx.x*256 + threadIdx.x;
    if (k >= n) return;
    double gl = 1e300, gu = -1e300;
    for (int i = 0; i < n; ++i){
        double em = (i > 0) ? fabs(e[i-1]) : 0.0, ep = (i < n-1) ? fabs(e[i]) : 0.0;
        double lo2 = d[i] - em - ep, hi2 = d[i] + em + ep;
        gl = fmin(gl, lo2); gu = fmax(gu, hi2);
    }
    double lo = gl - 1e-10, hi = gu + 1e-10;
    const double pivmin = 1e-280;
    for (int it = 0; it < 42; ++it){
        double mid = 0.5*(lo + hi);
        int cnt = 0; double q = 1.0;
        for (int i = 0; i < n; ++i){
            double t;
            if (i == 0) t = d[0] - mid;
            else { double ei = e[i-1]; t = d[i] - mid - ei*(ei/q); }
            if (fabs(t) < pivmin) t = -pivmin;
            if (t < 0.0) ++cnt;
            q = t;
        }
        if (cnt <= k) lo = mid; else hi = mid;
    }
    w[k] = 0.5*(lo + hi);
}

__global__ __launch_bounds__(256) void invit_k(const double* __restrict__ d, const double* __restrict__ e,
                                               const double* __restrict__ w,
                                               double* __restrict__ FD, double* __restrict__ FL,
                                               double* __restrict__ FU, double* __restrict__ FU2,
                                               signed char* __restrict__ PIV, double* __restrict__ Z, int n)
{
    int k = blockIdx.x*256 + threadIdx.x;
    if (k >= n) return;
    const double lam = w[k];
    const double tiny = 1e-280;
    double dcur = d[0] - lam;
    double ucur = e[0];
    for (int i = 0; i < n-1; ++i){
        double dli = e[i];
        double dnext_init = d[i+1] - lam;
        double unext_init = (i < n-2) ? e[i+1] : 0.0;
        size_t o = (size_t)i*n + k;
        if (fabs(dcur) >= fabs(dli)){
            if (dcur == 0.0) dcur = tiny;
            double f = dli/dcur;
            FD[o] = dcur; FL[o] = f; FU[o] = ucur; FU2[o] = 0.0; PIV[o] = 0;
            dcur = dnext_init - f*ucur;
            ucur = unext_init;
        } else {
            double f = dcur/dli;
            FD[o] = dli; FL[o] = f; FU[o] = dnext_init; FU2[o] = unext_init; PIV[o] = 1;
            dcur = ucur - f*dnext_init;
            ucur = -f*unext_init;
        }
    }
    if (dcur == 0.0) dcur = tiny;
    FD[(size_t)(n-1)*n + k] = dcur;
    for (int i = 0; i < n; ++i){
        unsigned h = (unsigned)(i + 1)*0x9E3779B9u + (unsigned)(k + 1)*0x85EBCA6Bu;
        h ^= h >> 16; h *= 0x7FEB352Du; h ^= h >> 15; h *= 0x846CA68Bu; h ^= h >> 16;
        Z[(size_t)i*n + k] = (double)(h >> 8)*(1.0/16777216.0) - 0.5;
    }
    for (int iter = 0; iter < 2; ++iter){
        double zc = Z[k];
        for (int i = 0; i < n-1; ++i){
            size_t o = (size_t)i*n + k;
            double fl = FL[o];
            double zn = Z[o + n];
            if (!PIV[o]){
                Z[o] = zc;
                zc = zn - fl*zc;
            } else {
                Z[o] = zn;
                zc = zc - fl*zn;
            }
        }
        double za = zc / FD[(size_t)(n-1)*n + k];
        Z[(size_t)(n-1)*n + k] = za;
        size_t o2 = (size_t)(n-2)*n + k;
        double zaa = (Z[o2] - FU[o2]*za) / FD[o2];
        Z[o2] = zaa;
        double zb = za;
        for (int i = n-3; i >= 0; --i){
            size_t o = (size_t)i*n + k;
            double znew = (Z[o] - FU[o]*zaa - FU2[o]*zb) / FD[o];
            Z[o] = znew;
            zb = zaa; zaa = znew;
        }
        double mx = 0.0;
        for (int i = 0; i < n; ++i) mx = fmax(mx, fabs(Z[(size_t)i*n + k]));
        double s = (mx > 0.0) ? 1.0/mx : 1.0;
        for (int i = 0; i < n; ++i) Z[(size_t)i*n + k] *= s;
    }
    double nrm = 0.0;
    for (int i = 0; i < n; ++i){ double v = Z[(size_t)i*n + k]; nrm += v*v; }
    double s = 1.0/sqrt(nrm);
    for (int i = 0; i < n; ++i) Z[(size_t)i*n + k] *= s;
}

// ============================ blocked-WY back-transform ============================
// v_j stored in ROW j of A64 (cols j+1..): v(r)=1 at r==j+1, else A64[j][r]*scale[j]
__global__ __launch_bounds__(256) void build_V_k(const double* __restrict__ A64, const double* __restrict__ scaleg,
                                                 double* __restrict__ V, int n, int b, int nbsz)
{
    size_t idx = (size_t)blockIdx.x*256 + threadIdx.x;
    if (idx >= (size_t)n*64) return;
    int r = (int)(idx >> 6), t = (int)(idx & 63);
    double v = 0.0;
    if (t < nbsz){
        int j = b + t;
        if (r == j + 1) v = 1.0;
        else if (r > j + 1) v = A64[(size_t)j*n + r]*scaleg[j];
    }
    V[(size_t)r*64 + t] = v;
}

__global__ __launch_bounds__(256) void build_T_k(const double* __restrict__ V, const double* __restrict__ tau,
                                                 double* __restrict__ T, int n, int b, int nbsz)
{
    __shared__ double G[64][64];
    int tid = threadIdx.x;
    for (int p = tid; p < 64*64; p += 256){
        int t = p >> 6, s2 = p & 63;
        double g = 0.0;
        if (t < s2 && s2 < nbsz){
            for (int r = b + s2 + 1; r < n; ++r) g += V[(size_t)r*64 + t]*V[(size_t)r*64 + s2];
        }
        G[t][s2] = g;
    }
    __syncthreads();
    for (int t = nbsz - 1; t >= 0; --t){
        for (int u = tid; u < nbsz; u += 256){
            if (u == t) T[t*64 + u] = tau[b + t];
            else if (u > t){
                double s = 0.0;
                for (int s2 = t + 1; s2 <= u; ++s2) s += G[t][s2]*T[s2*64 + u];
                T[t*64 + u] = -tau[b + t]*s;
            } else T[t*64 + u] = 0.0;
        }
        __syncthreads();
    }
}

// ============================ host dispatch helpers ============================
static void gemmf32(hipStream_t st, int epi,
                    const float* A, const float* B, float* C, int M, int N, int K,
                    const float* bias, const float* D)
{
    if ((K & 15) == 0 && (N & 7) == 0){
        dim3 g((N + 127)/128, (M + 127)/128), b(256);
        switch (epi){
        case EPI_NONE:      gemm128<EPI_NONE><<<g, b, 0, st>>>(A, B, C, M, N, K, bias, D); break;
        case EPI_BIAS:      gemm128<EPI_BIAS><<<g, b, 0, st>>>(A, B, C, M, N, K, bias, D); break;
        case EPI_BIAS_ADD:  gemm128<EPI_BIAS_ADD><<<g, b, 0, st>>>(A, B, C, M, N, K, bias, D); break;
        case EPI_ABS_DIAG1: gemm128<EPI_ABS_DIAG1><<<g, b, 0, st>>>(A, B, C, M, N, K, bias, D); break;
        case EPI_RELU:      gemm128<EPI_RELU><<<g, b, 0, st>>>(A, B, C, M, N, K, bias, D); break;
        }
    } else {
        dim3 g((N + 63)/64, (M + 63)/64), b(256);
        switch (epi){
        case EPI_NONE:      gemm32<EPI_NONE><<<g, b, 0, st>>>(A, B, C, M, N, K, bias, D); break;
        case EPI_BIAS:      gemm32<EPI_BIAS><<<g, b, 0, st>>>(A, B, C, M, N, K, bias, D); break;
        case EPI_BIAS_ADD:  gemm32<EPI_BIAS_ADD><<<g, b, 0, st>>>(A, B, C, M, N, K, bias, D); break;
        case EPI_ABS_DIAG1: gemm32<EPI_ABS_DIAG1><<<g, b, 0, st>>>(A, B, C, M, N, K, bias, D); break;
        case EPI_RELU:      gemm32<EPI_RELU><<<g, b, 0, st>>>(A, B, C, M, N, K, bias, D); break;
        }
    }
}

static void gemmf64(hipStream_t st, bool tra,
                    const double* A, int lda, const double* B, int ldb,
                    double* C, int ldc, int M, int N, int K, double alpha, double beta)
{
    dim3 g((N + 63)/64, (M + 63)/64), b(256);
    if (tra) gemm64b<true ><<<g, b, 0, st>>>(A, lda, B, ldb, C, ldc, M, N, K, alpha, beta);
    else     gemm64b<false><<<g, b, 0, st>>>(A, lda, B, ldb, C, ldc, M, N, K, alpha, beta);
}

// ============================ kernel_launch ============================
extern "C" void kernel_launch(void* const* d_in, const int* in_sizes, int n_in,
                              void* d_out, int out_size, void* d_ws, size_t ws_size,
                              hipStream_t stream)
{
    (void)in_sizes; (void)n_in; (void)out_size; (void)ws_size;
    const float* lr       = (const float*)d_in[0];
    const float* gsr_w    = (const float*)d_in[1];
    const float* start_w  = (const float*)d_in[2];
    const float* start_b  = (const float*)d_in[3];
    const float* down_w   = (const float*)d_in[4];
    const float* down_b   = (const float*)d_in[5];
    const float* pool_w   = (const float*)d_in[6];
    const float* pool_b   = (const float*)d_in[7];
    const float* bottom_w = (const float*)d_in[8];
    const float* bottom_b = (const float*)d_in[9];
    const float* end_w    = (const float*)d_in[10];
    const float* end_b    = (const float*)d_in[11];
    const float* up_w     = (const float*)d_in[12];
    const float* up_b     = (const float*)d_in[13];
    const float* gc1      = (const float*)d_in[14];
    const float* gc2      = (const float*)d_in[15];

    float* out_z     = (float*)d_out;                       // [2048,2048]
    float* out_net   = out_z + (size_t)HRD*HRD;             // [1024,2048]
    float* out_start = out_net + (size_t)NN*HRD;            // [1024,320]
    float* out_adj   = out_start + (size_t)NN*DIMF;         // [2048,2048]

    static const int LVL_N[4] = {1024, 921, 644, 386};
    static const int LVL_K[4] = {921, 644, 386, 193};

    // -------- workspace arena --------
    char* Wb = (char*)d_ws;
    size_t off = 0;
    auto alloc = [&](size_t bb)->char*{ char* p = Wb + off; off = (off + bb + 255) & ~(size_t)255; return p; };

    float*  A32  = (float*) alloc((size_t)NN*NN*4);
    double* A64  = (double*)alloc((size_t)NN*NN*8);
    float*  UfT  = (float*) alloc((size_t)NN*NN*4);   // U^T as [k][j] fp32
    double* r64  = (double*)alloc(NN*8);
    double* dD   = (double*)alloc(NN*8);
    double* dE   = (double*)alloc(NN*8);
    double* dTau = (double*)alloc(NN*8);
    double* dScl = (double*)alloc(NN*8);
    double* dWev = (double*)alloc(NN*8);
    double* pvA  = (double*)alloc(NN*8);
    unsigned* barcnt = (unsigned*)alloc(8192);
    double* Tm   = (double*)alloc(64*64*8);
    double* Vp   = (double*)alloc((size_t)NN*64*8);
    double* Yt   = (double*)alloc((size_t)64*NN*8);
    double* W2   = (double*)alloc((size_t)64*NN*8);
    char* SBASE = Wb + off;

    // P2 overlay (U-Net)
    size_t so = 0;
    auto salloc = [&](size_t bb)->char*{ char* p = SBASE + so; so = (so + bb + 255) & ~(size_t)255; return p; };
    float* XT  = (float*)salloc((size_t)NN*DIMF*4);
    float* XP1 = (float*)salloc((size_t)NN*DIMF*4);
    float* XP2 = (float*)salloc((size_t)NN*DIMF*4);
    float* XU  = (float*)salloc((size_t)NN*DIMF*4);
    float* DN[4]; for (int l = 0; l < 4; ++l) DN[l] = (float*)salloc((size_t)NN*DIMF*4);
    float* Asub[4];
    for (int l = 0; l < 4; ++l) Asub[l] = (float*)salloc((size_t)LVL_K[l]*LVL_K[l]*4);
    float* SC = (float*)salloc(NN*4);
    int*   IDX[4]; for (int l = 0; l < 4; ++l) IDX[l] = (int*)salloc(NN*4);
    float* VAL[4]; for (int l = 0; l < 4; ++l) VAL[l] = (float*)salloc(NN*4);
    float* XC  = (float*)salloc((size_t)NN*2*DIMF*4);
    float* AXC = (float*)salloc((size_t)NN*2*DIMF*4);

    // P3 overlay (eigensolver scratch)
    const size_t PL = (size_t)NN*NN*8;
    double* Z64 = (double*)(SBASE);
    double* FD  = (double*)(SBASE + PL);       // doubles as Pmat during sytrd
    double* FL  = (double*)(SBASE + 2*PL);
    double* FU  = (double*)(SBASE + 3*PL);
    double* FU2 = (double*)(SBASE + 4*PL);
    signed char* FPIV = (signed char*)(SBASE + 5*PL);
    double* Pmat = FD;                         // [jend x NN] p-vectors (zeroed before sytrd)

    // P4 overlay (GSR / refinement)
    const size_t MB8  = (size_t)HRD*NN*4;    // 8 MiB
    const size_t MB16 = (size_t)HRD*HRD*4;   // 16 MiB
    float* P4a   = (float*)(SBASE);               // [2048,1024]
    float* P4t1  = (float*)(SBASE + MB8);         // [2048,1024]
    float* P4adT = (float*)(SBASE);               // [2048,2048]
    float* P4Zb  = (float*)(SBASE + MB16);        // [2048,2048]
    float* P4ZG  = (float*)(SBASE);               // [2048,1024]
    float* P4h1  = (float*)(SBASE + MB8);         // [2048,1024]
    float* P4HG  = (float*)(SBASE + MB16);        // [2048,2048]
    float* P4h2  = (float*)(SBASE);               // [2048,2048]

    // =============== P1: normalized adjacency ===============
    rowsum_rsqrt_k<<<NN, 256, 0, stream>>>(lr, r64, NN);
    build_A_k<<<(NN*NN + 255)/256, 256, 0, stream>>>(lr, r64, A32, A64, NN);

    // =============== P2: graph U-Net (fp32) ===============
    gemmf32(stream, EPI_BIAS, A32, start_w, out_start, NN, DIMF, NN, start_b, nullptr);

    const float* Xcur = out_start;
    const float* Acur = A32;
    float* ping = XP1; float* pong = XP2;
    for (int l = 0; l < 4; ++l){
        int nl = LVL_N[l], kl = LVL_K[l];
        gemmf32(stream, EPI_NONE, Acur, Xcur, XT, nl, DIMF, nl, nullptr, nullptr);
        gemmf32(stream, EPI_BIAS, XT, down_w + (size_t)l*DIMF*DIMF, DN[l], nl, DIMF, DIMF,
                down_b + (size_t)l*DIMF, nullptr);
        score_k<<<(nl + 3)/4, 256, 0, stream>>>(DN[l], pool_w + (size_t)l*DIMF, pool_b + l, SC, nl, DIMF);
        topk_k<<<1, 256, 0, stream>>>(SC, nl, kl, IDX[l], VAL[l]);
        gatherX_k<<<(unsigned)(((size_t)kl*DIMF + 255)/256), 256, 0, stream>>>(DN[l], IDX[l], VAL[l], ping, kl, DIMF);
        gatherA_k<<<(unsigned)(((size_t)kl*kl + 255)/256), 256, 0, stream>>>(Acur, IDX[l], Asub[l], kl, nl);
        Xcur = ping; Acur = Asub[l];
        float* t = ping; ping = pong; pong = t;
    }
    gemmf32(stream, EPI_NONE, Acur, Xcur, XT, 193, DIMF, 193, nullptr, nullptr);
    float* Xb = ping;
    gemmf32(stream, EPI_BIAS, XT, bottom_w, Xb, 193, DIMF, DIMF, bottom_b, nullptr);
    const float* Xup = Xb;
    float* upbuf[2] = { (Xb == XP1) ? XP2 : XP1, (Xb == XP1) ? XP1 : XP2 };
    for (int i2 = 0; i2 < 4; ++i2){
        int jl = 3 - i2;
        int nj = LVL_N[jl];
        int kj = LVL_K[jl];
        fill0_k<<<(unsigned)(((size_t)nj*DIMF + 255)/256), 256, 0, stream>>>(XU, (size_t)nj*DIMF);
        scatterX_k<<<(unsigned)(((size_t)kj*DIMF + 255)/256), 256, 0, stream>>>(Xup, IDX[jl], XU, kj, DIMF);
        const float* Aj = (jl == 0) ? A32 : Asub[jl - 1];
        gemmf32(stream, EPI_NONE, Aj, XU, XT, nj, DIMF, nj, nullptr, nullptr);
        float* Xn = upbuf[i2 & 1];
        gemmf32(stream, EPI_BIAS_ADD, XT, up_w + (size_t)i2*DIMF*DIMF, Xn, nj, DIMF, DIMF,
                up_b + (size_t)i2*DIMF, DN[jl]);
        Xup = Xn;
    }
    concat_k<<<(unsigned)(((size_t)NN*2*DIMF + 255)/256), 256, 0, stream>>>(Xup, out_start, XC, NN, DIMF);
    gemmf32(stream, EPI_NONE, A32, XC, AXC, NN, 2*DIMF, NN, nullptr, nullptr);
    gemmf32(stream, EPI_BIAS, AXC, end_w, out_net, NN, HRD, 2*DIMF, end_b, nullptr);

    // =============== P3: eigendecomposition of A (fp64) ===============
    const int JEND = NN - TB;
    init_sytrd_k<<<4, 256, 0, stream>>>(pvA, barcnt, NN);
    filld0_k<<<(unsigned)(((size_t)JEND*NN + 255)/256), 256, 0, stream>>>(Pmat, (size_t)JEND*NN);
    sytrd_coop3<<<CB2, BT2, 0, stream>>>(A64, dE, dTau, dScl, Pmat, pvA, barcnt, NN, JEND);
    hh_tail<<<1, 256, 0, stream>>>(A64, dE, dTau, dScl, NN);
    extract_de_k<<<4, 256, 0, stream>>>(A64, dD, dE, NN);
    bisect_k<<<4, 256, 0, stream>>>(dD, dE, dWev, NN);
    invit_k<<<4, 256, 0, stream>>>(dD, dE, dWev, FD, FL, FU, FU2, FPIV, Z64, NN);
    for (int g = 15; g >= 0; --g){
        int b0 = g*64;
        int nbsz = (NN - 2) - b0; if (nbsz > 64) nbsz = 64;
        build_V_k<<<(NN*64 + 255)/256, 256, 0, stream>>>(A64, dScl, Vp, NN, b0, nbsz);
        build_T_k<<<1, 256, 0, stream>>>(Vp, dTau, Tm, NN, b0, nbsz);
        int r0 = b0 + 1;
        gemmf64(stream, true,  Vp + (size_t)r0*64, 64, Z64 + (size_t)r0*NN, NN, Yt, NN, nbsz, NN, NN - r0, 1.0, 0.0);
        gemmf64(stream, false, Tm, 64, Yt, NN, W2, NN, nbsz, NN, nbsz, 1.0, 0.0);
        gemmf64(stream, false, Vp + (size_t)r0*64, 64, W2, NN, Z64 + (size_t)r0*NN, NN, NN - r0, NN, nbsz, -1.0, 1.0);
    }
    {
        dim3 g(NN/32, NN/32), b(256);
        transpose_cast_k<<<g, b, 0, stream>>>(Z64, UfT, NN);
    }

    // =============== P4: GSR layer + refinement (fp32) ===============
    build_a_k<<<(unsigned)(((size_t)HRD*NN + 255)/256), 256, 0, stream>>>(gsr_w, P4a);
    gemmf32(stream, EPI_NONE, P4a, UfT, P4t1, HRD, NN, NN, nullptr, nullptr);               // a @ U^T
    gemmf32(stream, EPI_ABS_DIAG1, P4t1, out_net, out_adj, HRD, HRD, NN, nullptr, nullptr); // adj
    {
        dim3 g(HRD/32, HRD/32), b(256);
        transpose32_k<<<g, b, 0, stream>>>(out_adj, P4adT, HRD);                            // adj^T
    }
    gemmf32(stream, EPI_NONE, out_adj, P4adT, P4Zb, HRD, HRD, HRD, nullptr, nullptr);       // adj @ adj^T
    symabs1_k<<<(unsigned)(((size_t)HRD*HRD + 255)/256), 256, 0, stream>>>(P4Zb, HRD);      // Z
    gemmf32(stream, EPI_NONE, P4Zb, gc1, P4ZG, HRD, NN, HRD, nullptr, nullptr);             // Z @ gc1
    gemmf32(stream, EPI_RELU, out_adj, P4ZG, P4h1, HRD, NN, HRD, nullptr, nullptr);         // h1
    gemmf32(stream, EPI_NONE, P4h1, gc2, P4HG, HRD, HRD, NN, nullptr, nullptr);             // h1 @ gc2
    gemmf32(stream, EPI_RELU, out_adj, P4HG, P4h2, HRD, HRD, HRD, nullptr, nullptr);        // h2
    final_z_k<<<(unsigned)(((size_t)HRD*HRD + 255)/256), 256, 0, stream>>>(P4h2, out_z, HRD); // z
}

// Round 7
// 26931.149 us; speedup vs baseline: 2.9590x; 1.6747x over previous
//
#include <hip/hip_runtime.h>
#include <cstddef>
#include <cstdint>
#include <math.h>

// ============================ constants ============================
static constexpr int NN   = 1024;   // lr_dim
static constexpr int HRD  = 2048;   // hr_dim
static constexpr int DIMF = 320;
static constexpr int TB   = 85;     // sytrd LDS tail block (85x87 fp64 = 59 KB LDS)
static constexpr int CB2  = 256;    // persistent sytrd blocks (<= CU count -> co-resident)
static constexpr int BT2  = 1024;   // threads per sytrd block (16 waves)
static constexpr int NGRP = 8;      // barrier tree groups
static constexpr int BPG  = 32;     // blocks per group (CB2 = NGRP*BPG)
static constexpr int NWY  = 16;     // WY reflector groups (64 each)

#define EPI_NONE      0
#define EPI_BIAS      1
#define EPI_BIAS_ADD  2
#define EPI_ABS_DIAG1 3
#define EPI_RELU      4

// ============================ fp32 GEMM 64-tile (fallback, odd K) ============================
template<int EPI>
__global__ __launch_bounds__(256) void gemm32(
    const float* __restrict__ A, const float* __restrict__ B, float* __restrict__ C,
    int M, int N, int K, const float* __restrict__ bias, const float* __restrict__ D)
{
    __shared__ float As[16][65];
    __shared__ float Bs[16][65];
    const int bm = blockIdx.y << 6, bn = blockIdx.x << 6;
    const int tid = threadIdx.x;
    const int tm = (tid >> 4) << 2, tn = (tid & 15) << 2;
    float acc[4][4] = {};
    const int kt = (K + 15) >> 4;
    for (int k0 = 0; k0 < kt; ++k0){
        const int kb = k0 << 4;
        for (int t = tid; t < 1024; t += 256){
            int m = t >> 4, k = t & 15;
            int gm = bm + m, gk = kb + k;
            As[k][m] = (gm < M && gk < K) ? A[(size_t)gm*K + gk] : 0.f;
        }
        for (int t = tid; t < 1024; t += 256){
            int k = t >> 6, nn2 = t & 63;
            int gk = kb + k, gn = bn + nn2;
            Bs[k][nn2] = (gk < K && gn < N) ? B[(size_t)gk*N + gn] : 0.f;
        }
        __syncthreads();
        #pragma unroll
        for (int k = 0; k < 16; ++k){
            float a0 = As[k][tm], a1 = As[k][tm+1], a2 = As[k][tm+2], a3 = As[k][tm+3];
            float b0 = Bs[k][tn], b1 = Bs[k][tn+1], b2 = Bs[k][tn+2], b3 = Bs[k][tn+3];
            acc[0][0] += a0*b0; acc[0][1] += a0*b1; acc[0][2] += a0*b2; acc[0][3] += a0*b3;
            acc[1][0] += a1*b0; acc[1][1] += a1*b1; acc[1][2] += a1*b2; acc[1][3] += a1*b3;
            acc[2][0] += a2*b0; acc[2][1] += a2*b1; acc[2][2] += a2*b2; acc[2][3] += a2*b3;
            acc[3][0] += a3*b0; acc[3][1] += a3*b1; acc[3][2] += a3*b2; acc[3][3] += a3*b3;
        }
        __syncthreads();
    }
    #pragma unroll
    for (int r = 0; r < 4; ++r){
        int gm = bm + tm + r; if (gm >= M) continue;
        #pragma unroll
        for (int c = 0; c < 4; ++c){
            int gn = bn + tn + c; if (gn >= N) continue;
            float v = acc[r][c];
            if (EPI == EPI_BIAS)            v += bias[gn];
            else if (EPI == EPI_BIAS_ADD)   v += bias[gn] + D[(size_t)gm*N + gn];
            else if (EPI == EPI_ABS_DIAG1)  v = (gm == gn) ? 1.0f : fabsf(v);
            else if (EPI == EPI_RELU)       v = fmaxf(v, 0.0f);
            C[(size_t)gm*N + gn] = v;
        }
    }
}

// ============================ fp32 GEMM 128-tile (K%16==0, N%8==0) ============================
template<int EPI>
__global__ __launch_bounds__(256) void gemm128(
    const float* __restrict__ A, const float* __restrict__ B, float* __restrict__ C,
    int M, int N, int K, const float* __restrict__ bias, const float* __restrict__ D)
{
    __shared__ float As[16][132];
    __shared__ float Bs[16][132];
    const int bm = blockIdx.y << 7, bn = blockIdx.x << 7;
    const int tid = threadIdx.x;
    const int tm = (tid >> 4) << 3;
    const int tn = (tid & 15) << 3;
    const int ar = tid >> 1;
    const int ak = (tid & 1) << 3;
    const int br = tid >> 4;
    const int bc = (tid & 15) << 3;
    float acc[8][8] = {};
    for (int kb = 0; kb < K; kb += 16){
        {
            int gm = bm + ar, gk = kb + ak;
            float4 a0, a1;
            if (gm < M){
                const float* p = A + (size_t)gm*K + gk;
                a0 = *(const float4*)p; a1 = *(const float4*)(p + 4);
            } else { a0 = make_float4(0.f,0.f,0.f,0.f); a1 = a0; }
            As[ak+0][ar]=a0.x; As[ak+1][ar]=a0.y; As[ak+2][ar]=a0.z; As[ak+3][ar]=a0.w;
            As[ak+4][ar]=a1.x; As[ak+5][ar]=a1.y; As[ak+6][ar]=a1.z; As[ak+7][ar]=a1.w;
        }
        {
            int gk = kb + br, gn = bn + bc;
            float4 b0, b1;
            if (gn + 7 < N){
                const float* p = B + (size_t)gk*N + gn;
                b0 = *(const float4*)p; b1 = *(const float4*)(p + 4);
            } else {
                float t0[8];
                #pragma unroll
                for (int i = 0; i < 8; ++i){ int g = gn + i; t0[i] = (g < N) ? B[(size_t)gk*N + g] : 0.f; }
                b0 = make_float4(t0[0],t0[1],t0[2],t0[3]); b1 = make_float4(t0[4],t0[5],t0[6],t0[7]);
            }
            *(float4*)&Bs[br][bc] = b0; *(float4*)&Bs[br][bc+4] = b1;
        }
        __syncthreads();
        #pragma unroll
        for (int k = 0; k < 16; ++k){
            float4 a0 = *(const float4*)&As[k][tm];
            float4 a1 = *(const float4*)&As[k][tm+4];
            float4 b0 = *(const float4*)&Bs[k][tn];
            float4 b1 = *(const float4*)&Bs[k][tn+4];
            float av[8] = {a0.x,a0.y,a0.z,a0.w,a1.x,a1.y,a1.z,a1.w};
            float bv[8] = {b0.x,b0.y,b0.z,b0.w,b1.x,b1.y,b1.z,b1.w};
            #pragma unroll
            for (int i = 0; i < 8; ++i)
                #pragma unroll
                for (int jj = 0; jj < 8; ++jj) acc[i][jj] += av[i]*bv[jj];
        }
        __syncthreads();
    }
    #pragma unroll
    for (int i = 0; i < 8; ++i){
        int gm = bm + tm + i; if (gm >= M) continue;
        #pragma unroll
        for (int jj = 0; jj < 8; ++jj){
            int gn = bn + tn + jj; if (gn >= N) continue;
            float v = acc[i][jj];
            if (EPI == EPI_BIAS)            v += bias[gn];
            else if (EPI == EPI_BIAS_ADD)   v += bias[gn] + D[(size_t)gm*N + gn];
            else if (EPI == EPI_ABS_DIAG1)  v = (gm == gn) ? 1.0f : fabsf(v);
            else if (EPI == EPI_RELU)       v = fmaxf(v, 0.0f);
            C[(size_t)gm*N + gn] = v;
        }
    }
}

// ============================ small kernels ============================
__global__ __launch_bounds__(256) void rowsum_rsqrt_k(const float* __restrict__ lr, double* __restrict__ r64, int n)
{
    __shared__ double sm[256];
    int row = blockIdx.x;
    double s = 0.0;
    for (int j = threadIdx.x; j < n; j += 256) s += (double)lr[(size_t)row*n + j];
    sm[threadIdx.x] = s; __syncthreads();
    for (int o = 128; o; o >>= 1){ if (threadIdx.x < o) sm[threadIdx.x] += sm[threadIdx.x + o]; __syncthreads(); }
    if (threadIdx.x == 0){
        double t = sm[0];
        r64[row] = (t > 0.0) ? 1.0/sqrt(t) : 0.0;
    }
}

__global__ __launch_bounds__(256) void build_A_k(const float* __restrict__ lr, const double* __restrict__ r64,
                                                 float* __restrict__ A32, double* __restrict__ A64, int n)
{
    size_t idx = (size_t)blockIdx.x*256 + threadIdx.x;
    if (idx >= (size_t)n*n) return;
    int i = (int)(idx / n), j = (int)(idx % n);
    if (j < i) return;
    double v = (double)lr[(size_t)j*n + i] * r64[i] * r64[j];
    A64[(size_t)i*n + j] = v; A64[(size_t)j*n + i] = v;
    float vf = (float)v;
    A32[(size_t)i*n + j] = vf; A32[(size_t)j*n + i] = vf;
}

__global__ __launch_bounds__(256) void score_k(const float* __restrict__ X, const float* __restrict__ pw,
                                               const float* __restrict__ pb, float* __restrict__ out,
                                               int n, int dim)
{
    int row = blockIdx.x*4 + (threadIdx.x >> 6);
    int lane = threadIdx.x & 63;
    if (row >= n) return;
    float acc = 0.f;
    for (int c = lane; c < dim; c += 64) acc += X[(size_t)row*dim + c]*pw[c];
    #pragma unroll
    for (int o = 32; o; o >>= 1) acc += __shfl_down(acc, o);
    if (lane == 0){
        float t = (acc + pb[0]) * 0.01f;
        out[row] = 1.0f/(1.0f + expf(-t));
    }
}

// jax.lax.top_k semantics: descending value, ties -> lower index first
__global__ __launch_bounds__(256) void topk_k(const float* __restrict__ scores, int n, int k,
                                              int* __restrict__ idxo, float* __restrict__ valo)
{
    __shared__ float s[1024];
    int tid = threadIdx.x;
    for (int i = tid; i < n; i += 256) s[i] = scores[i];
    __syncthreads();
    for (int i = tid; i < n; i += 256){
        float si = s[i]; int r = 0;
        for (int j = 0; j < n; ++j){
            float sj = s[j];
            r += (sj > si) || (sj == si && j < i);
        }
        if (r < k){ idxo[r] = i; valo[r] = si; }
    }
}

__global__ __launch_bounds__(256) void gatherX_k(const float* __restrict__ X, const int* __restrict__ idx,
                                                 const float* __restrict__ vals, float* __restrict__ Xo,
                                                 int k, int dim)
{
    size_t t = (size_t)blockIdx.x*256 + threadIdx.x;
    if (t >= (size_t)k*dim) return;
    int m = (int)(t / dim), c = (int)(t % dim);
    Xo[t] = X[(size_t)idx[m]*dim + c] * vals[m];
}

__global__ __launch_bounds__(256) void scatterX_k(const float* __restrict__ Xs, const int* __restrict__ idx,
                                                  float* __restrict__ Xu, int k, int dim)
{
    size_t t = (size_t)blockIdx.x*256 + threadIdx.x;
    if (t >= (size_t)k*dim) return;
    int m = (int)(t / dim), c = (int)(t % dim);
    Xu[(size_t)idx[m]*dim + c] = Xs[t];
}

__global__ __launch_bounds__(256) void gatherA_k(const float* __restrict__ A, const int* __restrict__ idx,
                                                 float* __restrict__ Ao, int k, int n)
{
    size_t t = (size_t)blockIdx.x*256 + threadIdx.x;
    if (t >= (size_t)k*k) return;
    int m1 = (int)(t / k), m2 = (int)(t % k);
    Ao[t] = A[(size_t)idx[m1]*n + idx[m2]];
}

__global__ __launch_bounds__(256) void fill0_k(float* __restrict__ p, size_t cnt)
{
    size_t t = (size_t)blockIdx.x*256 + threadIdx.x;
    if (t < cnt) p[t] = 0.f;
}

__global__ __launch_bounds__(256) void filld0_k(double* __restrict__ p, size_t cnt)
{
    size_t t = (size_t)blockIdx.x*256 + threadIdx.x;
    if (t < cnt) p[t] = 0.0;
}

__global__ __launch_bounds__(256) void init_sytrd_k(double* __restrict__ pv, unsigned* __restrict__ bar, int n)
{
    int t = blockIdx.x*256 + threadIdx.x;
    if (t < n) pv[t] = 0.0;
    if (t < 1024) bar[t] = 0u;
}

__global__ __launch_bounds__(256) void concat_k(const float* __restrict__ X, const float* __restrict__ orgX,
                                                float* __restrict__ Xc, int n, int dim)
{
    size_t t = (size_t)blockIdx.x*256 + threadIdx.x;
    size_t tot = (size_t)n*2*dim;
    if (t >= tot) return;
    int i = (int)(t / (2*dim)), c = (int)(t % (2*dim));
    Xc[t] = (c < dim) ? X[(size_t)i*dim + c] : orgX[(size_t)i*dim + (c - dim)];
}

__global__ __launch_bounds__(256) void build_a_k(const float* __restrict__ gsr, float* __restrict__ a)
{
    size_t idx = (size_t)blockIdx.x*256 + threadIdx.x;
    if (idx >= (size_t)HRD*NN) return;
    int i = (int)(idx >> 10), k = (int)(idx & 1023);
    a[idx] = gsr[(size_t)i*HRD + k] + gsr[(size_t)i*HRD + NN + k];
}

__global__ __launch_bounds__(256) void symabs1_k(float* __restrict__ Z, int n)
{
    size_t idx = (size_t)blockIdx.x*256 + threadIdx.x;
    if (idx >= (size_t)n*n) return;
    int i = (int)(idx / n), j = (int)(idx % n);
    if (i > j) return;
    float a = Z[(size_t)i*n + j], b = Z[(size_t)j*n + i];
    float v = 0.5f*(a + b);
    float o = (i == j) ? 1.0f : fabsf(v);
    Z[(size_t)i*n + j] = o; Z[(size_t)j*n + i] = o;
}

__global__ __launch_bounds__(256) void final_z_k(const float* __restrict__ h2, float* __restrict__ z, int n)
{
    size_t idx = (size_t)blockIdx.x*256 + threadIdx.x;
    if (idx >= (size_t)n*n) return;
    int i = (int)(idx / n), j = (int)(idx % n);
    if (i > j) return;
    float v = 0.5f*(h2[(size_t)i*n + j] + h2[(size_t)j*n + i]);
    float o = (i == j) ? 1.0f : fabsf(v);
    z[(size_t)i*n + j] = o; z[(size_t)j*n + i] = o;
}

// dst[c][r] = (float)src[r][c]   (n x n, n % 32 == 0)
__global__ __launch_bounds__(256) void transpose_cast_k(const double* __restrict__ src, float* __restrict__ dst, int n)
{
    __shared__ float tile[32][33];
    int r0 = blockIdx.y*32, c0 = blockIdx.x*32;
    int tx = threadIdx.x & 31, ty = threadIdx.x >> 5;
    for (int i = ty; i < 32; i += 8)
        tile[i][tx] = (float)src[(size_t)(r0 + i)*n + (c0 + tx)];
    __syncthreads();
    for (int i = ty; i < 32; i += 8)
        dst[(size_t)(c0 + i)*n + (r0 + tx)] = tile[tx][i];
}

// dst[c][r] = src[r][c]  (n x n, n % 32 == 0)
__global__ __launch_bounds__(256) void transpose32_k(const float* __restrict__ src, float* __restrict__ dst, int n)
{
    __shared__ float tile[32][33];
    int r0 = blockIdx.y*32, c0 = blockIdx.x*32;
    int tx = threadIdx.x & 31, ty = threadIdx.x >> 5;
    for (int i = ty; i < 32; i += 8)
        tile[i][tx] = src[(size_t)(r0 + i)*n + (c0 + tx)];
    __syncthreads();
    for (int i = ty; i < 32; i += 8)
        dst[(size_t)(c0 + i)*n + (r0 + tx)] = tile[tx][i];
}

// ============================ persistent Householder tridiagonalization ============================
// Barrier: RELAXED arrivals + RELAXED spin (no per-poll cache invalidate),
// one release fence before arrival, one acquire fence after exit. Two-level tree.
// [R6 measured: this dropped sytrd 72 ms -> 13.4 ms vs acquire-spin version.]
__device__ __forceinline__ void gbar3(unsigned* __restrict__ bar, unsigned epoch)
{
    __syncthreads();
    if (threadIdx.x == 0){
        __threadfence();   // release
        int g = blockIdx.x >> 5;   // / BPG
        unsigned t = __hip_atomic_fetch_add(&bar[g*32], 1u, __ATOMIC_RELAXED, __HIP_MEMORY_SCOPE_AGENT);
        if ((t & (unsigned)(BPG - 1)) == (unsigned)(BPG - 1))
            __hip_atomic_fetch_add(&bar[256], 1u, __ATOMIC_RELAXED, __HIP_MEMORY_SCOPE_AGENT);
        unsigned target = epoch * (unsigned)NGRP;
        while (__hip_atomic_load(&bar[256], __ATOMIC_RELAXED, __HIP_MEMORY_SCOPE_AGENT) < target)
            __builtin_amdgcn_s_sleep(8);
        __threadfence();   // acquire
    }
    __syncthreads();
}

// One-barrier-per-column fused sytrd (see round-6 notes; unchanged — it matched prediction).
__global__ __launch_bounds__(BT2) void sytrd_coop3(
    double* __restrict__ A, double* __restrict__ e, double* __restrict__ tauA,
    double* __restrict__ sclA, double* __restrict__ P, double* __restrict__ pvA,
    unsigned* __restrict__ bar, int n, int jend)
{
    __shared__ double VP[1024], WP[1024], VJ[1024];
    __shared__ double red16[16];
    __shared__ double sh_b;
    const int tid  = threadIdx.x;
    const int bid  = blockIdx.x;
    const int lane = tid & 63;
    const int wid  = tid >> 6;
    const int gw   = bid*(BT2/64) + wid;
    const int rowUnit = gw >> 2;
    const int chunk   = gw & 3;
    const unsigned gtid = (unsigned)bid*(unsigned)BT2 + (unsigned)tid;
    const unsigned NT   = (unsigned)CB2*(unsigned)BT2;

    double tau_p = 0.0, sc_p = 0.0;
    unsigned ep = 0;

    for (int j = 0; j < jend; ++j){
        const int m = n - 1 - j;
        double* __restrict__ row = A + (size_t)j*n + (j+1);
        double c2_p = 0.0;
        if (j > 0){
            c2_p = 0.5*tau_p*tau_p*pvA[j-1];
            const double* __restrict__ rowp = A + (size_t)(j-1)*n + j;
            const double* __restrict__ pp   = P + (size_t)(j-1)*NN;
            for (int i = tid; i <= m; i += BT2){
                double vp = (i == 0) ? 1.0 : rowp[i]*sc_p;
                VP[i] = vp;
                WP[i] = tau_p*pp[i] - c2_p*vp;
            }
            __syncthreads();
        }
        double s = 0.0;
        if (j > 0){
            double wp0 = WP[0];
            for (int t = tid; t < m; t += BT2){
                double x = row[t] - WP[1+t] - wp0*VP[1+t];
                VJ[t] = x;
                if (t >= 1) s += x*x;
            }
        } else {
            for (int t = tid; t < m; t += BT2){
                double x = row[t];
                VJ[t] = x;
                if (t >= 1) s += x*x;
            }
        }
        #pragma unroll
        for (int o = 32; o; o >>= 1) s += __shfl_down(s, o);
        if (lane == 0) red16[wid] = s;
        __syncthreads();
        if (tid == 0){
            double t2 = 0.0;
            #pragma unroll
            for (int i = 0; i < 16; ++i) t2 += red16[i];
            sh_b = t2;
        }
        __syncthreads();
        double sigma2 = sh_b;
        double alpha = VJ[0];
        double beta, tl, sc;
        if (sigma2 == 0.0){ beta = alpha; tl = 0.0; sc = 0.0; }
        else {
            beta = -copysign(sqrt(alpha*alpha + sigma2), alpha);
            tl = (beta - alpha)/beta;
            sc = 1.0/(alpha - beta);
        }
        if (bid == 0){
            for (int t = tid; t < m; t += BT2) row[t] = VJ[t];
            if (tid == 0){
                e[j] = beta; tauA[j] = tl; sclA[j] = sc;
                if (j > 0) A[(size_t)j*n + j] -= 2.0*WP[0];
            }
        }
        double pvloc = 0.0;
        if (rowUnit < m){
            const int r = rowUnit;
            double* __restrict__ Ar = A + (size_t)(j+1+r)*n + (j+1);
            double acc = 0.0;
            if (j > 0){
                double vpr = VP[1+r], wpr = WP[1+r];
                for (int c = chunk*64 + lane; c < m; c += 256){
                    double a = Ar[c] - (vpr*WP[1+c] + wpr*VP[1+c]);
                    Ar[c] = a;
                    double vj = (c == 0) ? 1.0 : VJ[c]*sc;
                    acc += a*vj;
                }
            } else {
                for (int c = chunk*64 + lane; c < m; c += 256){
                    double a = Ar[c];
                    double vj = (c == 0) ? 1.0 : VJ[c]*sc;
                    acc += a*vj;
                }
            }
            #pragma unroll
            for (int o = 32; o; o >>= 1) acc += __shfl_down(acc, o);
            if (lane == 0){
                atomicAdd(&P[(size_t)j*NN + r], acc);
                double vr = (r == 0) ? 1.0 : VJ[r]*sc;
                pvloc = acc*vr;
            }
        }
        if (lane == 0) red16[wid] = pvloc;
        __syncthreads();
        if (tid == 0){
            double t2 = 0.0;
            #pragma unroll
            for (int i = 0; i < 16; ++i) t2 += red16[i];
            if (t2 != 0.0) atomicAdd(&pvA[j], t2);
        }
        ++ep; gbar3(bar, ep);
        tau_p = tl; sc_p = sc;
    }
    {
        double c2f = 0.5*tau_p*tau_p*pvA[jend-1];
        const double* __restrict__ rowp = A + (size_t)(jend-1)*n + jend;
        const double* __restrict__ pp   = P + (size_t)(jend-1)*NN;
        const int tb = n - jend;
        const unsigned tot = (unsigned)(tb*tb);
        for (unsigned idx = gtid; idx < tot; idx += NT){
            int ri = (int)(idx / (unsigned)tb), ci = (int)(idx % (unsigned)tb);
            double vpr = (ri == 0) ? 1.0 : rowp[ri]*sc_p;
            double wpr = tau_p*pp[ri] - c2f*vpr;
            double vpc = (ci == 0) ? 1.0 : rowp[ci]*sc_p;
            double wpc = tau_p*pp[ci] - c2f*vpc;
            A[(size_t)(jend+ri)*n + (jend+ci)] -= vpr*wpc + wpr*vpc;
        }
    }
}

// Tail: remaining (TB-2) Householder steps entirely in LDS (single block).
__global__ __launch_bounds__(256) void hh_tail(double* __restrict__ A64, double* __restrict__ e,
                                               double* __restrict__ tau, double* __restrict__ scaleg, int n)
{
    __shared__ double T[TB][TB+2];
    __shared__ double v[TB], p[TB], red[256];
    const int base = n - TB;
    const int tid = threadIdx.x;
    for (int t = tid; t < TB*TB; t += 256){
        int r = t / TB, c = t % TB;
        T[r][c] = A64[(size_t)(base + r)*n + base + c];
    }
    __syncthreads();
    for (int l = 0; l <= TB - 3; ++l){
        const int m = TB - 1 - l;
        double s = 0.0;
        for (int i = 1 + tid; i < m; i += 256){ double x = T[l+1+i][l]; s += x*x; }
        red[tid] = s; __syncthreads();
        for (int o = 128; o; o >>= 1){ if (tid < o) red[tid] += red[tid + o]; __syncthreads(); }
        double sigma2 = red[0];
        double alpha = T[l+1][l];
        double beta, tl, sc;
        if (sigma2 == 0.0){ beta = alpha; tl = 0.0; sc = 0.0; }
        else {
            beta = -copysign(sqrt(alpha*alpha + sigma2), alpha);
            tl = (beta - alpha)/beta;
            sc = 1.0/(alpha - beta);
        }
        for (int i = tid; i < m; i += 256) v[i] = (i == 0) ? 1.0 : T[l+1+i][l]*sc;
        __syncthreads();
        for (int i = tid; i < m; i += 256){
            double acc = 0.0;
            for (int c = 0; c < m; ++c) acc += T[l+1+i][l+1+c]*v[c];
            p[i] = acc;
        }
        __syncthreads();
        double s2 = 0.0;
        for (int i = tid; i < m; i += 256) s2 += p[i]*v[i];
        red[tid] = s2; __syncthreads();
        for (int o = 128; o; o >>= 1){ if (tid < o) red[tid] += red[tid + o]; __syncthreads(); }
        double pvv = red[0];
        double c2 = 0.5*tl*tl*pvv;
        for (int t2 = tid; t2 < m*m; t2 += 256){
            int r = t2 / m, c = t2 % m;
            double wr = tl*p[r] - c2*v[r];
            double wc = tl*p[c] - c2*v[c];
            T[l+1+r][l+1+c] -= v[r]*wc + wr*v[c];
        }
        if (tid == 0){ int j = base + l; e[j] = beta; tau[j] = tl; scaleg[j] = 1.0; }
        for (int i = tid; i < m; i += 256) A64[(size_t)(base + l)*n + (base + l + 1) + i] = v[i];
        __syncthreads();
    }
    for (int r = tid; r < TB; r += 256) A64[(size_t)(base + r)*n + base + r] = T[r][r];
    if (tid == 0) A64[(size_t)(n-1)*n + (n-2)] = T[TB-1][TB-2];
}

__global__ __launch_bounds__(256) void extract_de_k(const double* __restrict__ A64, double* __restrict__ d,
                                                    double* __restrict__ e, int n)
{
    int i = blockIdx.x*256 + threadIdx.x;
    if (i < n) d[i] = A64[(size_t)i*n + i];
    if (i == 0) e[n-2] = A64[(size_t)(n-1)*n + (n-2)];
}

// ============================ tridiagonal eigensolver ============================
__global__ __launch_bounds__(256) void bisect_k(const double* __restrict__ d, const double* __restrict__ e,
                                                double* __restrict__ w, int n)
{
    int k = blockIdx.x*256 + threadIdx.x;
    if (k >= n) return;
    double gl = 1e300, gu = -1e300;
    for (int i = 0; i < n; ++i){
        double em = (i > 0) ? fabs(e[i-1]) : 0.0, ep = (i < n-1) ? fabs(e[i]) : 0.0;
        double lo2 = d[i] - em - ep, hi2 = d[i] + em + ep;
        gl = fmin(gl, lo2); gu = fmax(gu, hi2);
    }
    double lo = gl - 1e-10, hi = gu + 1e-10;
    const double pivmin = 1e-280;
    for (int it = 0; it < 42; ++it){
        double mid = 0.5*(lo + hi);
        int cnt = 0; double q = 1.0;
        for (int i = 0; i < n; ++i){
            double t;
            if (i == 0) t = d[0] - mid;
            else { double ei = e[i-1]; t = d[i] - mid - ei*(ei/q); }
            if (fabs(t) < pivmin) t = -pivmin;
            if (t < 0.0) ++cnt;
            q = t;
        }
        if (cnt <= k) lo = mid; else hi = mid;
    }
    w[k] = 0.5*(lo + hi);
}

__global__ __launch_bounds__(256) void invit_k(const double* __restrict__ d, const double* __restrict__ e,
                                               const double* __restrict__ w,
                                               double* __restrict__ FD, double* __restrict__ FL,
                                               double* __restrict__ FU, double* __restrict__ FU2,
                                               signed char* __restrict__ PIV, double* __restrict__ Z, int n)
{
    int k = blockIdx.x*256 + threadIdx.x;
    if (k >= n) return;
    const double lam = w[k];
    const double tiny = 1e-280;
    double dcur = d[0] - lam;
    double ucur = e[0];
    for (int i = 0; i < n-1; ++i){
        double dli = e[i];
        double dnext_init = d[i+1] - lam;
        double unext_init = (i < n-2) ? e[i+1] : 0.0;
        size_t o = (size_t)i*n + k;
        if (fabs(dcur) >= fabs(dli)){
            if (dcur == 0.0) dcur = tiny;
            double f = dli/dcur;
            FD[o] = dcur; FL[o] = f; FU[o] = ucur; FU2[o] = 0.0; PIV[o] = 0;
            dcur = dnext_init - f*ucur;
            ucur = unext_init;
        } else {
            double f = dcur/dli;
            FD[o] = dli; FL[o] = f; FU[o] = dnext_init; FU2[o] = unext_init; PIV[o] = 1;
            dcur = ucur - f*dnext_init;
            ucur = -f*unext_init;
        }
    }
    if (dcur == 0.0) dcur = tiny;
    FD[(size_t)(n-1)*n + k] = dcur;
    for (int i = 0; i < n; ++i){
        unsigned h = (unsigned)(i + 1)*0x9E3779B9u + (unsigned)(k + 1)*0x85EBCA6Bu;
        h ^= h >> 16; h *= 0x7FEB352Du; h ^= h >> 15; h *= 0x846CA68Bu; h ^= h >> 16;
        Z[(size_t)i*n + k] = (double)(h >> 8)*(1.0/16777216.0) - 0.5;
    }
    for (int iter = 0; iter < 2; ++iter){
        double zc = Z[k];
        for (int i = 0; i < n-1; ++i){
            size_t o = (size_t)i*n + k;
            double fl = FL[o];
            double zn = Z[o + n];
            if (!PIV[o]){
                Z[o] = zc;
                zc = zn - fl*zc;
            } else {
                Z[o] = zn;
                zc = zc - fl*zn;
            }
        }
        double za = zc / FD[(size_t)(n-1)*n + k];
        Z[(size_t)(n-1)*n + k] = za;
        size_t o2 = (size_t)(n-2)*n + k;
        double zaa = (Z[o2] - FU[o2]*za) / FD[o2];
        Z[o2] = zaa;
        double zb = za;
        for (int i = n-3; i >= 0; --i){
            size_t o = (size_t)i*n + k;
            double znew = (Z[o] - FU[o]*zaa - FU2[o]*zb) / FD[o];
            Z[o] = znew;
            zb = zaa; zaa = znew;
        }
        double mx = 0.0;
        for (int i = 0; i < n; ++i) mx = fmax(mx, fabs(Z[(size_t)i*n + k]));
        double s = (mx > 0.0) ? 1.0/mx : 1.0;
        for (int i = 0; i < n; ++i) Z[(size_t)i*n + k] *= s;
    }
    double nrm = 0.0;
    for (int i = 0; i < n; ++i){ double v = Z[(size_t)i*n + k]; nrm += v*v; }
    double s = 1.0/sqrt(nrm);
    for (int i = 0; i < n; ++i) Z[(size_t)i*n + k] *= s;
}

// ============================ batched blocked-WY back-transform ============================
// Vbig[g][r][t]: reflector t of group g (j = 64g + t), zero-padded (V[r][t]=0 for r<=j).
__global__ __launch_bounds__(256) void wy_buildV_k(const double* __restrict__ A64, const double* __restrict__ scaleg,
                                                   double* __restrict__ Vbig, int n)
{
    size_t idx = (size_t)blockIdx.x*256 + threadIdx.x;
    if (idx >= (size_t)NWY*1024*64) return;
    int g = (int)(idx >> 16);
    int r = (int)((idx >> 6) & 1023);
    int t = (int)(idx & 63);
    int b0 = g*64;
    int nbsz = (n - 2) - b0; if (nbsz > 64) nbsz = 64;
    double v = 0.0;
    if (t < nbsz){
        int j = b0 + t;
        if (r == j + 1) v = 1.0;
        else if (r > j + 1) v = A64[(size_t)j*n + r]*scaleg[j];
    }
    Vbig[idx] = v;
}

// One block per group: G = V^T V (strict upper), then T recurrence, write Tbig[g] (64x64).
__global__ __launch_bounds__(256) void wy_buildT_k(const double* __restrict__ Vbig, const double* __restrict__ tau,
                                                   double* __restrict__ Tbig, int n)
{
    __shared__ double G[64][65];
    __shared__ double Ts[64][65];
    __shared__ double Vs[32][65];
    const int g = blockIdx.x;
    const int tid = threadIdx.x;
    const double* __restrict__ V = Vbig + ((size_t)g << 16);
    const int b0 = g*64;
    int nbsz = (n - 2) - b0; if (nbsz > 64) nbsz = 64;
    for (int p = tid; p < 64*64; p += 256) G[p >> 6][p & 63] = 0.0;
    __syncthreads();
    for (int rb = b0; rb < n; rb += 32){
        for (int s = tid; s < 2048; s += 256){
            int rr = s >> 6, tt = s & 63;
            Vs[rr][tt] = V[((size_t)(rb + rr) << 6) + tt];
        }
        __syncthreads();
        for (int p = tid; p < 4096; p += 256){
            int t = p >> 6, s2 = p & 63;
            if (t < s2 && s2 < nbsz){
                double acc = 0.0;
                #pragma unroll 8
                for (int rr = 0; rr < 32; ++rr) acc += Vs[rr][t]*Vs[rr][s2];
                G[t][s2] += acc;
            }
        }
        __syncthreads();
    }
    // T recurrence (in LDS)
    for (int t = nbsz - 1; t >= 0; --t){
        for (int u = tid; u < 64; u += 256){
            double val = 0.0;
            if (u == t) val = tau[b0 + t];
            else if (u > t && u < nbsz){
                double s = 0.0;
                for (int s2 = t + 1; s2 <= u; ++s2) s += G[t][s2]*Ts[s2][u];
                val = -tau[b0 + t]*s;
            }
            Ts[t][u] = val;
        }
        __syncthreads();
    }
    for (int p = tid; p < 64*64; p += 256){
        int t = p >> 6, u = p & 63;
        Tbig[((size_t)g << 12) + p] = (t < nbsz) ? Ts[t][u] : 0.0;
    }
}

// Column-parallel WY application: each block owns 16 Z-columns and loops all groups
// locally (no inter-block deps: groups touch all rows but only our columns).
__global__ __launch_bounds__(256) void wy_apply_k(const double* __restrict__ Vbig, const double* __restrict__ Tbig,
                                                  double* __restrict__ Z, int n)
{
    __shared__ double Vs[32][65];   // 16.6 KB
    __shared__ double Zs[32][17];   //  4.4 KB
    __shared__ double Y[64][17];    //  8.7 KB
    __shared__ double W[64][17];    //  8.7 KB
    const int tid = threadIdx.x;
    const int c   = tid & 15;       // column within tile
    const int tq  = tid >> 4;       // 0..15 -> owns t in [tq*4, tq*4+4)
    const int c0  = blockIdx.x * 16;

    for (int g = NWY - 1; g >= 0; --g){
        const double* __restrict__ V = Vbig + ((size_t)g << 16);
        const double* __restrict__ T = Tbig + ((size_t)g << 12);
        const int b0 = g*64;
        // ---- Y = V^T Z (rows b0..n-1; rows < first reflector are zero in V) ----
        double acc0 = 0.0, acc1 = 0.0, acc2 = 0.0, acc3 = 0.0;
        for (int rb = b0; rb < n; rb += 32){
            for (int s = tid; s < 2048; s += 256){
                int rr = s >> 6, tt = s & 63;
                Vs[rr][tt] = V[((size_t)(rb + rr) << 6) + tt];
            }
            for (int s = tid; s < 512; s += 256){
                int rr = s >> 4, cc = s & 15;
                Zs[rr][cc] = Z[(size_t)(rb + rr)*n + c0 + cc];
            }
            __syncthreads();
            #pragma unroll 8
            for (int rr = 0; rr < 32; ++rr){
                double z = Zs[rr][c];
                acc0 += Vs[rr][tq*4+0]*z;
                acc1 += Vs[rr][tq*4+1]*z;
                acc2 += Vs[rr][tq*4+2]*z;
                acc3 += Vs[rr][tq*4+3]*z;
            }
            __syncthreads();
        }
        Y[tq*4+0][c] = acc0; Y[tq*4+1][c] = acc1; Y[tq*4+2][c] = acc2; Y[tq*4+3][c] = acc3;
        __syncthreads();
        // ---- W = T * Y (T upper triangular) ----
        #pragma unroll
        for (int i = 0; i < 4; ++i){
            int t = tq*4 + i;
            double a = 0.0;
            for (int s = t; s < 64; ++s) a += T[(t << 6) + s]*Y[s][c];
            W[t][c] = a;
        }
        __syncthreads();
        // ---- Z -= V * W ----
        for (int rb = b0; rb < n; rb += 32){
            for (int s = tid; s < 2048; s += 256){
                int rr = s >> 6, tt = s & 63;
                Vs[rr][tt] = V[((size_t)(rb + rr) << 6) + tt];
            }
            __syncthreads();
            #pragma unroll
            for (int half = 0; half < 2; ++half){
                int item = tid + half*256;
                int rr = item >> 4, cc = item & 15;
                double s = 0.0;
                #pragma unroll 16
                for (int t = 0; t < 64; ++t) s += Vs[rr][t]*W[t][cc];
                Z[(size_t)(rb + rr)*n + c0 + cc] -= s;
            }
            __syncthreads();
        }
        __syncthreads();
    }
}

// ============================ host dispatch helpers ============================
static void gemmf32(hipStream_t st, int epi,
                    const float* A, const float* B, float* C, int M, int N, int K,
                    const float* bias, const float* D)
{
    if ((K & 15) == 0 && (N & 7) == 0){
        dim3 g((N + 127)/128, (M + 127)/128), b(256);
        switch (epi){
        case EPI_NONE:      gemm128<EPI_NONE><<<g, b, 0, st>>>(A, B, C, M, N, K, bias, D); break;
        case EPI_BIAS:      gemm128<EPI_BIAS><<<g, b, 0, st>>>(A, B, C, M, N, K, bias, D); break;
        case EPI_BIAS_ADD:  gemm128<EPI_BIAS_ADD><<<g, b, 0, st>>>(A, B, C, M, N, K, bias, D); break;
        case EPI_ABS_DIAG1: gemm128<EPI_ABS_DIAG1><<<g, b, 0, st>>>(A, B, C, M, N, K, bias, D); break;
        case EPI_RELU:      gemm128<EPI_RELU><<<g, b, 0, st>>>(A, B, C, M, N, K, bias, D); break;
        }
    } else {
        dim3 g((N + 63)/64, (M + 63)/64), b(256);
        switch (epi){
        case EPI_NONE:      gemm32<EPI_NONE><<<g, b, 0, st>>>(A, B, C, M, N, K, bias, D); break;
        case EPI_BIAS:      gemm32<EPI_BIAS><<<g, b, 0, st>>>(A, B, C, M, N, K, bias, D); break;
        case EPI_BIAS_ADD:  gemm32<EPI_BIAS_ADD><<<g, b, 0, st>>>(A, B, C, M, N, K, bias, D); break;
        case EPI_ABS_DIAG1: gemm32<EPI_ABS_DIAG1><<<g, b, 0, st>>>(A, B, C, M, N, K, bias, D); break;
        case EPI_RELU:      gemm32<EPI_RELU><<<g, b, 0, st>>>(A, B, C, M, N, K, bias, D); break;
        }
    }
}

// ============================ kernel_launch ============================
extern "C" void kernel_launch(void* const* d_in, const int* in_sizes, int n_in,
                              void* d_out, int out_size, void* d_ws, size_t ws_size,
                              hipStream_t stream)
{
    (void)in_sizes; (void)n_in; (void)out_size; (void)ws_size;
    const float* lr       = (const float*)d_in[0];
    const float* gsr_w    = (const float*)d_in[1];
    const float* start_w  = (const float*)d_in[2];
    const float* start_b  = (const float*)d_in[3];
    const float* down_w   = (const float*)d_in[4];
    const float* down_b   = (const float*)d_in[5];
    const float* pool_w   = (const float*)d_in[6];
    const float* pool_b   = (const float*)d_in[7];
    const float* bottom_w = (const float*)d_in[8];
    const float* bottom_b = (const float*)d_in[9];
    const float* end_w    = (const float*)d_in[10];
    const float* end_b    = (const float*)d_in[11];
    const float* up_w     = (const float*)d_in[12];
    const float* up_b     = (const float*)d_in[13];
    const float* gc1      = (const float*)d_in[14];
    const float* gc2      = (const float*)d_in[15];

    float* out_z     = (float*)d_out;                       // [2048,2048]
    float* out_net   = out_z + (size_t)HRD*HRD;             // [1024,2048]
    float* out_start = out_net + (size_t)NN*HRD;            // [1024,320]
    float* out_adj   = out_start + (size_t)NN*DIMF;         // [2048,2048]

    static const int LVL_N[4] = {1024, 921, 644, 386};
    static const int LVL_K[4] = {921, 644, 386, 193};

    // -------- workspace arena --------
    char* Wb = (char*)d_ws;
    size_t off = 0;
    auto alloc = [&](size_t bb)->char*{ char* p = Wb + off; off = (off + bb + 255) & ~(size_t)255; return p; };

    float*  A32  = (float*) alloc((size_t)NN*NN*4);
    double* A64  = (double*)alloc((size_t)NN*NN*8);
    float*  UfT  = (float*) alloc((size_t)NN*NN*4);   // U^T as [k][j] fp32
    double* r64  = (double*)alloc(NN*8);
    double* dD   = (double*)alloc(NN*8);
    double* dE   = (double*)alloc(NN*8);
    double* dTau = (double*)alloc(NN*8);
    double* dScl = (double*)alloc(NN*8);
    double* dWev = (double*)alloc(NN*8);
    double* pvA  = (double*)alloc(NN*8);
    unsigned* barcnt = (unsigned*)alloc(8192);
    char* SBASE = Wb + off;

    // P2 overlay (U-Net)
    size_t so = 0;
    auto salloc = [&](size_t bb)->char*{ char* p = SBASE + so; so = (so + bb + 255) & ~(size_t)255; return p; };
    float* XT  = (float*)salloc((size_t)NN*DIMF*4);
    float* XP1 = (float*)salloc((size_t)NN*DIMF*4);
    float* XP2 = (float*)salloc((size_t)NN*DIMF*4);
    float* XU  = (float*)salloc((size_t)NN*DIMF*4);
    float* DN[4]; for (int l = 0; l < 4; ++l) DN[l] = (float*)salloc((size_t)NN*DIMF*4);
    float* Asub[4];
    for (int l = 0; l < 4; ++l) Asub[l] = (float*)salloc((size_t)LVL_K[l]*LVL_K[l]*4);
    float* SC = (float*)salloc(NN*4);
    int*   IDX[4]; for (int l = 0; l < 4; ++l) IDX[l] = (int*)salloc(NN*4);
    float* VAL[4]; for (int l = 0; l < 4; ++l) VAL[l] = (float*)salloc(NN*4);
    float* XC  = (float*)salloc((size_t)NN*2*DIMF*4);
    float* AXC = (float*)salloc((size_t)NN*2*DIMF*4);

    // P3 overlay (eigensolver scratch)
    const size_t PL = (size_t)NN*NN*8;
    double* Z64 = (double*)(SBASE);
    double* FD  = (double*)(SBASE + PL);       // doubles as Pmat during sytrd, Vbig during WY
    double* FL  = (double*)(SBASE + 2*PL);     // doubles as Tbig during WY
    double* FU  = (double*)(SBASE + 3*PL);
    double* FU2 = (double*)(SBASE + 4*PL);
    signed char* FPIV = (signed char*)(SBASE + 5*PL);
    double* Pmat = FD;                         // [jend x NN] p-vectors (zeroed before sytrd)
    double* Vbig = FD;                         // [16][1024][64] = 8 MB (after invit)
    double* Tbig = FL;                         // [16][64][64]   = 0.5 MB (after invit)

    // P4 overlay (GSR / refinement)
    const size_t MB8  = (size_t)HRD*NN*4;    // 8 MiB
    const size_t MB16 = (size_t)HRD*HRD*4;   // 16 MiB
    float* P4a   = (float*)(SBASE);               // [2048,1024]
    float* P4t1  = (float*)(SBASE + MB8);         // [2048,1024]
    float* P4adT = (float*)(SBASE);               // [2048,2048]
    float* P4Zb  = (float*)(SBASE + MB16);        // [2048,2048]
    float* P4ZG  = (float*)(SBASE);               // [2048,1024]
    float* P4h1  = (float*)(SBASE + MB8);         // [2048,1024]
    float* P4HG  = (float*)(SBASE + MB16);        // [2048,2048]
    float* P4h2  = (float*)(SBASE);               // [2048,2048]

    // =============== P1: normalized adjacency ===============
    rowsum_rsqrt_k<<<NN, 256, 0, stream>>>(lr, r64, NN);
    build_A_k<<<(NN*NN + 255)/256, 256, 0, stream>>>(lr, r64, A32, A64, NN);

    // =============== P2: graph U-Net (fp32) ===============
    gemmf32(stream, EPI_BIAS, A32, start_w, out_start, NN, DIMF, NN, start_b, nullptr);

    const float* Xcur = out_start;
    const float* Acur = A32;
    float* ping = XP1; float* pong = XP2;
    for (int l = 0; l < 4; ++l){
        int nl = LVL_N[l], kl = LVL_K[l];
        gemmf32(stream, EPI_NONE, Acur, Xcur, XT, nl, DIMF, nl, nullptr, nullptr);
        gemmf32(stream, EPI_BIAS, XT, down_w + (size_t)l*DIMF*DIMF, DN[l], nl, DIMF, DIMF,
                down_b + (size_t)l*DIMF, nullptr);
        score_k<<<(nl + 3)/4, 256, 0, stream>>>(DN[l], pool_w + (size_t)l*DIMF, pool_b + l, SC, nl, DIMF);
        topk_k<<<1, 256, 0, stream>>>(SC, nl, kl, IDX[l], VAL[l]);
        gatherX_k<<<(unsigned)(((size_t)kl*DIMF + 255)/256), 256, 0, stream>>>(DN[l], IDX[l], VAL[l], ping, kl, DIMF);
        gatherA_k<<<(unsigned)(((size_t)kl*kl + 255)/256), 256, 0, stream>>>(Acur, IDX[l], Asub[l], kl, nl);
        Xcur = ping; Acur = Asub[l];
        float* t = ping; ping = pong; pong = t;
    }
    gemmf32(stream, EPI_NONE, Acur, Xcur, XT, 193, DIMF, 193, nullptr, nullptr);
    float* Xb = ping;
    gemmf32(stream, EPI_BIAS, XT, bottom_w, Xb, 193, DIMF, DIMF, bottom_b, nullptr);
    const float* Xup = Xb;
    float* upbuf[2] = { (Xb == XP1) ? XP2 : XP1, (Xb == XP1) ? XP1 : XP2 };
    for (int i2 = 0; i2 < 4; ++i2){
        int jl = 3 - i2;
        int nj = LVL_N[jl];
        int kj = LVL_K[jl];
        fill0_k<<<(unsigned)(((size_t)nj*DIMF + 255)/256), 256, 0, stream>>>(XU, (size_t)nj*DIMF);
        scatterX_k<<<(unsigned)(((size_t)kj*DIMF + 255)/256), 256, 0, stream>>>(Xup, IDX[jl], XU, kj, DIMF);
        const float* Aj = (jl == 0) ? A32 : Asub[jl - 1];
        gemmf32(stream, EPI_NONE, Aj, XU, XT, nj, DIMF, nj, nullptr, nullptr);
        float* Xn = upbuf[i2 & 1];
        gemmf32(stream, EPI_BIAS_ADD, XT, up_w + (size_t)i2*DIMF*DIMF, Xn, nj, DIMF, DIMF,
                up_b + (size_t)i2*DIMF, DN[jl]);
        Xup = Xn;
    }
    concat_k<<<(unsigned)(((size_t)NN*2*DIMF + 255)/256), 256, 0, stream>>>(Xup, out_start, XC, NN, DIMF);
    gemmf32(stream, EPI_NONE, A32, XC, AXC, NN, 2*DIMF, NN, nullptr, nullptr);
    gemmf32(stream, EPI_BIAS, AXC, end_w, out_net, NN, HRD, 2*DIMF, end_b, nullptr);

    // =============== P3: eigendecomposition of A (fp64) ===============
    const int JEND = NN - TB;
    init_sytrd_k<<<4, 256, 0, stream>>>(pvA, barcnt, NN);
    filld0_k<<<(unsigned)(((size_t)JEND*NN + 255)/256), 256, 0, stream>>>(Pmat, (size_t)JEND*NN);
    sytrd_coop3<<<CB2, BT2, 0, stream>>>(A64, dE, dTau, dScl, Pmat, pvA, barcnt, NN, JEND);
    hh_tail<<<1, 256, 0, stream>>>(A64, dE, dTau, dScl, NN);
    extract_de_k<<<4, 256, 0, stream>>>(A64, dD, dE, NN);
    bisect_k<<<4, 256, 0, stream>>>(dD, dE, dWev, NN);
    invit_k<<<4, 256, 0, stream>>>(dD, dE, dWev, FD, FL, FU, FU2, FPIV, Z64, NN);
    // batched WY back-transform: 3 launches, column-parallel application
    wy_buildV_k<<<(unsigned)(((size_t)NWY*1024*64 + 255)/256), 256, 0, stream>>>(A64, dScl, Vbig, NN);
    wy_buildT_k<<<NWY, 256, 0, stream>>>(Vbig, dTau, Tbig, NN);
    wy_apply_k<<<NN/16, 256, 0, stream>>>(Vbig, Tbig, Z64, NN);
    {
        dim3 g(NN/32, NN/32), b(256);
        transpose_cast_k<<<g, b, 0, stream>>>(Z64, UfT, NN);
    }

    // =============== P4: GSR layer + refinement (fp32) ===============
    build_a_k<<<(unsigned)(((size_t)HRD*NN + 255)/256), 256, 0, stream>>>(gsr_w, P4a);
    gemmf32(stream, EPI_NONE, P4a, UfT, P4t1, HRD, NN, NN, nullptr, nullptr);               // a @ U^T
    gemmf32(stream, EPI_ABS_DIAG1, P4t1, out_net, out_adj, HRD, HRD, NN, nullptr, nullptr); // adj
    {
        dim3 g(HRD/32, HRD/32), b(256);
        transpose32_k<<<g, b, 0, stream>>>(out_adj, P4adT, HRD);                            // adj^T
    }
    gemmf32(stream, EPI_NONE, out_adj, P4adT, P4Zb, HRD, HRD, HRD, nullptr, nullptr);       // adj @ adj^T
    symabs1_k<<<(unsigned)(((size_t)HRD*HRD + 255)/256), 256, 0, stream>>>(P4Zb, HRD);      // Z
    gemmf32(stream, EPI_NONE, P4Zb, gc1, P4ZG, HRD, NN, HRD, nullptr, nullptr);             // Z @ gc1
    gemmf32(stream, EPI_RELU, out_adj, P4ZG, P4h1, HRD, NN, HRD, nullptr, nullptr);         // h1
    gemmf32(stream, EPI_NONE, P4h1, gc2, P4HG, HRD, HRD, NN, nullptr, nullptr);             // h1 @ gc2
    gemmf32(stream, EPI_RELU, out_adj, P4HG, P4h2, HRD, HRD, HRD, nullptr, nullptr);        // h2
    final_z_k<<<(unsigned)(((size_t)HRD*HRD + 255)/256), 256, 0, stream>>>(P4h2, out_z, HRD); // z
}

// Round 8
// 24069.547 us; speedup vs baseline: 3.3107x; 1.1189x over previous
//
#include <hip/hip_runtime.h>
#include <cstddef>
#include <cstdint>
#include <math.h>

// ============================ constants ============================
static constexpr int NN   = 1024;   // lr_dim
static constexpr int HRD  = 2048;   // hr_dim
static constexpr int DIMF = 320;
static constexpr int TB   = 85;     // sytrd LDS tail block (85x87 fp64 = 59 KB LDS)
static constexpr int CB2  = 256;    // persistent sytrd blocks (<= CU count -> co-resident)
static constexpr int BT2  = 1024;   // threads per sytrd block (16 waves)
static constexpr int NGRP = 8;      // barrier tree groups
static constexpr int BPG  = 32;     // blocks per group (CB2 = NGRP*BPG)
static constexpr int NWY  = 16;     // WY reflector groups (64 each)

#define EPI_NONE      0
#define EPI_BIAS      1
#define EPI_BIAS_ADD  2
#define EPI_ABS_DIAG1 3
#define EPI_RELU      4

// agent-scope coherent access helpers (sc1): bypass stale per-XCD L2 without fences.
// [R6 measured: RELAXED agent loads observe remote atomicAdds -> coherent read path works]
__device__ __forceinline__ double gload(const double* p){
    return __hip_atomic_load(p, __ATOMIC_RELAXED, __HIP_MEMORY_SCOPE_AGENT);
}
__device__ __forceinline__ void gstore(double* p, double v){
    __hip_atomic_store(p, v, __ATOMIC_RELAXED, __HIP_MEMORY_SCOPE_AGENT);
}

// ============================ fp32 GEMM 64-tile (fallback, odd K) ============================
template<int EPI>
__global__ __launch_bounds__(256) void gemm32(
    const float* __restrict__ A, const float* __restrict__ B, float* __restrict__ C,
    int M, int N, int K, const float* __restrict__ bias, const float* __restrict__ D)
{
    __shared__ float As[16][65];
    __shared__ float Bs[16][65];
    const int bm = blockIdx.y << 6, bn = blockIdx.x << 6;
    const int tid = threadIdx.x;
    const int tm = (tid >> 4) << 2, tn = (tid & 15) << 2;
    float acc[4][4] = {};
    const int kt = (K + 15) >> 4;
    for (int k0 = 0; k0 < kt; ++k0){
        const int kb = k0 << 4;
        for (int t = tid; t < 1024; t += 256){
            int m = t >> 4, k = t & 15;
            int gm = bm + m, gk = kb + k;
            As[k][m] = (gm < M && gk < K) ? A[(size_t)gm*K + gk] : 0.f;
        }
        for (int t = tid; t < 1024; t += 256){
            int k = t >> 6, nn2 = t & 63;
            int gk = kb + k, gn = bn + nn2;
            Bs[k][nn2] = (gk < K && gn < N) ? B[(size_t)gk*N + gn] : 0.f;
        }
        __syncthreads();
        #pragma unroll
        for (int k = 0; k < 16; ++k){
            float a0 = As[k][tm], a1 = As[k][tm+1], a2 = As[k][tm+2], a3 = As[k][tm+3];
            float b0 = Bs[k][tn], b1 = Bs[k][tn+1], b2 = Bs[k][tn+2], b3 = Bs[k][tn+3];
            acc[0][0] += a0*b0; acc[0][1] += a0*b1; acc[0][2] += a0*b2; acc[0][3] += a0*b3;
            acc[1][0] += a1*b0; acc[1][1] += a1*b1; acc[1][2] += a1*b2; acc[1][3] += a1*b3;
            acc[2][0] += a2*b0; acc[2][1] += a2*b1; acc[2][2] += a2*b2; acc[2][3] += a2*b3;
            acc[3][0] += a3*b0; acc[3][1] += a3*b1; acc[3][2] += a3*b2; acc[3][3] += a3*b3;
        }
        __syncthreads();
    }
    #pragma unroll
    for (int r = 0; r < 4; ++r){
        int gm = bm + tm + r; if (gm >= M) continue;
        #pragma unroll
        for (int c = 0; c < 4; ++c){
            int gn = bn + tn + c; if (gn >= N) continue;
            float v = acc[r][c];
            if (EPI == EPI_BIAS)            v += bias[gn];
            else if (EPI == EPI_BIAS_ADD)   v += bias[gn] + D[(size_t)gm*N + gn];
            else if (EPI == EPI_ABS_DIAG1)  v = (gm == gn) ? 1.0f : fabsf(v);
            else if (EPI == EPI_RELU)       v = fmaxf(v, 0.0f);
            C[(size_t)gm*N + gn] = v;
        }
    }
}

// ============================ fp32 GEMM 128-tile (K%16==0, N%8==0) ============================
template<int EPI>
__global__ __launch_bounds__(256) void gemm128(
    const float* __restrict__ A, const float* __restrict__ B, float* __restrict__ C,
    int M, int N, int K, const float* __restrict__ bias, const float* __restrict__ D)
{
    __shared__ float As[16][132];
    __shared__ float Bs[16][132];
    const int bm = blockIdx.y << 7, bn = blockIdx.x << 7;
    const int tid = threadIdx.x;
    const int tm = (tid >> 4) << 3;
    const int tn = (tid & 15) << 3;
    const int ar = tid >> 1;
    const int ak = (tid & 1) << 3;
    const int br = tid >> 4;
    const int bc = (tid & 15) << 3;
    float acc[8][8] = {};
    for (int kb = 0; kb < K; kb += 16){
        {
            int gm = bm + ar, gk = kb + ak;
            float4 a0, a1;
            if (gm < M){
                const float* p = A + (size_t)gm*K + gk;
                a0 = *(const float4*)p; a1 = *(const float4*)(p + 4);
            } else { a0 = make_float4(0.f,0.f,0.f,0.f); a1 = a0; }
            As[ak+0][ar]=a0.x; As[ak+1][ar]=a0.y; As[ak+2][ar]=a0.z; As[ak+3][ar]=a0.w;
            As[ak+4][ar]=a1.x; As[ak+5][ar]=a1.y; As[ak+6][ar]=a1.z; As[ak+7][ar]=a1.w;
        }
        {
            int gk = kb + br, gn = bn + bc;
            float4 b0, b1;
            if (gn + 7 < N){
                const float* p = B + (size_t)gk*N + gn;
                b0 = *(const float4*)p; b1 = *(const float4*)(p + 4);
            } else {
                float t0[8];
                #pragma unroll
                for (int i = 0; i < 8; ++i){ int g = gn + i; t0[i] = (g < N) ? B[(size_t)gk*N + g] : 0.f; }
                b0 = make_float4(t0[0],t0[1],t0[2],t0[3]); b1 = make_float4(t0[4],t0[5],t0[6],t0[7]);
            }
            *(float4*)&Bs[br][bc] = b0; *(float4*)&Bs[br][bc+4] = b1;
        }
        __syncthreads();
        #pragma unroll
        for (int k = 0; k < 16; ++k){
            float4 a0 = *(const float4*)&As[k][tm];
            float4 a1 = *(const float4*)&As[k][tm+4];
            float4 b0 = *(const float4*)&Bs[k][tn];
            float4 b1 = *(const float4*)&Bs[k][tn+4];
            float av[8] = {a0.x,a0.y,a0.z,a0.w,a1.x,a1.y,a1.z,a1.w};
            float bv[8] = {b0.x,b0.y,b0.z,b0.w,b1.x,b1.y,b1.z,b1.w};
            #pragma unroll
            for (int i = 0; i < 8; ++i)
                #pragma unroll
                for (int jj = 0; jj < 8; ++jj) acc[i][jj] += av[i]*bv[jj];
        }
        __syncthreads();
    }
    #pragma unroll
    for (int i = 0; i < 8; ++i){
        int gm = bm + tm + i; if (gm >= M) continue;
        #pragma unroll
        for (int jj = 0; jj < 8; ++jj){
            int gn = bn + tn + jj; if (gn >= N) continue;
            float v = acc[i][jj];
            if (EPI == EPI_BIAS)            v += bias[gn];
            else if (EPI == EPI_BIAS_ADD)   v += bias[gn] + D[(size_t)gm*N + gn];
            else if (EPI == EPI_ABS_DIAG1)  v = (gm == gn) ? 1.0f : fabsf(v);
            else if (EPI == EPI_RELU)       v = fmaxf(v, 0.0f);
            C[(size_t)gm*N + gn] = v;
        }
    }
}

// ============================ small kernels ============================
__global__ __launch_bounds__(256) void rowsum_rsqrt_k(const float* __restrict__ lr, double* __restrict__ r64, int n)
{
    __shared__ double sm[256];
    int row = blockIdx.x;
    double s = 0.0;
    for (int j = threadIdx.x; j < n; j += 256) s += (double)lr[(size_t)row*n + j];
    sm[threadIdx.x] = s; __syncthreads();
    for (int o = 128; o; o >>= 1){ if (threadIdx.x < o) sm[threadIdx.x] += sm[threadIdx.x + o]; __syncthreads(); }
    if (threadIdx.x == 0){
        double t = sm[0];
        r64[row] = (t > 0.0) ? 1.0/sqrt(t) : 0.0;
    }
}

__global__ __launch_bounds__(256) void build_A_k(const float* __restrict__ lr, const double* __restrict__ r64,
                                                 float* __restrict__ A32, double* __restrict__ A64, int n)
{
    size_t idx = (size_t)blockIdx.x*256 + threadIdx.x;
    if (idx >= (size_t)n*n) return;
    int i = (int)(idx / n), j = (int)(idx % n);
    if (j < i) return;
    double v = (double)lr[(size_t)j*n + i] * r64[i] * r64[j];
    A64[(size_t)i*n + j] = v; A64[(size_t)j*n + i] = v;
    float vf = (float)v;
    A32[(size_t)i*n + j] = vf; A32[(size_t)j*n + i] = vf;
}

__global__ __launch_bounds__(256) void score_k(const float* __restrict__ X, const float* __restrict__ pw,
                                               const float* __restrict__ pb, float* __restrict__ out,
                                               int n, int dim)
{
    int row = blockIdx.x*4 + (threadIdx.x >> 6);
    int lane = threadIdx.x & 63;
    if (row >= n) return;
    float acc = 0.f;
    for (int c = lane; c < dim; c += 64) acc += X[(size_t)row*dim + c]*pw[c];
    #pragma unroll
    for (int o = 32; o; o >>= 1) acc += __shfl_down(acc, o);
    if (lane == 0){
        float t = (acc + pb[0]) * 0.01f;
        out[row] = 1.0f/(1.0f + expf(-t));
    }
}

// jax.lax.top_k semantics: descending value, ties -> lower index first
__global__ __launch_bounds__(256) void topk_k(const float* __restrict__ scores, int n, int k,
                                              int* __restrict__ idxo, float* __restrict__ valo)
{
    __shared__ float s[1024];
    int tid = threadIdx.x;
    for (int i = tid; i < n; i += 256) s[i] = scores[i];
    __syncthreads();
    for (int i = tid; i < n; i += 256){
        float si = s[i]; int r = 0;
        for (int j = 0; j < n; ++j){
            float sj = s[j];
            r += (sj > si) || (sj == si && j < i);
        }
        if (r < k){ idxo[r] = i; valo[r] = si; }
    }
}

__global__ __launch_bounds__(256) void gatherX_k(const float* __restrict__ X, const int* __restrict__ idx,
                                                 const float* __restrict__ vals, float* __restrict__ Xo,
                                                 int k, int dim)
{
    size_t t = (size_t)blockIdx.x*256 + threadIdx.x;
    if (t >= (size_t)k*dim) return;
    int m = (int)(t / dim), c = (int)(t % dim);
    Xo[t] = X[(size_t)idx[m]*dim + c] * vals[m];
}

__global__ __launch_bounds__(256) void scatterX_k(const float* __restrict__ Xs, const int* __restrict__ idx,
                                                  float* __restrict__ Xu, int k, int dim)
{
    size_t t = (size_t)blockIdx.x*256 + threadIdx.x;
    if (t >= (size_t)k*dim) return;
    int m = (int)(t / dim), c = (int)(t % dim);
    Xu[(size_t)idx[m]*dim + c] = Xs[t];
}

__global__ __launch_bounds__(256) void gatherA_k(const float* __restrict__ A, const int* __restrict__ idx,
                                                 float* __restrict__ Ao, int k, int n)
{
    size_t t = (size_t)blockIdx.x*256 + threadIdx.x;
    if (t >= (size_t)k*k) return;
    int m1 = (int)(t / k), m2 = (int)(t % k);
    Ao[t] = A[(size_t)idx[m1]*n + idx[m2]];
}

__global__ __launch_bounds__(256) void fill0_k(float* __restrict__ p, size_t cnt)
{
    size_t t = (size_t)blockIdx.x*256 + threadIdx.x;
    if (t < cnt) p[t] = 0.f;
}

__global__ __launch_bounds__(256) void filld0_k(double* __restrict__ p, size_t cnt)
{
    size_t t = (size_t)blockIdx.x*256 + threadIdx.x;
    if (t < cnt) p[t] = 0.0;
}

__global__ __launch_bounds__(256) void init_sytrd_k(double* __restrict__ pv, unsigned* __restrict__ bar, int n)
{
    int t = blockIdx.x*256 + threadIdx.x;
    if (t < n) pv[t] = 0.0;
    if (t < 1024) bar[t] = 0u;
}

__global__ __launch_bounds__(256) void concat_k(const float* __restrict__ X, const float* __restrict__ orgX,
                                                float* __restrict__ Xc, int n, int dim)
{
    size_t t = (size_t)blockIdx.x*256 + threadIdx.x;
    size_t tot = (size_t)n*2*dim;
    if (t >= tot) return;
    int i = (int)(t / (2*dim)), c = (int)(t % (2*dim));
    Xc[t] = (c < dim) ? X[(size_t)i*dim + c] : orgX[(size_t)i*dim + (c - dim)];
}

__global__ __launch_bounds__(256) void build_a_k(const float* __restrict__ gsr, float* __restrict__ a)
{
    size_t idx = (size_t)blockIdx.x*256 + threadIdx.x;
    if (idx >= (size_t)HRD*NN) return;
    int i = (int)(idx >> 10), k = (int)(idx & 1023);
    a[idx] = gsr[(size_t)i*HRD + k] + gsr[(size_t)i*HRD + NN + k];
}

__global__ __launch_bounds__(256) void symabs1_k(float* __restrict__ Z, int n)
{
    size_t idx = (size_t)blockIdx.x*256 + threadIdx.x;
    if (idx >= (size_t)n*n) return;
    int i = (int)(idx / n), j = (int)(idx % n);
    if (i > j) return;
    float a = Z[(size_t)i*n + j], b = Z[(size_t)j*n + i];
    float v = 0.5f*(a + b);
    float o = (i == j) ? 1.0f : fabsf(v);
    Z[(size_t)i*n + j] = o; Z[(size_t)j*n + i] = o;
}

__global__ __launch_bounds__(256) void final_z_k(const float* __restrict__ h2, float* __restrict__ z, int n)
{
    size_t idx = (size_t)blockIdx.x*256 + threadIdx.x;
    if (idx >= (size_t)n*n) return;
    int i = (int)(idx / n), j = (int)(idx % n);
    if (i > j) return;
    float v = 0.5f*(h2[(size_t)i*n + j] + h2[(size_t)j*n + i]);
    float o = (i == j) ? 1.0f : fabsf(v);
    z[(size_t)i*n + j] = o; z[(size_t)j*n + i] = o;
}

// dst[c][r] = (float)src[r][c]   (n x n, n % 32 == 0)
__global__ __launch_bounds__(256) void transpose_cast_k(const double* __restrict__ src, float* __restrict__ dst, int n)
{
    __shared__ float tile[32][33];
    int r0 = blockIdx.y*32, c0 = blockIdx.x*32;
    int tx = threadIdx.x & 31, ty = threadIdx.x >> 5;
    for (int i = ty; i < 32; i += 8)
        tile[i][tx] = (float)src[(size_t)(r0 + i)*n + (c0 + tx)];
    __syncthreads();
    for (int i = ty; i < 32; i += 8)
        dst[(size_t)(c0 + i)*n + (r0 + tx)] = tile[tx][i];
}

// dst[c][r] = src[r][c]  (n x n, n % 32 == 0)
__global__ __launch_bounds__(256) void transpose32_k(const float* __restrict__ src, float* __restrict__ dst, int n)
{
    __shared__ float tile[32][33];
    int r0 = blockIdx.y*32, c0 = blockIdx.x*32;
    int tx = threadIdx.x & 31, ty = threadIdx.x >> 5;
    for (int i = ty; i < 32; i += 8)
        tile[i][tx] = src[(size_t)(r0 + i)*n + (c0 + tx)];
    __syncthreads();
    for (int i = ty; i < 32; i += 8)
        dst[(size_t)(c0 + i)*n + (r0 + tx)] = tile[tx][i];
}

// ============================ persistent Householder tridiagonalization ============================
// Barrier: RELAXED arrivals + RELAXED spin. With all cross-block data on the sc1
// (agent-coherent) path, the post-spin acquire fence is unnecessary; the pre-arrival
// __threadfence is ~free (no dirty L2 lines: all shared stores are write-through sc1).
__device__ __forceinline__ void gbar4(unsigned* __restrict__ bar, unsigned epoch)
{
    __syncthreads();
    if (threadIdx.x == 0){
        __threadfence();   // drain stores; wbl2 cheap (nothing dirty: sc1 stores)
        int g = blockIdx.x >> 5;   // / BPG
        unsigned t = __hip_atomic_fetch_add(&bar[g*32], 1u, __ATOMIC_RELAXED, __HIP_MEMORY_SCOPE_AGENT);
        if ((t & (unsigned)(BPG - 1)) == (unsigned)(BPG - 1))
            __hip_atomic_fetch_add(&bar[256], 1u, __ATOMIC_RELAXED, __HIP_MEMORY_SCOPE_AGENT);
        unsigned target = epoch * (unsigned)NGRP;
        while (__hip_atomic_load(&bar[256], __ATOMIC_RELAXED, __HIP_MEMORY_SCOPE_AGENT) < target)
            __builtin_amdgcn_s_sleep(2);
    }
    __syncthreads();
}

// One-barrier-per-column fused sytrd; all cross-block global traffic on sc1 path.
__global__ __launch_bounds__(BT2) void sytrd_coop4(
    double* __restrict__ A, double* __restrict__ e, double* __restrict__ tauA,
    double* __restrict__ sclA, double* __restrict__ P, double* __restrict__ pvA,
    unsigned* __restrict__ bar, int n, int jend)
{
    __shared__ double VP[1024], WP[1024], VJ[1024];
    __shared__ double red16[16];
    __shared__ double sh_b;
    const int tid  = threadIdx.x;
    const int bid  = blockIdx.x;
    const int lane = tid & 63;
    const int wid  = tid >> 6;
    const int gw   = bid*(BT2/64) + wid;
    const int rowUnit = gw >> 2;
    const int chunk   = gw & 3;
    const unsigned gtid = (unsigned)bid*(unsigned)BT2 + (unsigned)tid;
    const unsigned NT   = (unsigned)CB2*(unsigned)BT2;

    double tau_p = 0.0, sc_p = 0.0;
    unsigned ep = 0;

    for (int j = 0; j < jend; ++j){
        const int m = n - 1 - j;
        double* __restrict__ row = A + (size_t)j*n + (j+1);
        double c2_p = 0.0;
        // ---- phase A: block-redundant pivot-row update + sigma2 ----
        if (j > 0){
            c2_p = 0.5*tau_p*tau_p*gload(&pvA[j-1]);
            const double* __restrict__ rowp = A + (size_t)(j-1)*n + j;
            const double* __restrict__ pp   = P + (size_t)(j-1)*NN;
            for (int i = tid; i <= m; i += BT2){
                double vp = (i == 0) ? 1.0 : gload(&rowp[i])*sc_p;
                VP[i] = vp;
                WP[i] = tau_p*gload(&pp[i]) - c2_p*vp;
            }
            __syncthreads();
        }
        double s = 0.0;
        if (j > 0){
            double wp0 = WP[0];
            for (int t = tid; t < m; t += BT2){
                double x = gload(&row[t]) - WP[1+t] - wp0*VP[1+t];
                VJ[t] = x;
                if (t >= 1) s += x*x;
            }
        } else {
            for (int t = tid; t < m; t += BT2){
                double x = gload(&row[t]);
                VJ[t] = x;
                if (t >= 1) s += x*x;
            }
        }
        #pragma unroll
        for (int o = 32; o; o >>= 1) s += __shfl_down(s, o);
        if (lane == 0) red16[wid] = s;
        __syncthreads();
        if (tid == 0){
            double t2 = 0.0;
            #pragma unroll
            for (int i = 0; i < 16; ++i) t2 += red16[i];
            sh_b = t2;
        }
        __syncthreads();
        double sigma2 = sh_b;
        double alpha = VJ[0];
        double beta, tl, sc;
        if (sigma2 == 0.0){ beta = alpha; tl = 0.0; sc = 0.0; }
        else {
            beta = -copysign(sqrt(alpha*alpha + sigma2), alpha);
            tl = (beta - alpha)/beta;
            sc = 1.0/(alpha - beta);
        }
        if (bid == 0){
            for (int t = tid; t < m; t += BT2) gstore(&row[t], VJ[t]);
            if (tid == 0){
                e[j] = beta; tauA[j] = tl; sclA[j] = sc;
                if (j > 0){
                    double* dp = A + (size_t)j*n + j;
                    gstore(dp, gload(dp) - 2.0*WP[0]);
                }
            }
        }
        // ---- phase B: trailing update + matvec ----
        double pvloc = 0.0;
        if (rowUnit < m){
            const int r = rowUnit;
            double* __restrict__ Ar = A + (size_t)(j+1+r)*n + (j+1);
            double acc = 0.0;
            if (j > 0){
                double vpr = VP[1+r], wpr = WP[1+r];
                for (int c = chunk*64 + lane; c < m; c += 256){
                    double a = gload(&Ar[c]) - (vpr*WP[1+c] + wpr*VP[1+c]);
                    gstore(&Ar[c], a);
                    double vj = (c == 0) ? 1.0 : VJ[c]*sc;
                    acc += a*vj;
                }
            } else {
                for (int c = chunk*64 + lane; c < m; c += 256){
                    double a = gload(&Ar[c]);
                    double vj = (c == 0) ? 1.0 : VJ[c]*sc;
                    acc += a*vj;
                }
            }
            #pragma unroll
            for (int o = 32; o; o >>= 1) acc += __shfl_down(acc, o);
            if (lane == 0){
                atomicAdd(&P[(size_t)j*NN + r], acc);
                double vr = (r == 0) ? 1.0 : VJ[r]*sc;
                pvloc = acc*vr;
            }
        }
        if (lane == 0) red16[wid] = pvloc;
        __syncthreads();
        if (tid == 0){
            double t2 = 0.0;
            #pragma unroll
            for (int i = 0; i < 16; ++i) t2 += red16[i];
            if (t2 != 0.0) atomicAdd(&pvA[j], t2);
        }
        ++ep; gbar4(bar, ep);
        tau_p = tl; sc_p = sc;
    }
    // ---- apply final pending update (column jend-1) on the TB x TB tail ----
    {
        double c2f = 0.5*tau_p*tau_p*gload(&pvA[jend-1]);
        const double* __restrict__ rowp = A + (size_t)(jend-1)*n + jend;
        const double* __restrict__ pp   = P + (size_t)(jend-1)*NN;
        const int tb = n - jend;
        const unsigned tot = (unsigned)(tb*tb);
        for (unsigned idx = gtid; idx < tot; idx += NT){
            int ri = (int)(idx / (unsigned)tb), ci = (int)(idx % (unsigned)tb);
            double vpr = (ri == 0) ? 1.0 : gload(&rowp[ri])*sc_p;
            double wpr = tau_p*gload(&pp[ri]) - c2f*vpr;
            double vpc = (ci == 0) ? 1.0 : gload(&rowp[ci])*sc_p;
            double wpc = tau_p*gload(&pp[ci]) - c2f*vpc;
            double* ap = A + (size_t)(jend+ri)*n + (jend+ci);
            gstore(ap, gload(ap) - (vpr*wpc + wpr*vpc));
        }
    }
}

// Tail: remaining (TB-2) Householder steps entirely in LDS (single block).
__global__ __launch_bounds__(256) void hh_tail(double* __restrict__ A64, double* __restrict__ e,
                                               double* __restrict__ tau, double* __restrict__ scaleg, int n)
{
    __shared__ double T[TB][TB+2];
    __shared__ double v[TB], p[TB], red[256];
    const int base = n - TB;
    const int tid = threadIdx.x;
    for (int t = tid; t < TB*TB; t += 256){
        int r = t / TB, c = t % TB;
        T[r][c] = A64[(size_t)(base + r)*n + base + c];
    }
    __syncthreads();
    for (int l = 0; l <= TB - 3; ++l){
        const int m = TB - 1 - l;
        double s = 0.0;
        for (int i = 1 + tid; i < m; i += 256){ double x = T[l+1+i][l]; s += x*x; }
        red[tid] = s; __syncthreads();
        for (int o = 128; o; o >>= 1){ if (tid < o) red[tid] += red[tid + o]; __syncthreads(); }
        double sigma2 = red[0];
        double alpha = T[l+1][l];
        double beta, tl, sc;
        if (sigma2 == 0.0){ beta = alpha; tl = 0.0; sc = 0.0; }
        else {
            beta = -copysign(sqrt(alpha*alpha + sigma2), alpha);
            tl = (beta - alpha)/beta;
            sc = 1.0/(alpha - beta);
        }
        for (int i = tid; i < m; i += 256) v[i] = (i == 0) ? 1.0 : T[l+1+i][l]*sc;
        __syncthreads();
        for (int i = tid; i < m; i += 256){
            double acc = 0.0;
            for (int c = 0; c < m; ++c) acc += T[l+1+i][l+1+c]*v[c];
            p[i] = acc;
        }
        __syncthreads();
        double s2 = 0.0;
        for (int i = tid; i < m; i += 256) s2 += p[i]*v[i];
        red[tid] = s2; __syncthreads();
        for (int o = 128; o; o >>= 1){ if (tid < o) red[tid] += red[tid + o]; __syncthreads(); }
        double pvv = red[0];
        double c2 = 0.5*tl*tl*pvv;
        for (int t2 = tid; t2 < m*m; t2 += 256){
            int r = t2 / m, c = t2 % m;
            double wr = tl*p[r] - c2*v[r];
            double wc = tl*p[c] - c2*v[c];
            T[l+1+r][l+1+c] -= v[r]*wc + wr*v[c];
        }
        if (tid == 0){ int j = base + l; e[j] = beta; tau[j] = tl; scaleg[j] = 1.0; }
        for (int i = tid; i < m; i += 256) A64[(size_t)(base + l)*n + (base + l + 1) + i] = v[i];
        __syncthreads();
    }
    for (int r = tid; r < TB; r += 256) A64[(size_t)(base + r)*n + base + r] = T[r][r];
    if (tid == 0) A64[(size_t)(n-1)*n + (n-2)] = T[TB-1][TB-2];
}

__global__ __launch_bounds__(256) void extract_de_k(const double* __restrict__ A64, double* __restrict__ d,
                                                    double* __restrict__ e, int n)
{
    int i = blockIdx.x*256 + threadIdx.x;
    if (i < n) d[i] = A64[(size_t)i*n + i];
    if (i == 0) e[n-2] = A64[(size_t)(n-1)*n + (n-2)];
}

// ============================ tridiagonal eigensolver ============================
// Multiplication-form Sturm count (no division in the dependent chain):
//   p_i = (d_i - x) p_{i-1} - e_{i-1}^2 p_{i-2};  q_i = p_i/p_{i-1};
//   count = #{i : q_i < 0} = # sign changes; pair-rescaled to avoid under/overflow.
__global__ __launch_bounds__(256) void bisect_k(const double* __restrict__ d, const double* __restrict__ e,
                                                double* __restrict__ w, int n)
{
    __shared__ double ds[1024], e2s[1024];
    const int tid = threadIdx.x;
    for (int i = tid; i < n; i += 256) ds[i] = d[i];
    for (int i = tid; i < n-1; i += 256){ double ei = e[i]; e2s[i] = ei*ei; }
    __syncthreads();
    int k = blockIdx.x*256 + tid;
    if (k >= n) return;
    double gl = 1e300, gu = -1e300;
    for (int i = 0; i < n; ++i){
        double em = (i > 0) ? sqrt(e2s[i-1]) : 0.0, ep2 = (i < n-1) ? sqrt(e2s[i]) : 0.0;
        double lo2 = ds[i] - em - ep2, hi2 = ds[i] + em + ep2;
        gl = fmin(gl, lo2); gu = fmax(gu, hi2);
    }
    double lo = gl - 1e-10, hi = gu + 1e-10;
    for (int it = 0; it < 42; ++it){
        double mid = 0.5*(lo + hi);
        int cnt = 0;
        double p0 = 1.0;
        double p1 = ds[0] - mid;
        if (p1 <= 0.0){ ++cnt; if (p1 == 0.0) p1 = -1e-300; }
        for (int i = 1; i < n; ++i){
            double pn = (ds[i] - mid)*p1 - e2s[i-1]*p0;
            bool neg = ((pn < 0.0) != (p1 < 0.0)) || (pn == 0.0);
            cnt += neg;
            if (pn == 0.0) pn = (p1 > 0.0) ? -1e-300 : 1e-300;
            p0 = p1; p1 = pn;
            double ap = fabs(p1);
            if (ap > 1e120){ p1 *= 1e-200; p0 *= 1e-200; }
            else if (ap < 1e-120){ p1 *= 1e200; p0 *= 1e200; }
        }
        if (cnt <= k) lo = mid; else hi = mid;
    }
    w[k] = 0.5*(lo + hi);
}

__global__ __launch_bounds__(256) void invit_k(const double* __restrict__ d, const double* __restrict__ e,
                                               const double* __restrict__ w,
                                               double* __restrict__ FD, double* __restrict__ FL,
                                               double* __restrict__ FU, double* __restrict__ FU2,
                                               signed char* __restrict__ PIV, double* __restrict__ Z, int n)
{
    int k = blockIdx.x*256 + threadIdx.x;
    if (k >= n) return;
    const double lam = w[k];
    const double tiny = 1e-280;
    double dcur = d[0] - lam;
    double ucur = e[0];
    for (int i = 0; i < n-1; ++i){
        double dli = e[i];
        double dnext_init = d[i+1] - lam;
        double unext_init = (i < n-2) ? e[i+1] : 0.0;
        size_t o = (size_t)i*n + k;
        if (fabs(dcur) >= fabs(dli)){
            if (dcur == 0.0) dcur = tiny;
            double f = dli/dcur;
            FD[o] = dcur; FL[o] = f; FU[o] = ucur; FU2[o] = 0.0; PIV[o] = 0;
            dcur = dnext_init - f*ucur;
            ucur = unext_init;
        } else {
            double f = dcur/dli;
            FD[o] = dli; FL[o] = f; FU[o] = dnext_init; FU2[o] = unext_init; PIV[o] = 1;
            dcur = ucur - f*dnext_init;
            ucur = -f*unext_init;
        }
    }
    if (dcur == 0.0) dcur = tiny;
    FD[(size_t)(n-1)*n + k] = dcur;
    for (int i = 0; i < n; ++i){
        unsigned h = (unsigned)(i + 1)*0x9E3779B9u + (unsigned)(k + 1)*0x85EBCA6Bu;
        h ^= h >> 16; h *= 0x7FEB352Du; h ^= h >> 15; h *= 0x846CA68Bu; h ^= h >> 16;
        Z[(size_t)i*n + k] = (double)(h >> 8)*(1.0/16777216.0) - 0.5;
    }
    for (int iter = 0; iter < 2; ++iter){
        double zc = Z[k];
        for (int i = 0; i < n-1; ++i){
            size_t o = (size_t)i*n + k;
            double fl = FL[o];
            double zn = Z[o + n];
            if (!PIV[o]){
                Z[o] = zc;
                zc = zn - fl*zc;
            } else {
                Z[o] = zn;
                zc = zc - fl*zn;
            }
        }
        double za = zc / FD[(size_t)(n-1)*n + k];
        Z[(size_t)(n-1)*n + k] = za;
        size_t o2 = (size_t)(n-2)*n + k;
        double zaa = (Z[o2] - FU[o2]*za) / FD[o2];
        Z[o2] = zaa;
        double zb = za;
        for (int i = n-3; i >= 0; --i){
            size_t o = (size_t)i*n + k;
            double znew = (Z[o] - FU[o]*zaa - FU2[o]*zb) / FD[o];
            Z[o] = znew;
            zb = zaa; zaa = znew;
        }
        double mx = 0.0;
        for (int i = 0; i < n; ++i) mx = fmax(mx, fabs(Z[(size_t)i*n + k]));
        double s = (mx > 0.0) ? 1.0/mx : 1.0;
        for (int i = 0; i < n; ++i) Z[(size_t)i*n + k] *= s;
    }
    double nrm = 0.0;
    for (int i = 0; i < n; ++i){ double v = Z[(size_t)i*n + k]; nrm += v*v; }
    double s = 1.0/sqrt(nrm);
    for (int i = 0; i < n; ++i) Z[(size_t)i*n + k] *= s;
}

// ============================ batched blocked-WY back-transform ============================
__global__ __launch_bounds__(256) void wy_buildV_k(const double* __restrict__ A64, const double* __restrict__ scaleg,
                                                   double* __restrict__ Vbig, int n)
{
    size_t idx = (size_t)blockIdx.x*256 + threadIdx.x;
    if (idx >= (size_t)NWY*1024*64) return;
    int g = (int)(idx >> 16);
    int r = (int)((idx >> 6) & 1023);
    int t = (int)(idx & 63);
    int b0 = g*64;
    int nbsz = (n - 2) - b0; if (nbsz > 64) nbsz = 64;
    double v = 0.0;
    if (t < nbsz){
        int j = b0 + t;
        if (r == j + 1) v = 1.0;
        else if (r > j + 1) v = A64[(size_t)j*n + r]*scaleg[j];
    }
    Vbig[idx] = v;
}

__global__ __launch_bounds__(256) void wy_buildT_k(const double* __restrict__ Vbig, const double* __restrict__ tau,
                                                   double* __restrict__ Tbig, int n)
{
    __shared__ double G[64][65];
    __shared__ double Ts[64][65];
    __shared__ double Vs[32][65];
    const int g = blockIdx.x;
    const int tid = threadIdx.x;
    const double* __restrict__ V = Vbig + ((size_t)g << 16);
    const int b0 = g*64;
    int nbsz = (n - 2) - b0; if (nbsz > 64) nbsz = 64;
    for (int p = tid; p < 64*64; p += 256) G[p >> 6][p & 63] = 0.0;
    __syncthreads();
    for (int rb = b0; rb < n; rb += 32){
        for (int s = tid; s < 2048; s += 256){
            int rr = s >> 6, tt = s & 63;
            Vs[rr][tt] = V[((size_t)(rb + rr) << 6) + tt];
        }
        __syncthreads();
        for (int p = tid; p < 4096; p += 256){
            int t = p >> 6, s2 = p & 63;
            if (t < s2 && s2 < nbsz){
                double acc = 0.0;
                #pragma unroll 8
                for (int rr = 0; rr < 32; ++rr) acc += Vs[rr][t]*Vs[rr][s2];
                G[t][s2] += acc;
            }
        }
        __syncthreads();
    }
    for (int t = nbsz - 1; t >= 0; --t){
        for (int u = tid; u < 64; u += 256){
            double val = 0.0;
            if (u == t) val = tau[b0 + t];
            else if (u > t && u < nbsz){
                double s = 0.0;
                for (int s2 = t + 1; s2 <= u; ++s2) s += G[t][s2]*Ts[s2][u];
                val = -tau[b0 + t]*s;
            }
            Ts[t][u] = val;
        }
        __syncthreads();
    }
    for (int p = tid; p < 64*64; p += 256){
        int t = p >> 6, u = p & 63;
        Tbig[((size_t)g << 12) + p] = (t < nbsz) ? Ts[t][u] : 0.0;
    }
}

__global__ __launch_bounds__(256) void wy_apply_k(const double* __restrict__ Vbig, const double* __restrict__ Tbig,
                                                  double* __restrict__ Z, int n)
{
    __shared__ double Vs[32][65];
    __shared__ double Zs[32][17];
    __shared__ double Y[64][17];
    __shared__ double W[64][17];
    const int tid = threadIdx.x;
    const int c   = tid & 15;
    const int tq  = tid >> 4;
    const int c0  = blockIdx.x * 16;

    for (int g = NWY - 1; g >= 0; --g){
        const double* __restrict__ V = Vbig + ((size_t)g << 16);
        const double* __restrict__ T = Tbig + ((size_t)g << 12);
        const int b0 = g*64;
        double acc0 = 0.0, acc1 = 0.0, acc2 = 0.0, acc3 = 0.0;
        for (int rb = b0; rb < n; rb += 32){
            for (int s = tid; s < 2048; s += 256){
                int rr = s >> 6, tt = s & 63;
                Vs[rr][tt] = V[((size_t)(rb + rr) << 6) + tt];
            }
            for (int s = tid; s < 512; s += 256){
                int rr = s >> 4, cc = s & 15;
                Zs[rr][cc] = Z[(size_t)(rb + rr)*n + c0 + cc];
            }
            __syncthreads();
            #pragma unroll 8
            for (int rr = 0; rr < 32; ++rr){
                double z = Zs[rr][c];
                acc0 += Vs[rr][tq*4+0]*z;
                acc1 += Vs[rr][tq*4+1]*z;
                acc2 += Vs[rr][tq*4+2]*z;
                acc3 += Vs[rr][tq*4+3]*z;
            }
            __syncthreads();
        }
        Y[tq*4+0][c] = acc0; Y[tq*4+1][c] = acc1; Y[tq*4+2][c] = acc2; Y[tq*4+3][c] = acc3;
        __syncthreads();
        #pragma unroll
        for (int i = 0; i < 4; ++i){
            int t = tq*4 + i;
            double a = 0.0;
            for (int s = t; s < 64; ++s) a += T[(t << 6) + s]*Y[s][c];
            W[t][c] = a;
        }
        __syncthreads();
        for (int rb = b0; rb < n; rb += 32){
            for (int s = tid; s < 2048; s += 256){
                int rr = s >> 6, tt = s & 63;
                Vs[rr][tt] = V[((size_t)(rb + rr) << 6) + tt];
            }
            __syncthreads();
            #pragma unroll
            for (int half = 0; half < 2; ++half){
                int item = tid + half*256;
                int rr = item >> 4, cc = item & 15;
                double s = 0.0;
                #pragma unroll 16
                for (int t = 0; t < 64; ++t) s += Vs[rr][t]*W[t][cc];
                Z[(size_t)(rb + rr)*n + c0 + cc] -= s;
            }
            __syncthreads();
        }
        __syncthreads();
    }
}

// ============================ host dispatch helpers ============================
static void gemmf32(hipStream_t st, int epi,
                    const float* A, const float* B, float* C, int M, int N, int K,
                    const float* bias, const float* D)
{
    if ((K & 15) == 0 && (N & 7) == 0){
        dim3 g((N + 127)/128, (M + 127)/128), b(256);
        switch (epi){
        case EPI_NONE:      gemm128<EPI_NONE><<<g, b, 0, st>>>(A, B, C, M, N, K, bias, D); break;
        case EPI_BIAS:      gemm128<EPI_BIAS><<<g, b, 0, st>>>(A, B, C, M, N, K, bias, D); break;
        case EPI_BIAS_ADD:  gemm128<EPI_BIAS_ADD><<<g, b, 0, st>>>(A, B, C, M, N, K, bias, D); break;
        case EPI_ABS_DIAG1: gemm128<EPI_ABS_DIAG1><<<g, b, 0, st>>>(A, B, C, M, N, K, bias, D); break;
        case EPI_RELU:      gemm128<EPI_RELU><<<g, b, 0, st>>>(A, B, C, M, N, K, bias, D); break;
        }
    } else {
        dim3 g((N + 63)/64, (M + 63)/64), b(256);
        switch (epi){
        case EPI_NONE:      gemm32<EPI_NONE><<<g, b, 0, st>>>(A, B, C, M, N, K, bias, D); break;
        case EPI_BIAS:      gemm32<EPI_BIAS><<<g, b, 0, st>>>(A, B, C, M, N, K, bias, D); break;
        case EPI_BIAS_ADD:  gemm32<EPI_BIAS_ADD><<<g, b, 0, st>>>(A, B, C, M, N, K, bias, D); break;
        case EPI_ABS_DIAG1: gemm32<EPI_ABS_DIAG1><<<g, b, 0, st>>>(A, B, C, M, N, K, bias, D); break;
        case EPI_RELU:      gemm32<EPI_RELU><<<g, b, 0, st>>>(A, B, C, M, N, K, bias, D); break;
        }
    }
}

// ============================ kernel_launch ============================
extern "C" void kernel_launch(void* const* d_in, const int* in_sizes, int n_in,
                              void* d_out, int out_size, void* d_ws, size_t ws_size,
                              hipStream_t stream)
{
    (void)in_sizes; (void)n_in; (void)out_size; (void)ws_size;
    const float* lr       = (const float*)d_in[0];
    const float* gsr_w    = (const float*)d_in[1];
    const float* start_w  = (const float*)d_in[2];
    const float* start_b  = (const float*)d_in[3];
    const float* down_w   = (const float*)d_in[4];
    const float* down_b   = (const float*)d_in[5];
    const float* pool_w   = (const float*)d_in[6];
    const float* pool_b   = (const float*)d_in[7];
    const float* bottom_w = (const float*)d_in[8];
    const float* bottom_b = (const float*)d_in[9];
    const float* end_w    = (const float*)d_in[10];
    const float* end_b    = (const float*)d_in[11];
    const float* up_w     = (const float*)d_in[12];
    const float* up_b     = (const float*)d_in[13];
    const float* gc1      = (const float*)d_in[14];
    const float* gc2      = (const float*)d_in[15];

    float* out_z     = (float*)d_out;                       // [2048,2048]
    float* out_net   = out_z + (size_t)HRD*HRD;             // [1024,2048]
    float* out_start = out_net + (size_t)NN*HRD;            // [1024,320]
    float* out_adj   = out_start + (size_t)NN*DIMF;         // [2048,2048]

    static const int LVL_N[4] = {1024, 921, 644, 386};
    static const int LVL_K[4] = {921, 644, 386, 193};

    // -------- workspace arena --------
    char* Wb = (char*)d_ws;
    size_t off = 0;
    auto alloc = [&](size_t bb)->char*{ char* p = Wb + off; off = (off + bb + 255) & ~(size_t)255; return p; };

    float*  A32  = (float*) alloc((size_t)NN*NN*4);
    double* A64  = (double*)alloc((size_t)NN*NN*8);
    float*  UfT  = (float*) alloc((size_t)NN*NN*4);   // U^T as [k][j] fp32
    double* r64  = (double*)alloc(NN*8);
    double* dD   = (double*)alloc(NN*8);
    double* dE   = (double*)alloc(NN*8);
    double* dTau = (double*)alloc(NN*8);
    double* dScl = (double*)alloc(NN*8);
    double* dWev = (double*)alloc(NN*8);
    double* pvA  = (double*)alloc(NN*8);
    unsigned* barcnt = (unsigned*)alloc(8192);
    char* SBASE = Wb + off;

    // P2 overlay (U-Net)
    size_t so = 0;
    auto salloc = [&](size_t bb)->char*{ char* p = SBASE + so; so = (so + bb + 255) & ~(size_t)255; return p; };
    float* XT  = (float*)salloc((size_t)NN*DIMF*4);
    float* XP1 = (float*)salloc((size_t)NN*DIMF*4);
    float* XP2 = (float*)salloc((size_t)NN*DIMF*4);
    float* XU  = (float*)salloc((size_t)NN*DIMF*4);
    float* DN[4]; for (int l = 0; l < 4; ++l) DN[l] = (float*)salloc((size_t)NN*DIMF*4);
    float* Asub[4];
    for (int l = 0; l < 4; ++l) Asub[l] = (float*)salloc((size_t)LVL_K[l]*LVL_K[l]*4);
    float* SC = (float*)salloc(NN*4);
    int*   IDX[4]; for (int l = 0; l < 4; ++l) IDX[l] = (int*)salloc(NN*4);
    float* VAL[4]; for (int l = 0; l < 4; ++l) VAL[l] = (float*)salloc(NN*4);
    float* XC  = (float*)salloc((size_t)NN*2*DIMF*4);
    float* AXC = (float*)salloc((size_t)NN*2*DIMF*4);

    // P3 overlay (eigensolver scratch)
    const size_t PL = (size_t)NN*NN*8;
    double* Z64 = (double*)(SBASE);
    double* FD  = (double*)(SBASE + PL);       // doubles as Pmat during sytrd, Vbig during WY
    double* FL  = (double*)(SBASE + 2*PL);     // doubles as Tbig during WY
    double* FU  = (double*)(SBASE + 3*PL);
    double* FU2 = (double*)(SBASE + 4*PL);
    signed char* FPIV = (signed char*)(SBASE + 5*PL);
    double* Pmat = FD;
    double* Vbig = FD;
    double* Tbig = FL;

    // P4 overlay (GSR / refinement)
    const size_t MB8  = (size_t)HRD*NN*4;    // 8 MiB
    const size_t MB16 = (size_t)HRD*HRD*4;   // 16 MiB
    float* P4a   = (float*)(SBASE);
    float* P4t1  = (float*)(SBASE + MB8);
    float* P4adT = (float*)(SBASE);
    float* P4Zb  = (float*)(SBASE + MB16);
    float* P4ZG  = (float*)(SBASE);
    float* P4h1  = (float*)(SBASE + MB8);
    float* P4HG  = (float*)(SBASE + MB16);
    float* P4h2  = (float*)(SBASE);

    // =============== P1: normalized adjacency ===============
    rowsum_rsqrt_k<<<NN, 256, 0, stream>>>(lr, r64, NN);
    build_A_k<<<(NN*NN + 255)/256, 256, 0, stream>>>(lr, r64, A32, A64, NN);

    // =============== P2: graph U-Net (fp32) ===============
    gemmf32(stream, EPI_BIAS, A32, start_w, out_start, NN, DIMF, NN, start_b, nullptr);

    const float* Xcur = out_start;
    const float* Acur = A32;
    float* ping = XP1; float* pong = XP2;
    for (int l = 0; l < 4; ++l){
        int nl = LVL_N[l], kl = LVL_K[l];
        gemmf32(stream, EPI_NONE, Acur, Xcur, XT, nl, DIMF, nl, nullptr, nullptr);
        gemmf32(stream, EPI_BIAS, XT, down_w + (size_t)l*DIMF*DIMF, DN[l], nl, DIMF, DIMF,
                down_b + (size_t)l*DIMF, nullptr);
        score_k<<<(nl + 3)/4, 256, 0, stream>>>(DN[l], pool_w + (size_t)l*DIMF, pool_b + l, SC, nl, DIMF);
        topk_k<<<1, 256, 0, stream>>>(SC, nl, kl, IDX[l], VAL[l]);
        gatherX_k<<<(unsigned)(((size_t)kl*DIMF + 255)/256), 256, 0, stream>>>(DN[l], IDX[l], VAL[l], ping, kl, DIMF);
        gatherA_k<<<(unsigned)(((size_t)kl*kl + 255)/256), 256, 0, stream>>>(Acur, IDX[l], Asub[l], kl, nl);
        Xcur = ping; Acur = Asub[l];
        float* t = ping; ping = pong; pong = t;
    }
    gemmf32(stream, EPI_NONE, Acur, Xcur, XT, 193, DIMF, 193, nullptr, nullptr);
    float* Xb = ping;
    gemmf32(stream, EPI_BIAS, XT, bottom_w, Xb, 193, DIMF, DIMF, bottom_b, nullptr);
    const float* Xup = Xb;
    float* upbuf[2] = { (Xb == XP1) ? XP2 : XP1, (Xb == XP1) ? XP1 : XP2 };
    for (int i2 = 0; i2 < 4; ++i2){
        int jl = 3 - i2;
        int nj = LVL_N[jl];
        int kj = LVL_K[jl];
        fill0_k<<<(unsigned)(((size_t)nj*DIMF + 255)/256), 256, 0, stream>>>(XU, (size_t)nj*DIMF);
        scatterX_k<<<(unsigned)(((size_t)kj*DIMF + 255)/256), 256, 0, stream>>>(Xup, IDX[jl], XU, kj, DIMF);
        const float* Aj = (jl == 0) ? A32 : Asub[jl - 1];
        gemmf32(stream, EPI_NONE, Aj, XU, XT, nj, DIMF, nj, nullptr, nullptr);
        float* Xn = upbuf[i2 & 1];
        gemmf32(stream, EPI_BIAS_ADD, XT, up_w + (size_t)i2*DIMF*DIMF, Xn, nj, DIMF, DIMF,
                up_b + (size_t)i2*DIMF, DN[jl]);
        Xup = Xn;
    }
    concat_k<<<(unsigned)(((size_t)NN*2*DIMF + 255)/256), 256, 0, stream>>>(Xup, out_start, XC, NN, DIMF);
    gemmf32(stream, EPI_NONE, A32, XC, AXC, NN, 2*DIMF, NN, nullptr, nullptr);
    gemmf32(stream, EPI_BIAS, AXC, end_w, out_net, NN, HRD, 2*DIMF, end_b, nullptr);

    // =============== P3: eigendecomposition of A (fp64) ===============
    const int JEND = NN - TB;
    init_sytrd_k<<<4, 256, 0, stream>>>(pvA, barcnt, NN);
    filld0_k<<<(unsigned)(((size_t)JEND*NN + 255)/256), 256, 0, stream>>>(Pmat, (size_t)JEND*NN);
    sytrd_coop4<<<CB2, BT2, 0, stream>>>(A64, dE, dTau, dScl, Pmat, pvA, barcnt, NN, JEND);
    hh_tail<<<1, 256, 0, stream>>>(A64, dE, dTau, dScl, NN);
    extract_de_k<<<4, 256, 0, stream>>>(A64, dD, dE, NN);
    bisect_k<<<4, 256, 0, stream>>>(dD, dE, dWev, NN);
    invit_k<<<4, 256, 0, stream>>>(dD, dE, dWev, FD, FL, FU, FU2, FPIV, Z64, NN);
    wy_buildV_k<<<(unsigned)(((size_t)NWY*1024*64 + 255)/256), 256, 0, stream>>>(A64, dScl, Vbig, NN);
    wy_buildT_k<<<NWY, 256, 0, stream>>>(Vbig, dTau, Tbig, NN);
    wy_apply_k<<<NN/16, 256, 0, stream>>>(Vbig, Tbig, Z64, NN);
    {
        dim3 g(NN/32, NN/32), b(256);
        transpose_cast_k<<<g, b, 0, stream>>>(Z64, UfT, NN);
    }

    // =============== P4: GSR layer + refinement (fp32) ===============
    build_a_k<<<(unsigned)(((size_t)HRD*NN + 255)/256), 256, 0, stream>>>(gsr_w, P4a);
    gemmf32(stream, EPI_NONE, P4a, UfT, P4t1, HRD, NN, NN, nullptr, nullptr);               // a @ U^T
    gemmf32(stream, EPI_ABS_DIAG1, P4t1, out_net, out_adj, HRD, HRD, NN, nullptr, nullptr); // adj
    {
        dim3 g(HRD/32, HRD/32), b(256);
        transpose32_k<<<g, b, 0, stream>>>(out_adj, P4adT, HRD);                            // adj^T
    }
    gemmf32(stream, EPI_NONE, out_adj, P4adT, P4Zb, HRD, HRD, HRD, nullptr, nullptr);       // adj @ adj^T
    symabs1_k<<<(unsigned)(((size_t)HRD*HRD + 255)/256), 256, 0, stream>>>(P4Zb, HRD);      // Z
    gemmf32(stream, EPI_NONE, P4Zb, gc1, P4ZG, HRD, NN, HRD, nullptr, nullptr);             // Z @ gc1
    gemmf32(stream, EPI_RELU, out_adj, P4ZG, P4h1, HRD, NN, HRD, nullptr, nullptr);         // h1
    gemmf32(stream, EPI_NONE, P4h1, gc2, P4HG, HRD, HRD, NN, nullptr, nullptr);             // h1 @ gc2
    gemmf32(stream, EPI_RELU, out_adj, P4HG, P4h2, HRD, HRD, HRD, nullptr, nullptr);        // h2
    final_z_k<<<(unsigned)(((size_t)HRD*HRD + 255)/256), 256, 0, stream>>>(P4h2, out_z, HRD); // z
}